// Round 3
// baseline (1175.162 us; speedup 1.0000x reference)
//
#include <hip/hip_runtime.h>
#include <math.h>
#include <stdint.h>

#define B_   2048
#define NS_  128
#define D_   1024
#define K_   8
#define DH_  512
#define G3_  3072

typedef unsigned short u16;
typedef short bf16x8 __attribute__((ext_vector_type(8)));
typedef float f32x4 __attribute__((ext_vector_type(4)));

__device__ __forceinline__ float bf2f(u16 u) {
  union { unsigned i; float f; } v; v.i = ((unsigned)u) << 16; return v.f;
}
__device__ __forceinline__ u16 f2bf(float f) {
  unsigned x = __float_as_uint(f);
  return (u16)((x + 0x7fffu + ((x >> 16) & 1u)) >> 16);
}

#define AS1C(p) ((const __attribute__((address_space(1))) void*)(uintptr_t)(p))
#define AS3(p)  ((__attribute__((address_space(3))) void*)(unsigned)(uintptr_t)(p))

// ---- Bresenham stripe dispatch: uniformly interleave nS stripe blocks among
// `total` blocks. Returns true if this block is a stripe (sid), else cid is
// the compute block index.
__device__ __forceinline__ bool stripe_take(int g, int nS, int total,
                                            int& sid, int& cid) {
  const int b0 = (int)(((long long)g * nS) / total);
  const int b1 = (int)(((long long)(g + 1) * nS) / total);
  sid = b0;
  cid = g - b0;
  return b1 > b0;
}

// ---- copy one batch's 128 rows S->Snew (256 threads) ----
__device__ __forceinline__ void copy_batch(const float* __restrict__ S,
                                           float* __restrict__ Snew, int b) {
  const int t = threadIdx.x;
  const f32x4* src = (const f32x4*)(S + (size_t)b * NS_ * D_) + t;
  f32x4* dst = (f32x4*)(Snew + (size_t)b * NS_ * D_) + t;
  #pragma unroll 4
  for (int r = 0; r < NS_; r += 4) {
    f32x4 v0 = src[0];
    f32x4 v1 = src[256];
    f32x4 v2 = src[512];
    f32x4 v3 = src[768];
    __builtin_nontemporal_store(v0, dst);
    __builtin_nontemporal_store(v1, dst + 256);
    __builtin_nontemporal_store(v2, dst + 512);
    __builtin_nontemporal_store(v3, dst + 768);
    src += 1024; dst += 1024;
  }
}

// ---- mean over one batch's 128 rows (f64 accum, 256 threads) ----
__device__ __forceinline__ void mean_batch(const float* __restrict__ S,
                                           float* __restrict__ mean, int b) {
  const int t = threadIdx.x, d0 = t * 4;
  const float* src = S + (size_t)b * NS_ * D_ + d0;
  double a0 = 0, a1 = 0, a2 = 0, a3 = 0;
  for (int s = 0; s < NS_; ++s) {
    float4 v = *(const float4*)(src + (size_t)s * D_);
    a0 += v.x; a1 += v.y; a2 += v.z; a3 += v.w;
  }
  float4 m;
  m.x = (float)(a0 * (1.0 / 128.0)); m.y = (float)(a1 * (1.0 / 128.0));
  m.z = (float)(a2 * (1.0 / 128.0)); m.w = (float)(a3 * (1.0 / 128.0));
  *(float4*)&mean[(size_t)b * D_ + d0] = m;
}

// ---------------- fused copy+mean (or mean-only), one batch per block ----------------
template<int DO_COPY>
__global__ __launch_bounds__(256)
void sp_copymean(const float* __restrict__ S, float* __restrict__ Snew,
                 float* __restrict__ mean, int batch0) {
  const int b = batch0 + blockIdx.x;
  const int t = threadIdx.x, d0 = t * 4;
  const float* src = S + (size_t)b * NS_ * D_ + d0;
  float* dst = Snew + (size_t)b * NS_ * D_ + d0;
  double a0 = 0, a1 = 0, a2 = 0, a3 = 0;
  for (int s = 0; s < NS_; ++s) {
    float4 v = *(const float4*)(src + (size_t)s * D_);
    if (DO_COPY) *(float4*)(dst + (size_t)s * D_) = v;
    a0 += v.x; a1 += v.y; a2 += v.z; a3 += v.w;
  }
  float4 m;
  m.x = (float)(a0 * (1.0 / 128.0)); m.y = (float)(a1 * (1.0 / 128.0));
  m.z = (float)(a2 * (1.0 / 128.0)); m.w = (float)(a3 * (1.0 / 128.0));
  *(float4*)&mean[(size_t)b * D_ + d0] = m;
}

// ---------------- fused f32 -> bf16 conversions (+ mean stripes) ----------------
__global__ __launch_bounds__(256)
void sp_convert_all(const float* __restrict__ x, const float* __restrict__ wih,
                    const float* __restrict__ whh, const float* __restrict__ wval,
                    const float* __restrict__ wout,
                    u16* __restrict__ xb, u16* __restrict__ wihb,
                    u16* __restrict__ whhb, u16* __restrict__ wvalb,
                    u16* __restrict__ woutb,
                    const float* __restrict__ S, float* __restrict__ mean,
                    int nS, int total, int batch0) {
  int sid, cid;
  if (stripe_take(blockIdx.x, nS, total, sid, cid)) {
    mean_batch(S, mean, batch0 + sid);
    return;
  }
  const int stride = (total - nS) * 256;
  for (int i = cid * 256 + threadIdx.x; i < 2621440; i += stride) {
    const float* s; u16* d; int off;
    if (i < 524288)       { s = x;    d = xb;    off = i; }
    else if (i < 1310720) { s = wih;  d = wihb;  off = i - 524288; }
    else if (i < 2097152) { s = whh;  d = whhb;  off = i - 1310720; }
    else if (i < 2359296) { s = wval; d = wvalb; off = i - 2097152; }
    else                  { s = wout; d = woutb; off = i - 2359296; }
    float4 v = ((const float4*)s)[off];
    ushort4 o;
    o.x = f2bf(v.x); o.y = f2bf(v.y); o.z = f2bf(v.z); o.w = f2bf(v.w);
    ((ushort4*)d)[off] = o;
  }
}

// ---------------- routing GEMM1 (f64 accum), split by K-half ----------------
// PHASE 0: hpart = x @ w1[:, 0:1024]^T   (+ mean stripes)
// PHASE 1: h = gelu(mean @ w1[:, 1024:2048]^T + hpart + b1)  (+ copy stripes)
template<int PHASE>
__global__ __launch_bounds__(256)
void sp_gemm1(const float* __restrict__ src, const float* __restrict__ w1,
              const float* __restrict__ b1, float* __restrict__ hpart,
              float* __restrict__ hout,
              const float* __restrict__ S, float* __restrict__ Snew,
              float* __restrict__ mean,
              int nS, int total, int batch0) {
  int sid, cid;
  if (stripe_take(blockIdx.x, nS, total, sid, cid)) {
    if (PHASE == 0) mean_batch(S, mean, batch0 + sid);
    else            copy_batch(S, Snew, batch0 + sid);
    return;
  }
  __shared__ float As[16][68];
  __shared__ float Bs[16][36];
  int wg = (cid & 7) * 64 + (cid >> 3);    // bijective XCD swizzle, 512 wgs
  const int n0 = (wg & 15) * 32;           // nbx = 16
  const int m0 = (wg >> 4) * 64;
  const int t = threadIdx.x;
  const int tx = t & 15, ty = t >> 4;
  double acc[4][2] = {};
  const int sr = t >> 2, sc = (t & 3) * 4;
  const int kw = PHASE ? D_ : 0;
  for (int k0 = 0; k0 < D_; k0 += 16) {
    float4 va = *(const float4*)&src[(size_t)(m0 + sr) * D_ + k0 + sc];
    As[sc + 0][sr] = va.x; As[sc + 1][sr] = va.y; As[sc + 2][sr] = va.z; As[sc + 3][sr] = va.w;
    if (t < 128) {
      const int bn = t >> 2, bc = (t & 3) * 4;
      float4 vb = *(const float4*)&w1[(size_t)(n0 + bn) * (2 * D_) + kw + k0 + bc];
      Bs[bc + 0][bn] = vb.x; Bs[bc + 1][bn] = vb.y; Bs[bc + 2][bn] = vb.z; Bs[bc + 3][bn] = vb.w;
    }
    __syncthreads();
    #pragma unroll
    for (int kk = 0; kk < 16; ++kk) {
      float4 a = *(const float4*)&As[kk][ty * 4];
      float2 bb = *(const float2*)&Bs[kk][tx * 2];
      double b0 = (double)bb.x, b1d = (double)bb.y;
      acc[0][0] += (double)a.x * b0; acc[0][1] += (double)a.x * b1d;
      acc[1][0] += (double)a.y * b0; acc[1][1] += (double)a.y * b1d;
      acc[2][0] += (double)a.z * b0; acc[2][1] += (double)a.z * b1d;
      acc[3][0] += (double)a.w * b0; acc[3][1] += (double)a.w * b1d;
    }
    __syncthreads();
  }
  #pragma unroll
  for (int i = 0; i < 4; ++i) {
    #pragma unroll
    for (int j = 0; j < 2; ++j) {
      const int r = m0 + ty * 4 + i, c = n0 + tx * 2 + j;
      if (PHASE == 0) {
        hpart[(size_t)r * DH_ + c] = (float)acc[i][j];
      } else {
        float v = (float)acc[i][j] + hpart[(size_t)r * DH_ + c] + b1[c];
        v = 0.5f * v * (1.0f + erff(v * 0.70710678118654752f));
        hout[(size_t)r * DH_ + c] = v;
      }
    }
  }
}

// ---------------- logits + top-8 + softmax (one wave per row, f64 dot) ----------------
__global__ __launch_bounds__(64)
void sp_route_topk(const float* __restrict__ h, const float* __restrict__ w2,
                   const float* __restrict__ b2, const float* __restrict__ tau,
                   int* __restrict__ tki, float* __restrict__ tkw) {
  __shared__ float hs[DH_];
  const int b = blockIdx.x, l = threadIdx.x;
  *(float4*)&hs[l * 4] = *(const float4*)&h[(size_t)b * DH_ + l * 4];
  *(float4*)&hs[256 + l * 4] = *(const float4*)&h[(size_t)b * DH_ + 256 + l * 4];
  __syncthreads();
  const double invd = 1.0 / ((double)fabsf(tau[0]) + 0.1);
  float v[2]; int id[2];
  #pragma unroll
  for (int c = 0; c < 2; ++c) {
    const int n = c * 64 + l;
    const float* wr = &w2[(size_t)n * DH_];
    double s = 0.0;
    for (int j = 0; j < DH_; j += 4) {
      float4 w4 = *(const float4*)&wr[j];
      s += (double)hs[j] * (double)w4.x;
      s += (double)hs[j + 1] * (double)w4.y;
      s += (double)hs[j + 2] * (double)w4.z;
      s += (double)hs[j + 3] * (double)w4.w;
    }
    v[c] = (float)((s + (double)b2[n]) * invd);
    id[c] = n;
  }
  float m0f = 0.f, sum = 0.f, mye = 0.f; int myi = 0;
  for (int r = 0; r < 8; ++r) {
    float mv; int mi;
    if (v[1] > v[0]) { mv = v[1]; mi = id[1]; } else { mv = v[0]; mi = id[0]; }
    #pragma unroll
    for (int off = 32; off > 0; off >>= 1) {
      float ov = __shfl_xor(mv, off);
      int oi = __shfl_xor(mi, off);
      if (ov > mv || (ov == mv && oi < mi)) { mv = ov; mi = oi; }
    }
    if (r == 0) m0f = mv;
    float er = expf(mv - m0f);
    sum += er;
    if (l == r) { mye = er; myi = mi; }
    if (mi == id[0]) v[0] = -3.0e38f;
    if (mi == id[1]) v[1] = -3.0e38f;
  }
  if (l < 8) { tki[b * K_ + l] = myi; tkw[b * K_ + l] = mye / sum; }
}

// ---------------- gather selected slot rows -> bf16 (+ copy stripes) ----------------
__global__ __launch_bounds__(256)
void sp_gather(const float* __restrict__ S, const int* __restrict__ tki,
               u16* __restrict__ slotb, float* __restrict__ Snew,
               int nS, int total, int batch0) {
  int sid, cid;
  if (stripe_take(blockIdx.x, nS, total, sid, cid)) {
    copy_batch(S, Snew, batch0 + sid);
    return;
  }
  const int b = cid >> 3, k = cid & 7;
  const int s = tki[b * K_ + k];
  const int t = threadIdx.x;
  float4 v = *(const float4*)&S[((size_t)b * NS_ + s) * D_ + t * 4];
  ushort4 o;
  o.x = f2bf(v.x); o.y = f2bf(v.y); o.z = f2bf(v.z); o.w = f2bf(v.w);
  *(ushort4*)&slotb[((size_t)b * K_ + k) * D_ + t * 4] = o;
}

// ---------------- bf16 TN MFMA GEMM: C[M,N] = A[M,K] * B[N,K]^T ----------------
// 128x128 tile, BK=32, 4 waves, 16x16x32 MFMA, global_load_lds, XCD swizzle,
// Bresenham-interleaved copy stripes.
// EPI: 0=f32 store, 1=bf16 store, 2=bias+f32, 3=bias+bf16
template<int EPI>
__global__ __launch_bounds__(256)
void sp_gemm_bf16(const u16* __restrict__ A, const u16* __restrict__ Bm,
                  void* __restrict__ Cv, const float* __restrict__ bias,
                  int M, int N, int Kd, int nbx,
                  const float* __restrict__ S, float* __restrict__ Snew,
                  float* __restrict__ mean, int stripeKind,
                  int nS, int total, int batch0) {
  int sid, cid;
  if (stripe_take(blockIdx.x, nS, total, sid, cid)) {
    if (stripeKind == 1) mean_batch(S, mean, batch0 + sid);
    else                 copy_batch(S, Snew, batch0 + sid);
    return;
  }
  __shared__ u16 lA[128 * 32];
  __shared__ u16 lB[128 * 32];
  int wg = cid;
  {
    const int nwg = nbx * ((M + 127) >> 7);
    const int cpx = nwg >> 3;               // nwg % 8 == 0 for all our shapes
    wg = (wg & 7) * cpx + (wg >> 3);
  }
  const int m0 = (wg / nbx) * 128, n0 = (wg % nbx) * 128;
  const int t = threadIdx.x;
  const int lane = t & 63;
  const int w = t >> 6;
  const int wm = w >> 1, wn = w & 1;

  f32x4 acc[4][4] = {};

  const int srow = t >> 2;
  const int scol = (t & 3) * 8;
  const u16* gA0 = A + (size_t)(m0 + srow) * Kd + scol;
  const u16* gA1 = A + (size_t)(m0 + 64 + srow) * Kd + scol;
  const u16* gB0 = Bm + (size_t)(n0 + srow) * Kd + scol;
  const u16* gB1 = Bm + (size_t)(n0 + 64 + srow) * Kd + scol;
  u16* lAw = &lA[(t & 192) * 8];
  u16* lBw = &lB[(t & 192) * 8];

  const int kb = (lane >> 4) * 8;
  const int rA = wm * 64 + (lane & 15);
  const int rB = wn * 64 + (lane & 15);

  for (int k0 = 0; k0 < Kd; k0 += 32) {
    __builtin_amdgcn_global_load_lds(AS1C(gA0 + k0), AS3(lAw), 16, 0, 0);
    __builtin_amdgcn_global_load_lds(AS1C(gA1 + k0), AS3(lAw + 2048), 16, 0, 0);
    __builtin_amdgcn_global_load_lds(AS1C(gB0 + k0), AS3(lBw), 16, 0, 0);
    __builtin_amdgcn_global_load_lds(AS1C(gB1 + k0), AS3(lBw + 2048), 16, 0, 0);
    __syncthreads();
    bf16x8 af[4], bfr[4];
    #pragma unroll
    for (int fm = 0; fm < 4; ++fm)
      af[fm] = *(const bf16x8*)&lA[(rA + fm * 16) * 32 + kb];
    #pragma unroll
    for (int fn = 0; fn < 4; ++fn)
      bfr[fn] = *(const bf16x8*)&lB[(rB + fn * 16) * 32 + kb];
    #pragma unroll
    for (int fm = 0; fm < 4; ++fm) {
      #pragma unroll
      for (int fn = 0; fn < 4; ++fn)
        acc[fm][fn] = __builtin_amdgcn_mfma_f32_16x16x32_bf16(af[fm], bfr[fn], acc[fm][fn], 0, 0, 0);
    }
    __syncthreads();
  }

  #pragma unroll
  for (int fm = 0; fm < 4; ++fm) {
    #pragma unroll
    for (int fn = 0; fn < 4; ++fn) {
      #pragma unroll
      for (int i = 0; i < 4; ++i) {
        const int r = m0 + wm * 64 + fm * 16 + (lane >> 4) * 4 + i;
        const int c = n0 + wn * 64 + fn * 16 + (lane & 15);
        float v = acc[fm][fn][i];
        if constexpr (EPI >= 2) v += bias[c];
        if constexpr (EPI == 0 || EPI == 2)
          ((float*)Cv)[(size_t)r * N + c] = v;
        else
          ((u16*)Cv)[(size_t)r * N + c] = f2bf(v);
      }
    }
  }
}

// ---------------- fused GRU elementwise + weighted mix (writes upd) ----------------
__global__ __launch_bounds__(256)
void sp_gru(const float* __restrict__ gi, const u16* __restrict__ gh,
            const float* __restrict__ S, const int* __restrict__ tki,
            const float* __restrict__ tkw, const float* __restrict__ bih,
            const float* __restrict__ bhh, float* __restrict__ upd,
            u16* __restrict__ umix) {
  const int b = blockIdx.x, t = threadIdx.x;
  const int d0 = t * 4;
  float Gr[4], Gz[4], Gn[4], Hr[4], Hz[4], Hn[4], Um[4] = {0.f, 0.f, 0.f, 0.f};
  {
    const size_t gb = (size_t)b * G3_;
    float4 a, c;
    a = *(const float4*)&gi[gb + d0];          c = *(const float4*)&bih[d0];
    Gr[0]=a.x+c.x; Gr[1]=a.y+c.y; Gr[2]=a.z+c.z; Gr[3]=a.w+c.w;
    a = *(const float4*)&gi[gb + D_ + d0];     c = *(const float4*)&bih[D_ + d0];
    Gz[0]=a.x+c.x; Gz[1]=a.y+c.y; Gz[2]=a.z+c.z; Gz[3]=a.w+c.w;
    a = *(const float4*)&gi[gb + 2 * D_ + d0]; c = *(const float4*)&bih[2 * D_ + d0];
    Gn[0]=a.x+c.x; Gn[1]=a.y+c.y; Gn[2]=a.z+c.z; Gn[3]=a.w+c.w;
    c = *(const float4*)&bhh[d0];          Hr[0]=c.x; Hr[1]=c.y; Hr[2]=c.z; Hr[3]=c.w;
    c = *(const float4*)&bhh[D_ + d0];     Hz[0]=c.x; Hz[1]=c.y; Hz[2]=c.z; Hz[3]=c.w;
    c = *(const float4*)&bhh[2 * D_ + d0]; Hn[0]=c.x; Hn[1]=c.y; Hn[2]=c.z; Hn[3]=c.w;
  }
  #pragma unroll
  for (int k = 0; k < K_; ++k) {
    const int s = tki[b * K_ + k];
    const float wk = tkw[b * K_ + k];
    const float4 sl = *(const float4*)&S[((size_t)b * NS_ + s) * D_ + d0];
    const u16* ghp = gh + ((size_t)b * K_ + k) * G3_ + d0;
    ushort4 r4 = *(const ushort4*)(ghp);
    ushort4 z4 = *(const ushort4*)(ghp + D_);
    ushort4 n4 = *(const ushort4*)(ghp + 2 * D_);
    float slc[4] = { sl.x, sl.y, sl.z, sl.w };
    u16 rr[4] = { r4.x, r4.y, r4.z, r4.w };
    u16 zz[4] = { z4.x, z4.y, z4.z, z4.w };
    u16 nn[4] = { n4.x, n4.y, n4.z, n4.w };
    float uv[4];
    #pragma unroll
    for (int j = 0; j < 4; ++j) {
      float rg = 1.f / (1.f + expf(-(Gr[j] + bf2f(rr[j]) + Hr[j])));
      float zg = 1.f / (1.f + expf(-(Gz[j] + bf2f(zz[j]) + Hz[j])));
      float ng = tanhf(Gn[j] + rg * (bf2f(nn[j]) + Hn[j]));
      uv[j] = (1.f - zg) * ng + zg * slc[j];
      Um[j] += wk * uv[j];
    }
    float4 o; o.x = uv[0]; o.y = uv[1]; o.z = uv[2]; o.w = uv[3];
    *(float4*)&upd[((size_t)b * K_ + k) * D_ + d0] = o;
  }
  ushort4 um;
  um.x = f2bf(Um[0]); um.y = f2bf(Um[1]); um.z = f2bf(Um[2]); um.w = f2bf(Um[3]);
  *(ushort4*)&umix[(size_t)b * D_ + d0] = um;
}

// ---------------- final scatter: Snew[b, tki[b,k], :] = upd[b,k,:] ----------------
__global__ __launch_bounds__(256)
void sp_scatter(const float* __restrict__ upd, const int* __restrict__ tki,
                float* __restrict__ Snew) {
  const int b = blockIdx.x, t = threadIdx.x;
  const int d0 = t * 4;
  #pragma unroll
  for (int k = 0; k < K_; ++k) {
    const int s = tki[b * K_ + k];
    float4 v = *(const float4*)&upd[((size_t)b * K_ + k) * D_ + d0];
    *(float4*)&Snew[((size_t)b * NS_ + s) * D_ + d0] = v;
  }
}

// ---------------- variant B: copy S->S_new with scatter of updated rows ----------------
__global__ __launch_bounds__(256)
void sp_copy_scatter(const float* __restrict__ S, const float* __restrict__ upd,
                     const int* __restrict__ tki, float* __restrict__ Snew) {
  const int b = blockIdx.x, t = threadIdx.x;
  const int d0 = t * 4;
  int idx[K_];
  #pragma unroll
  for (int k = 0; k < K_; ++k) idx[k] = tki[b * K_ + k];
  for (int s = 0; s < NS_; ++s) {
    int sk = -1;
    #pragma unroll
    for (int k = 0; k < K_; ++k) if (idx[k] == s) sk = k;
    float4 v;
    if (sk >= 0) v = *(const float4*)&upd[((size_t)b * K_ + sk) * D_ + d0];
    else         v = *(const float4*)&S[((size_t)b * NS_ + s) * D_ + d0];
    *(float4*)&Snew[((size_t)b * NS_ + s) * D_ + d0] = v;
  }
}

extern "C" void kernel_launch(void* const* d_in, const int* in_sizes, int n_in,
                              void* d_out, int out_size, void* d_ws, size_t ws_size,
                              hipStream_t stream) {
  const float* x    = (const float*)d_in[0];
  const float* S    = (const float*)d_in[1];
  const float* w1   = (const float*)d_in[2];
  const float* b1   = (const float*)d_in[3];
  const float* w2   = (const float*)d_in[4];
  const float* b2   = (const float*)d_in[5];
  const float* wih  = (const float*)d_in[6];
  const float* whh  = (const float*)d_in[7];
  const float* bih  = (const float*)d_in[8];
  const float* bhh  = (const float*)d_in[9];
  const float* wval = (const float*)d_in[10];
  const float* bval = (const float*)d_in[11];
  const float* wout = (const float*)d_in[12];
  const float* bout = (const float*)d_in[13];
  const float* tau  = (const float*)d_in[14];

  float* out  = (float*)d_out;
  float* Snew = out + (size_t)B_ * D_;

  const bool bigws = ws_size >= (size_t)400 * 1024 * 1024;
  char* bigbase = bigws ? (char*)d_ws : (char*)Snew;  // variant B: scratch in S_new region
  size_t bo = 0;
  auto balloc = [&](size_t bytes) -> void* {
    void* p = bigbase + bo; bo += (bytes + 255) & ~(size_t)255; return p;
  };

  float* mean  = (float*)balloc((size_t)B_ * D_ * 4);
  float* hpart = (float*)balloc((size_t)B_ * DH_ * 4);
  float* h     = (float*)balloc((size_t)B_ * DH_ * 4);
  u16* xb      = (u16*)balloc((size_t)B_ * D_ * 2);
  u16* wihb    = (u16*)balloc((size_t)G3_ * D_ * 2);
  u16* whhb    = (u16*)balloc((size_t)G3_ * D_ * 2);
  u16* wvalb   = (u16*)balloc((size_t)D_ * D_ * 2);
  u16* woutb   = (u16*)balloc((size_t)D_ * D_ * 2);
  float* gi    = (float*)balloc((size_t)B_ * G3_ * 4);
  u16* slotb   = (u16*)balloc((size_t)B_ * K_ * D_ * 2);
  u16* ghb     = (u16*)balloc((size_t)B_ * K_ * G3_ * 2);
  u16* umixb   = (u16*)balloc((size_t)B_ * D_ * 2);
  u16* mixedb  = (u16*)balloc((size_t)B_ * D_ * 2);

  // small buffers always live in d_ws
  char* wsb = (char*)d_ws;
  size_t so = bigws ? bo : 0;
  auto salloc = [&](size_t bytes) -> void* {
    void* p = wsb + so; so += (bytes + 255) & ~(size_t)255; return p;
  };
  int*   tki = (int*)salloc((size_t)B_ * K_ * 4);
  float* tkw = (float*)salloc((size_t)B_ * K_ * 4);
  float* upd = (float*)salloc((size_t)B_ * K_ * D_ * 4);

  if (bigws) {
    // Mean stripes cover batches 0..1299; fused copy+mean covers 1300..2047;
    // copy stripes (post-mean kernels) cover batches 0..1299.
    const int mCv = 300, mG1 = 500, mGi = 500;              // mean stripes
    const int cG1b = 250, cGa = 200, cGh = 700, cR1 = 75, cR2 = 75;  // copy stripes

    // 1. converts + mean stripes [0..300)
    sp_convert_all<<<1024 + mCv, 256, 0, stream>>>(
        x, wih, whh, wval, wout, xb, wihb, whhb, wvalb, woutb,
        S, mean, mCv, 1024 + mCv, 0);

    // 2. x-half of routing GEMM + mean stripes [300..800)
    sp_gemm1<0><<<512 + mG1, 256, 0, stream>>>(
        x, w1, b1, hpart, h, S, Snew, mean, mG1, 512 + mG1, 300);

    // 3. gi = x @ wih^T + mean stripes [800..1300)
    sp_gemm_bf16<0><<<384 + mGi, 256, 0, stream>>>(
        xb, wihb, gi, nullptr, B_, G3_, D_, G3_ / 128,
        S, Snew, mean, 1, mGi, 384 + mGi, 800);

    // 4. fused copy+mean remainder, batches [1300..2048)
    sp_copymean<1><<<748, 256, 0, stream>>>(S, Snew, mean, 1300);

    // 5. mean-half of routing GEMM + gelu + copy stripes [0..250)
    sp_gemm1<1><<<512 + cG1b, 256, 0, stream>>>(
        mean, w1, b1, hpart, h, S, Snew, mean, cG1b, 512 + cG1b, 0);

    // 6. logits + top-8 + softmax
    sp_route_topk<<<B_, 64, 0, stream>>>(h, w2, b2, tau, tki, tkw);

    // 7. gather + copy stripes [250..450)
    sp_gather<<<B_ * K_ + cGa, 256, 0, stream>>>(
        S, tki, slotb, Snew, cGa, B_ * K_ + cGa, 250);

    // 8. gh GEMM + copy stripes [450..1150)
    sp_gemm_bf16<1><<<3072 + cGh, 256, 0, stream>>>(
        slotb, whhb, ghb, nullptr, B_ * K_, G3_, D_, G3_ / 128,
        S, Snew, mean, 2, cGh, 3072 + cGh, 450);

    // 9. GRU elementwise + weighted mix (writes upd, no scatter)
    sp_gru<<<B_, 256, 0, stream>>>(gi, ghb, S, tki, tkw, bih, bhh, upd, umixb);

    // 10. readout GEMMs + copy stripes [1150..1225), [1225..1300)
    sp_gemm_bf16<3><<<128 + cR1, 256, 0, stream>>>(
        umixb, wvalb, mixedb, bval, B_, D_, D_, D_ / 128,
        S, Snew, mean, 2, cR1, 128 + cR1, 1150);
    sp_gemm_bf16<2><<<128 + cR2, 256, 0, stream>>>(
        mixedb, woutb, out, bout, B_, D_, D_, D_ / 128,
        S, Snew, mean, 2, cR2, 128 + cR2, 1225);

    // 11. final scatter of updated rows
    sp_scatter<<<B_, 256, 0, stream>>>(upd, tki, Snew);
  } else {
    // Variant B (small ws): serial, scratch in Snew region, merge-copy last.
    sp_copymean<0><<<B_, 256, 0, stream>>>(S, Snew, mean, 0);
    sp_convert_all<<<1024, 256, 0, stream>>>(
        x, wih, whh, wval, wout, xb, wihb, whhb, wvalb, woutb,
        S, mean, 0, 1024, 0);
    sp_gemm1<0><<<512, 256, 0, stream>>>(x, w1, b1, hpart, h, S, Snew, mean, 0, 512, 0);
    sp_gemm1<1><<<512, 256, 0, stream>>>(mean, w1, b1, hpart, h, S, Snew, mean, 0, 512, 0);
    sp_route_topk<<<B_, 64, 0, stream>>>(h, w2, b2, tau, tki, tkw);
    sp_gather<<<B_ * K_, 256, 0, stream>>>(S, tki, slotb, Snew, 0, B_ * K_, 0);
    sp_gemm_bf16<0><<<384, 256, 0, stream>>>(
        xb, wihb, gi, nullptr, B_, G3_, D_, G3_ / 128, S, Snew, mean, 0, 0, 384, 0);
    sp_gemm_bf16<1><<<3072, 256, 0, stream>>>(
        slotb, whhb, ghb, nullptr, B_ * K_, G3_, D_, G3_ / 128, S, Snew, mean, 0, 0, 3072, 0);
    sp_gru<<<B_, 256, 0, stream>>>(gi, ghb, S, tki, tkw, bih, bhh, upd, umixb);
    sp_gemm_bf16<3><<<128, 256, 0, stream>>>(
        umixb, wvalb, mixedb, bval, B_, D_, D_, D_ / 128, S, Snew, mean, 0, 0, 128, 0);
    sp_gemm_bf16<2><<<128, 256, 0, stream>>>(
        mixedb, woutb, out, bout, B_, D_, D_, D_ / 128, S, Snew, mean, 0, 0, 128, 0);
    sp_copy_scatter<<<B_, 256, 0, stream>>>(S, upd, tki, Snew);
  }
}

// Round 4
// 897.154 us; speedup vs baseline: 1.3099x; 1.3099x over previous
//
#include <hip/hip_runtime.h>
#include <math.h>
#include <stdint.h>

#define B_   2048
#define NS_  128
#define D_   1024
#define K_   8
#define DH_  512
#define G3_  3072

typedef unsigned short u16;
typedef short bf16x8 __attribute__((ext_vector_type(8)));
typedef float f32x4 __attribute__((ext_vector_type(4)));

__device__ __forceinline__ float bf2f(u16 u) {
  union { unsigned i; float f; } v; v.i = ((unsigned)u) << 16; return v.f;
}
__device__ __forceinline__ u16 f2bf(float f) {
  unsigned x = __float_as_uint(f);
  return (u16)((x + 0x7fffu + ((x >> 16) & 1u)) >> 16);
}

#define AS1C(p) ((const __attribute__((address_space(1))) void*)(uintptr_t)(p))
#define AS3(p)  ((__attribute__((address_space(3))) void*)(unsigned)(uintptr_t)(p))

// ---------------- fused S->Snew copy + slot mean (f64 accum, NT streams) ----------------
template<int DO_COPY>
__global__ __launch_bounds__(256)
void sp_copymean(const float* __restrict__ S, float* __restrict__ Snew,
                 float* __restrict__ mean) {
  const int b = blockIdx.x;
  const int t = threadIdx.x, d0 = t * 4;
  const f32x4* src = (const f32x4*)(S + (size_t)b * NS_ * D_) + t;
  f32x4* dst = (f32x4*)(Snew + (size_t)b * NS_ * D_) + t;
  double a0 = 0, a1 = 0, a2 = 0, a3 = 0;
  #pragma unroll 4
  for (int s = 0; s < NS_; ++s) {
    f32x4 v = __builtin_nontemporal_load(src);
    if (DO_COPY) __builtin_nontemporal_store(v, dst);
    a0 += v[0]; a1 += v[1]; a2 += v[2]; a3 += v[3];
    src += 256; dst += 256;
  }
  float4 m;
  m.x = (float)(a0 * (1.0 / 128.0)); m.y = (float)(a1 * (1.0 / 128.0));
  m.z = (float)(a2 * (1.0 / 128.0)); m.w = (float)(a3 * (1.0 / 128.0));
  *(float4*)&mean[(size_t)b * D_ + d0] = m;
}

// ---------------- fused f32 -> bf16 conversions (x, wih, whh, wval, wout) ----------------
__global__ __launch_bounds__(256)
void sp_convert_all(const float* __restrict__ x, const float* __restrict__ wih,
                    const float* __restrict__ whh, const float* __restrict__ wval,
                    const float* __restrict__ wout,
                    u16* __restrict__ xb, u16* __restrict__ wihb,
                    u16* __restrict__ whhb, u16* __restrict__ wvalb,
                    u16* __restrict__ woutb) {
  const int stride = gridDim.x * 256;
  for (int i = blockIdx.x * 256 + threadIdx.x; i < 2621440; i += stride) {
    const float* s; u16* d; int off;
    if (i < 524288)       { s = x;    d = xb;    off = i; }
    else if (i < 1310720) { s = wih;  d = wihb;  off = i - 524288; }
    else if (i < 2097152) { s = whh;  d = whhb;  off = i - 1310720; }
    else if (i < 2359296) { s = wval; d = wvalb; off = i - 2097152; }
    else                  { s = wout; d = woutb; off = i - 2359296; }
    float4 v = ((const float4*)s)[off];
    ushort4 o;
    o.x = f2bf(v.x); o.y = f2bf(v.y); o.z = f2bf(v.z); o.w = f2bf(v.w);
    ((ushort4*)d)[off] = o;
  }
}

// ---------------- routing GEMM1: h = gelu(ctx @ w1^T + b1), f32 FMA accum ----------------
// ctx = [x | mean], M=2048, N=512, K=2048. BM=64 BN=32 BK=16.
__global__ __launch_bounds__(256)
void sp_gemm1(const float* __restrict__ x, const float* __restrict__ mean,
              const float* __restrict__ w1, const float* __restrict__ bias1,
              float* __restrict__ h) {
  __shared__ float As[16][68];
  __shared__ float Bs[16][36];
  int wg = blockIdx.x;
  wg = (wg & 7) * 64 + (wg >> 3);          // bijective XCD swizzle, 512 wgs
  const int n0 = (wg & 15) * 32;           // nbx = 16
  const int m0 = (wg >> 4) * 64;
  const int t = threadIdx.x;
  const int tx = t & 15, ty = t >> 4;
  float acc[4][2] = {};
  const int sr = t >> 2, sc = (t & 3) * 4;
  for (int k0 = 0; k0 < 2 * D_; k0 += 16) {
    const float* src = (k0 < D_) ? (x + k0) : (mean + (k0 - D_));
    float4 va = *(const float4*)&src[(size_t)(m0 + sr) * D_ + sc];
    As[sc + 0][sr] = va.x; As[sc + 1][sr] = va.y; As[sc + 2][sr] = va.z; As[sc + 3][sr] = va.w;
    if (t < 128) {
      const int bn = t >> 2, bc = (t & 3) * 4;
      float4 vb = *(const float4*)&w1[(size_t)(n0 + bn) * (2 * D_) + k0 + bc];
      Bs[bc + 0][bn] = vb.x; Bs[bc + 1][bn] = vb.y; Bs[bc + 2][bn] = vb.z; Bs[bc + 3][bn] = vb.w;
    }
    __syncthreads();
    #pragma unroll
    for (int kk = 0; kk < 16; ++kk) {
      float4 a = *(const float4*)&As[kk][ty * 4];
      float2 bb = *(const float2*)&Bs[kk][tx * 2];
      acc[0][0] = fmaf(a.x, bb.x, acc[0][0]); acc[0][1] = fmaf(a.x, bb.y, acc[0][1]);
      acc[1][0] = fmaf(a.y, bb.x, acc[1][0]); acc[1][1] = fmaf(a.y, bb.y, acc[1][1]);
      acc[2][0] = fmaf(a.z, bb.x, acc[2][0]); acc[2][1] = fmaf(a.z, bb.y, acc[2][1]);
      acc[3][0] = fmaf(a.w, bb.x, acc[3][0]); acc[3][1] = fmaf(a.w, bb.y, acc[3][1]);
    }
    __syncthreads();
  }
  #pragma unroll
  for (int i = 0; i < 4; ++i) {
    #pragma unroll
    for (int j = 0; j < 2; ++j) {
      const int r = m0 + ty * 4 + i, c = n0 + tx * 2 + j;
      float v = acc[i][j] + bias1[c];
      v = 0.5f * v * (1.0f + erff(v * 0.70710678118654752f));
      h[(size_t)r * DH_ + c] = v;
    }
  }
}

// ---------------- logits + top-8 + softmax (one wave per row, f64 dot) ----------------
__global__ __launch_bounds__(64)
void sp_route_topk(const float* __restrict__ h, const float* __restrict__ w2,
                   const float* __restrict__ b2, const float* __restrict__ tau,
                   int* __restrict__ tki, float* __restrict__ tkw) {
  __shared__ float hs[DH_];
  const int b = blockIdx.x, l = threadIdx.x;
  *(float4*)&hs[l * 4] = *(const float4*)&h[(size_t)b * DH_ + l * 4];
  *(float4*)&hs[256 + l * 4] = *(const float4*)&h[(size_t)b * DH_ + 256 + l * 4];
  __syncthreads();
  const double invd = 1.0 / ((double)fabsf(tau[0]) + 0.1);
  float v[2]; int id[2];
  #pragma unroll
  for (int c = 0; c < 2; ++c) {
    const int n = c * 64 + l;
    const float* wr = &w2[(size_t)n * DH_];
    double s = 0.0;
    for (int j = 0; j < DH_; j += 4) {
      float4 w4 = *(const float4*)&wr[j];
      s += (double)hs[j] * (double)w4.x;
      s += (double)hs[j + 1] * (double)w4.y;
      s += (double)hs[j + 2] * (double)w4.z;
      s += (double)hs[j + 3] * (double)w4.w;
    }
    v[c] = (float)((s + (double)b2[n]) * invd);
    id[c] = n;
  }
  float m0f = 0.f, sum = 0.f, mye = 0.f; int myi = 0;
  for (int r = 0; r < 8; ++r) {
    float mv; int mi;
    if (v[1] > v[0]) { mv = v[1]; mi = id[1]; } else { mv = v[0]; mi = id[0]; }
    #pragma unroll
    for (int off = 32; off > 0; off >>= 1) {
      float ov = __shfl_xor(mv, off);
      int oi = __shfl_xor(mi, off);
      if (ov > mv || (ov == mv && oi < mi)) { mv = ov; mi = oi; }
    }
    if (r == 0) m0f = mv;
    float er = expf(mv - m0f);
    sum += er;
    if (l == r) { mye = er; myi = mi; }
    if (mi == id[0]) v[0] = -3.0e38f;
    if (mi == id[1]) v[1] = -3.0e38f;
  }
  if (l < 8) { tki[b * K_ + l] = myi; tkw[b * K_ + l] = mye / sum; }
}

// ---------------- gather selected slot rows -> bf16 ----------------
__global__ __launch_bounds__(256)
void sp_gather(const float* __restrict__ S, const int* __restrict__ tki,
               u16* __restrict__ slotb) {
  const int blk = blockIdx.x;
  const int b = blk >> 3, k = blk & 7;
  const int s = tki[b * K_ + k];
  const int t = threadIdx.x;
  float4 v = *(const float4*)&S[((size_t)b * NS_ + s) * D_ + t * 4];
  ushort4 o;
  o.x = f2bf(v.x); o.y = f2bf(v.y); o.z = f2bf(v.z); o.w = f2bf(v.w);
  *(ushort4*)&slotb[((size_t)b * K_ + k) * D_ + t * 4] = o;
}

// ---------------- bf16 TN MFMA GEMM: C[M,N] = A[M,K] * B[N,K]^T ----------------
// 128x128 tile, BK=32, 4 waves, 16x16x32 MFMA, global_load_lds, XCD swizzle.
// EPI: 0=f32 store, 1=bf16 store, 2=bias+f32, 3=bias+bf16
template<int EPI>
__global__ __launch_bounds__(256)
void sp_gemm_bf16(const u16* __restrict__ A, const u16* __restrict__ Bm,
                  void* __restrict__ Cv, const float* __restrict__ bias,
                  int M, int N, int Kd, int nbx) {
  __shared__ u16 lA[128 * 32];
  __shared__ u16 lB[128 * 32];
  int wg = blockIdx.x;
  {
    const int nwg = nbx * ((M + 127) >> 7);
    const int cpx = nwg >> 3;               // nwg % 8 == 0 for all our shapes
    wg = (wg & 7) * cpx + (wg >> 3);
  }
  const int m0 = (wg / nbx) * 128, n0 = (wg % nbx) * 128;
  const int t = threadIdx.x;
  const int lane = t & 63;
  const int w = t >> 6;
  const int wm = w >> 1, wn = w & 1;

  f32x4 acc[4][4] = {};

  const int srow = t >> 2;
  const int scol = (t & 3) * 8;
  const u16* gA0 = A + (size_t)(m0 + srow) * Kd + scol;
  const u16* gA1 = A + (size_t)(m0 + 64 + srow) * Kd + scol;
  const u16* gB0 = Bm + (size_t)(n0 + srow) * Kd + scol;
  const u16* gB1 = Bm + (size_t)(n0 + 64 + srow) * Kd + scol;
  u16* lAw = &lA[(t & 192) * 8];
  u16* lBw = &lB[(t & 192) * 8];

  const int kb = (lane >> 4) * 8;
  const int rA = wm * 64 + (lane & 15);
  const int rB = wn * 64 + (lane & 15);

  for (int k0 = 0; k0 < Kd; k0 += 32) {
    __builtin_amdgcn_global_load_lds(AS1C(gA0 + k0), AS3(lAw), 16, 0, 0);
    __builtin_amdgcn_global_load_lds(AS1C(gA1 + k0), AS3(lAw + 2048), 16, 0, 0);
    __builtin_amdgcn_global_load_lds(AS1C(gB0 + k0), AS3(lBw), 16, 0, 0);
    __builtin_amdgcn_global_load_lds(AS1C(gB1 + k0), AS3(lBw + 2048), 16, 0, 0);
    __syncthreads();
    bf16x8 af[4], bfr[4];
    #pragma unroll
    for (int fm = 0; fm < 4; ++fm)
      af[fm] = *(const bf16x8*)&lA[(rA + fm * 16) * 32 + kb];
    #pragma unroll
    for (int fn = 0; fn < 4; ++fn)
      bfr[fn] = *(const bf16x8*)&lB[(rB + fn * 16) * 32 + kb];
    #pragma unroll
    for (int fm = 0; fm < 4; ++fm) {
      #pragma unroll
      for (int fn = 0; fn < 4; ++fn)
        acc[fm][fn] = __builtin_amdgcn_mfma_f32_16x16x32_bf16(af[fm], bfr[fn], acc[fm][fn], 0, 0, 0);
    }
    __syncthreads();
  }

  #pragma unroll
  for (int fm = 0; fm < 4; ++fm) {
    #pragma unroll
    for (int fn = 0; fn < 4; ++fn) {
      #pragma unroll
      for (int i = 0; i < 4; ++i) {
        const int r = m0 + wm * 64 + fm * 16 + (lane >> 4) * 4 + i;
        const int c = n0 + wn * 64 + fn * 16 + (lane & 15);
        float v = acc[fm][fn][i];
        if constexpr (EPI >= 2) v += bias[c];
        if constexpr (EPI == 0 || EPI == 2)
          ((float*)Cv)[(size_t)r * N + c] = v;
        else
          ((u16*)Cv)[(size_t)r * N + c] = f2bf(v);
      }
    }
  }
}

// ---------------- fused GRU elementwise + scatter(direct) + weighted mix ----------------
template<bool DIRECT>
__global__ __launch_bounds__(256)
void sp_gru(const float* __restrict__ gi, const u16* __restrict__ gh,
            const float* __restrict__ S, const int* __restrict__ tki,
            const float* __restrict__ tkw, const float* __restrict__ bih,
            const float* __restrict__ bhh, float* __restrict__ dst,
            u16* __restrict__ umix) {
  const int b = blockIdx.x, t = threadIdx.x;
  const int d0 = t * 4;
  float Gr[4], Gz[4], Gn[4], Hr[4], Hz[4], Hn[4], Um[4] = {0.f, 0.f, 0.f, 0.f};
  {
    const size_t gb = (size_t)b * G3_;
    float4 a, c;
    a = *(const float4*)&gi[gb + d0];          c = *(const float4*)&bih[d0];
    Gr[0]=a.x+c.x; Gr[1]=a.y+c.y; Gr[2]=a.z+c.z; Gr[3]=a.w+c.w;
    a = *(const float4*)&gi[gb + D_ + d0];     c = *(const float4*)&bih[D_ + d0];
    Gz[0]=a.x+c.x; Gz[1]=a.y+c.y; Gz[2]=a.z+c.z; Gz[3]=a.w+c.w;
    a = *(const float4*)&gi[gb + 2 * D_ + d0]; c = *(const float4*)&bih[2 * D_ + d0];
    Gn[0]=a.x+c.x; Gn[1]=a.y+c.y; Gn[2]=a.z+c.z; Gn[3]=a.w+c.w;
    c = *(const float4*)&bhh[d0];          Hr[0]=c.x; Hr[1]=c.y; Hr[2]=c.z; Hr[3]=c.w;
    c = *(const float4*)&bhh[D_ + d0];     Hz[0]=c.x; Hz[1]=c.y; Hz[2]=c.z; Hz[3]=c.w;
    c = *(const float4*)&bhh[2 * D_ + d0]; Hn[0]=c.x; Hn[1]=c.y; Hn[2]=c.z; Hn[3]=c.w;
  }
  #pragma unroll
  for (int k = 0; k < K_; ++k) {
    const int s = tki[b * K_ + k];
    const float wk = tkw[b * K_ + k];
    const float4 sl = *(const float4*)&S[((size_t)b * NS_ + s) * D_ + d0];
    const u16* ghp = gh + ((size_t)b * K_ + k) * G3_ + d0;
    ushort4 r4 = *(const ushort4*)(ghp);
    ushort4 z4 = *(const ushort4*)(ghp + D_);
    ushort4 n4 = *(const ushort4*)(ghp + 2 * D_);
    float slc[4] = { sl.x, sl.y, sl.z, sl.w };
    u16 rr[4] = { r4.x, r4.y, r4.z, r4.w };
    u16 zz[4] = { z4.x, z4.y, z4.z, z4.w };
    u16 nn[4] = { n4.x, n4.y, n4.z, n4.w };
    float uv[4];
    #pragma unroll
    for (int j = 0; j < 4; ++j) {
      float rg = 1.f / (1.f + expf(-(Gr[j] + bf2f(rr[j]) + Hr[j])));
      float zg = 1.f / (1.f + expf(-(Gz[j] + bf2f(zz[j]) + Hz[j])));
      float ng = tanhf(Gn[j] + rg * (bf2f(nn[j]) + Hn[j]));
      uv[j] = (1.f - zg) * ng + zg * slc[j];
      Um[j] += wk * uv[j];
    }
    float4 o; o.x = uv[0]; o.y = uv[1]; o.z = uv[2]; o.w = uv[3];
    if (DIRECT)
      *(float4*)&dst[((size_t)b * NS_ + s) * D_ + d0] = o;
    else
      *(float4*)&dst[((size_t)b * K_ + k) * D_ + d0] = o;
  }
  ushort4 um;
  um.x = f2bf(Um[0]); um.y = f2bf(Um[1]); um.z = f2bf(Um[2]); um.w = f2bf(Um[3]);
  *(ushort4*)&umix[(size_t)b * D_ + d0] = um;
}

// ---------------- variant B: copy S->S_new with merge of updated rows ----------------
__global__ __launch_bounds__(256)
void sp_copy_scatter(const float* __restrict__ S, const float* __restrict__ upd,
                     const int* __restrict__ tki, float* __restrict__ Snew) {
  const int b = blockIdx.x, t = threadIdx.x;
  const int d0 = t * 4;
  int idx[K_];
  #pragma unroll
  for (int k = 0; k < K_; ++k) idx[k] = tki[b * K_ + k];
  for (int s = 0; s < NS_; ++s) {
    int sk = -1;
    #pragma unroll
    for (int k = 0; k < K_; ++k) if (idx[k] == s) sk = k;
    float4 v;
    if (sk >= 0) v = *(const float4*)&upd[((size_t)b * K_ + sk) * D_ + d0];
    else         v = *(const float4*)&S[((size_t)b * NS_ + s) * D_ + d0];
    *(float4*)&Snew[((size_t)b * NS_ + s) * D_ + d0] = v;
  }
}

extern "C" void kernel_launch(void* const* d_in, const int* in_sizes, int n_in,
                              void* d_out, int out_size, void* d_ws, size_t ws_size,
                              hipStream_t stream) {
  const float* x    = (const float*)d_in[0];
  const float* S    = (const float*)d_in[1];
  const float* w1   = (const float*)d_in[2];
  const float* b1   = (const float*)d_in[3];
  const float* w2   = (const float*)d_in[4];
  const float* b2   = (const float*)d_in[5];
  const float* wih  = (const float*)d_in[6];
  const float* whh  = (const float*)d_in[7];
  const float* bih  = (const float*)d_in[8];
  const float* bhh  = (const float*)d_in[9];
  const float* wval = (const float*)d_in[10];
  const float* bval = (const float*)d_in[11];
  const float* wout = (const float*)d_in[12];
  const float* bout = (const float*)d_in[13];
  const float* tau  = (const float*)d_in[14];

  float* out  = (float*)d_out;
  float* Snew = out + (size_t)B_ * D_;

  const bool bigws = ws_size >= (size_t)400 * 1024 * 1024;
  char* bigbase = bigws ? (char*)d_ws : (char*)Snew;  // variant B: scratch in S_new region
  size_t bo = 0;
  auto balloc = [&](size_t bytes) -> void* {
    void* p = bigbase + bo; bo += (bytes + 255) & ~(size_t)255; return p;
  };

  float* mean  = (float*)balloc((size_t)B_ * D_ * 4);
  float* h     = (float*)balloc((size_t)B_ * DH_ * 4);
  u16* xb      = (u16*)balloc((size_t)B_ * D_ * 2);
  u16* wihb    = (u16*)balloc((size_t)G3_ * D_ * 2);
  u16* whhb    = (u16*)balloc((size_t)G3_ * D_ * 2);
  u16* wvalb   = (u16*)balloc((size_t)D_ * D_ * 2);
  u16* woutb   = (u16*)balloc((size_t)D_ * D_ * 2);
  float* gi    = (float*)balloc((size_t)B_ * G3_ * 4);
  u16* slotb   = (u16*)balloc((size_t)B_ * K_ * D_ * 2);
  u16* ghb     = (u16*)balloc((size_t)B_ * K_ * G3_ * 2);
  u16* umixb   = (u16*)balloc((size_t)B_ * D_ * 2);
  u16* mixedb  = (u16*)balloc((size_t)B_ * D_ * 2);

  // small buffers always live in d_ws
  char* wsb = (char*)d_ws;
  size_t so = bigws ? bo : 0;
  auto salloc = [&](size_t bytes) -> void* {
    void* p = wsb + so; so += (bytes + 255) & ~(size_t)255; return p;
  };
  int*   tki = (int*)salloc((size_t)B_ * K_ * 4);
  float* tkw = (float*)salloc((size_t)B_ * K_ * 4);
  float* upd = bigws ? nullptr : (float*)salloc((size_t)B_ * K_ * D_ * 4);

  // 1. fused copy + mean (variant B: mean only; Snew region is scratch there)
  if (bigws) sp_copymean<1><<<B_, 256, 0, stream>>>(S, Snew, mean);
  else       sp_copymean<0><<<B_, 256, 0, stream>>>(S, Snew, mean);

  // 2. bf16 conversions (fused)
  sp_convert_all<<<1024, 256, 0, stream>>>(x, wih, whh, wval, wout,
                                           xb, wihb, whhb, wvalb, woutb);

  // 3. routing MLP (f32 FMA) + top-k (f64 dot)
  sp_gemm1<<<512, 256, 0, stream>>>(x, mean, w1, b1, h);
  sp_route_topk<<<B_, 64, 0, stream>>>(h, w2, b2, tau, tki, tkw);

  // 4. gather selected slots -> bf16
  sp_gather<<<B_ * K_, 256, 0, stream>>>(S, tki, slotb);

  // 5. GRU input/hidden GEMMs (bf16 MFMA)
  sp_gemm_bf16<0><<<384, 256, 0, stream>>>(xb, wihb, gi, nullptr, B_, G3_, D_, G3_ / 128);
  sp_gemm_bf16<1><<<3072, 256, 0, stream>>>(slotb, whhb, ghb, nullptr, B_ * K_, G3_, D_, G3_ / 128);

  // 6. GRU elementwise + scatter + weighted mix
  if (bigws)
    sp_gru<true><<<B_, 256, 0, stream>>>(gi, ghb, S, tki, tkw, bih, bhh, Snew, umixb);
  else
    sp_gru<false><<<B_, 256, 0, stream>>>(gi, ghb, S, tki, tkw, bih, bhh, upd, umixb);

  // 7. readout: mixed = umix @ wval^T + bval ; out = mixed @ wout^T + bout
  sp_gemm_bf16<3><<<128, 256, 0, stream>>>(umixb, wvalb, mixedb, bval, B_, D_, D_, D_ / 128);
  sp_gemm_bf16<2><<<128, 256, 0, stream>>>(mixedb, woutb, out, bout, B_, D_, D_, D_ / 128);

  // 8. variant B: final copy+merge
  if (!bigws)
    sp_copy_scatter<<<B_, 256, 0, stream>>>(S, upd, tki, Snew);
}

// Round 5
// 866.340 us; speedup vs baseline: 1.3565x; 1.0356x over previous
//
#include <hip/hip_runtime.h>
#include <math.h>
#include <stdint.h>

#define B_   2048
#define NS_  128
#define D_   1024
#define K_   8
#define DH_  512
#define G3_  3072

typedef unsigned short u16;
typedef short bf16x8 __attribute__((ext_vector_type(8)));
typedef float f32x4 __attribute__((ext_vector_type(4)));

__device__ __forceinline__ float bf2f(u16 u) {
  union { unsigned i; float f; } v; v.i = ((unsigned)u) << 16; return v.f;
}
__device__ __forceinline__ u16 f2bf(float f) {
  unsigned x = __float_as_uint(f);
  return (u16)((x + 0x7fffu + ((x >> 16) & 1u)) >> 16);
}

#define AS1C(p) ((const __attribute__((address_space(1))) void*)(uintptr_t)(p))
#define AS3(p)  ((__attribute__((address_space(3))) void*)(unsigned)(uintptr_t)(p))

// ---------------- fused S->Snew copy + slot mean (f64 accum, NT streams) ----------------
template<int DO_COPY>
__global__ __launch_bounds__(256)
void sp_copymean(const float* __restrict__ S, float* __restrict__ Snew,
                 float* __restrict__ mean) {
  const int b = blockIdx.x;
  const int t = threadIdx.x, d0 = t * 4;
  const f32x4* src = (const f32x4*)(S + (size_t)b * NS_ * D_) + t;
  f32x4* dst = (f32x4*)(Snew + (size_t)b * NS_ * D_) + t;
  double a0 = 0, a1 = 0, a2 = 0, a3 = 0;
  #pragma unroll 4
  for (int s = 0; s < NS_; ++s) {
    f32x4 v = __builtin_nontemporal_load(src);
    if (DO_COPY) __builtin_nontemporal_store(v, dst);
    a0 += v[0]; a1 += v[1]; a2 += v[2]; a3 += v[3];
    src += 256; dst += 256;
  }
  float4 m;
  m.x = (float)(a0 * (1.0 / 128.0)); m.y = (float)(a1 * (1.0 / 128.0));
  m.z = (float)(a2 * (1.0 / 128.0)); m.w = (float)(a3 * (1.0 / 128.0));
  *(float4*)&mean[(size_t)b * D_ + d0] = m;
}

// ---------------- fused f32 -> bf16 conversions (x, wih, whh, wval, wout) ----------------
__global__ __launch_bounds__(256)
void sp_convert_all(const float* __restrict__ x, const float* __restrict__ wih,
                    const float* __restrict__ whh, const float* __restrict__ wval,
                    const float* __restrict__ wout,
                    u16* __restrict__ xb, u16* __restrict__ wihb,
                    u16* __restrict__ whhb, u16* __restrict__ wvalb,
                    u16* __restrict__ woutb) {
  const int stride = gridDim.x * 256;
  for (int i = blockIdx.x * 256 + threadIdx.x; i < 2621440; i += stride) {
    const float* s; u16* d; int off;
    if (i < 524288)       { s = x;    d = xb;    off = i; }
    else if (i < 1310720) { s = wih;  d = wihb;  off = i - 524288; }
    else if (i < 2097152) { s = whh;  d = whhb;  off = i - 1310720; }
    else if (i < 2359296) { s = wval; d = wvalb; off = i - 2097152; }
    else                  { s = wout; d = woutb; off = i - 2359296; }
    float4 v = ((const float4*)s)[off];
    ushort4 o;
    o.x = f2bf(v.x); o.y = f2bf(v.y); o.z = f2bf(v.z); o.w = f2bf(v.w);
    ((ushort4*)d)[off] = o;
  }
}

// ---------------- routing GEMM1: h = gelu(ctx @ w1^T + b1), f32 FMA accum ----------------
__global__ __launch_bounds__(256)
void sp_gemm1(const float* __restrict__ x, const float* __restrict__ mean,
              const float* __restrict__ w1, const float* __restrict__ bias1,
              float* __restrict__ h) {
  __shared__ float As[16][68];
  __shared__ float Bs[16][36];
  int wg = blockIdx.x;
  wg = (wg & 7) * 64 + (wg >> 3);          // bijective XCD swizzle, 512 wgs
  const int n0 = (wg & 15) * 32;           // nbx = 16
  const int m0 = (wg >> 4) * 64;
  const int t = threadIdx.x;
  const int tx = t & 15, ty = t >> 4;
  float acc[4][2] = {};
  const int sr = t >> 2, sc = (t & 3) * 4;
  for (int k0 = 0; k0 < 2 * D_; k0 += 16) {
    const float* src = (k0 < D_) ? (x + k0) : (mean + (k0 - D_));
    float4 va = *(const float4*)&src[(size_t)(m0 + sr) * D_ + sc];
    As[sc + 0][sr] = va.x; As[sc + 1][sr] = va.y; As[sc + 2][sr] = va.z; As[sc + 3][sr] = va.w;
    if (t < 128) {
      const int bn = t >> 2, bc = (t & 3) * 4;
      float4 vb = *(const float4*)&w1[(size_t)(n0 + bn) * (2 * D_) + k0 + bc];
      Bs[bc + 0][bn] = vb.x; Bs[bc + 1][bn] = vb.y; Bs[bc + 2][bn] = vb.z; Bs[bc + 3][bn] = vb.w;
    }
    __syncthreads();
    #pragma unroll
    for (int kk = 0; kk < 16; ++kk) {
      float4 a = *(const float4*)&As[kk][ty * 4];
      float2 bb = *(const float2*)&Bs[kk][tx * 2];
      acc[0][0] = fmaf(a.x, bb.x, acc[0][0]); acc[0][1] = fmaf(a.x, bb.y, acc[0][1]);
      acc[1][0] = fmaf(a.y, bb.x, acc[1][0]); acc[1][1] = fmaf(a.y, bb.y, acc[1][1]);
      acc[2][0] = fmaf(a.z, bb.x, acc[2][0]); acc[2][1] = fmaf(a.z, bb.y, acc[2][1]);
      acc[3][0] = fmaf(a.w, bb.x, acc[3][0]); acc[3][1] = fmaf(a.w, bb.y, acc[3][1]);
    }
    __syncthreads();
  }
  #pragma unroll
  for (int i = 0; i < 4; ++i) {
    #pragma unroll
    for (int j = 0; j < 2; ++j) {
      const int r = m0 + ty * 4 + i, c = n0 + tx * 2 + j;
      float v = acc[i][j] + bias1[c];
      v = 0.5f * v * (1.0f + erff(v * 0.70710678118654752f));
      h[(size_t)r * DH_ + c] = v;
    }
  }
}

// ---------------- logits + top-8 + softmax (one wave per row, f64 dot) ----------------
__global__ __launch_bounds__(64)
void sp_route_topk(const float* __restrict__ h, const float* __restrict__ w2,
                   const float* __restrict__ b2, const float* __restrict__ tau,
                   int* __restrict__ tki, float* __restrict__ tkw) {
  __shared__ float hs[DH_];
  const int b = blockIdx.x, l = threadIdx.x;
  *(float4*)&hs[l * 4] = *(const float4*)&h[(size_t)b * DH_ + l * 4];
  *(float4*)&hs[256 + l * 4] = *(const float4*)&h[(size_t)b * DH_ + 256 + l * 4];
  __syncthreads();
  const double invd = 1.0 / ((double)fabsf(tau[0]) + 0.1);
  float v[2]; int id[2];
  #pragma unroll
  for (int c = 0; c < 2; ++c) {
    const int n = c * 64 + l;
    const float* wr = &w2[(size_t)n * DH_];
    double s = 0.0;
    for (int j = 0; j < DH_; j += 4) {
      float4 w4 = *(const float4*)&wr[j];
      s += (double)hs[j] * (double)w4.x;
      s += (double)hs[j + 1] * (double)w4.y;
      s += (double)hs[j + 2] * (double)w4.z;
      s += (double)hs[j + 3] * (double)w4.w;
    }
    v[c] = (float)((s + (double)b2[n]) * invd);
    id[c] = n;
  }
  float m0f = 0.f, sum = 0.f, mye = 0.f; int myi = 0;
  for (int r = 0; r < 8; ++r) {
    float mv; int mi;
    if (v[1] > v[0]) { mv = v[1]; mi = id[1]; } else { mv = v[0]; mi = id[0]; }
    #pragma unroll
    for (int off = 32; off > 0; off >>= 1) {
      float ov = __shfl_xor(mv, off);
      int oi = __shfl_xor(mi, off);
      if (ov > mv || (ov == mv && oi < mi)) { mv = ov; mi = oi; }
    }
    if (r == 0) m0f = mv;
    float er = expf(mv - m0f);
    sum += er;
    if (l == r) { mye = er; myi = mi; }
    if (mi == id[0]) v[0] = -3.0e38f;
    if (mi == id[1]) v[1] = -3.0e38f;
  }
  if (l < 8) { tki[b * K_ + l] = myi; tkw[b * K_ + l] = mye / sum; }
}

// ---------------- gather selected slot rows -> bf16 ----------------
__global__ __launch_bounds__(256)
void sp_gather(const float* __restrict__ S, const int* __restrict__ tki,
               u16* __restrict__ slotb) {
  const int blk = blockIdx.x;
  const int b = blk >> 3, k = blk & 7;
  const int s = tki[b * K_ + k];
  const int t = threadIdx.x;
  float4 v = *(const float4*)&S[((size_t)b * NS_ + s) * D_ + t * 4];
  ushort4 o;
  o.x = f2bf(v.x); o.y = f2bf(v.y); o.z = f2bf(v.z); o.w = f2bf(v.w);
  *(ushort4*)&slotb[((size_t)b * K_ + k) * D_ + t * 4] = o;
}

// ---------------- plain bf16 TN MFMA GEMM (gi + readout) ----------------
// 128x128 tile, BK=32, 4 waves, 16x16x32 MFMA, global_load_lds, XCD swizzle.
// EPI: 0=f32 store, 1=bf16 store, 2=bias+f32, 3=bias+bf16
template<int EPI>
__global__ __launch_bounds__(256)
void sp_gemm_bf16(const u16* __restrict__ A, const u16* __restrict__ Bm,
                  void* __restrict__ Cv, const float* __restrict__ bias,
                  int M, int N, int Kd, int nbx) {
  __shared__ u16 lA[128 * 32];
  __shared__ u16 lB[128 * 32];
  int wg = blockIdx.x;
  {
    const int nwg = nbx * ((M + 127) >> 7);
    const int cpx = nwg >> 3;               // nwg % 8 == 0 for all our shapes
    wg = (wg & 7) * cpx + (wg >> 3);
  }
  const int m0 = (wg / nbx) * 128, n0 = (wg % nbx) * 128;
  const int t = threadIdx.x;
  const int lane = t & 63;
  const int w = t >> 6;
  const int wm = w >> 1, wn = w & 1;

  f32x4 acc[4][4] = {};

  const int srow = t >> 2;
  const int scol = (t & 3) * 8;
  const u16* gA0 = A + (size_t)(m0 + srow) * Kd + scol;
  const u16* gA1 = A + (size_t)(m0 + 64 + srow) * Kd + scol;
  const u16* gB0 = Bm + (size_t)(n0 + srow) * Kd + scol;
  const u16* gB1 = Bm + (size_t)(n0 + 64 + srow) * Kd + scol;
  u16* lAw = &lA[(t & 192) * 8];
  u16* lBw = &lB[(t & 192) * 8];

  const int kb = (lane >> 4) * 8;
  const int rA = wm * 64 + (lane & 15);
  const int rB = wn * 64 + (lane & 15);

  for (int k0 = 0; k0 < Kd; k0 += 32) {
    __builtin_amdgcn_global_load_lds(AS1C(gA0 + k0), AS3(lAw), 16, 0, 0);
    __builtin_amdgcn_global_load_lds(AS1C(gA1 + k0), AS3(lAw + 2048), 16, 0, 0);
    __builtin_amdgcn_global_load_lds(AS1C(gB0 + k0), AS3(lBw), 16, 0, 0);
    __builtin_amdgcn_global_load_lds(AS1C(gB1 + k0), AS3(lBw + 2048), 16, 0, 0);
    __syncthreads();
    bf16x8 af[4], bfr[4];
    #pragma unroll
    for (int fm = 0; fm < 4; ++fm)
      af[fm] = *(const bf16x8*)&lA[(rA + fm * 16) * 32 + kb];
    #pragma unroll
    for (int fn = 0; fn < 4; ++fn)
      bfr[fn] = *(const bf16x8*)&lB[(rB + fn * 16) * 32 + kb];
    #pragma unroll
    for (int fm = 0; fm < 4; ++fm) {
      #pragma unroll
      for (int fn = 0; fn < 4; ++fn)
        acc[fm][fn] = __builtin_amdgcn_mfma_f32_16x16x32_bf16(af[fm], bfr[fn], acc[fm][fn], 0, 0, 0);
    }
    __syncthreads();
  }

  #pragma unroll
  for (int fm = 0; fm < 4; ++fm) {
    #pragma unroll
    for (int fn = 0; fn < 4; ++fn) {
      #pragma unroll
      for (int i = 0; i < 4; ++i) {
        const int r = m0 + wm * 64 + fm * 16 + (lane >> 4) * 4 + i;
        const int c = n0 + wn * 64 + fn * 16 + (lane & 15);
        float v = acc[fm][fn][i];
        if constexpr (EPI >= 2) v += bias[c];
        if constexpr (EPI == 0 || EPI == 2)
          ((float*)Cv)[(size_t)r * N + c] = v;
        else
          ((u16*)Cv)[(size_t)r * N + c] = f2bf(v);
      }
    }
  }
}

// ---------------- fused gh GEMM + GRU elementwise + scatter + weighted mix ----------------
// Tile: 64 rows x (3 gates x 64 d-cols). 4 waves (2x2): wave = 32 rows x (3 x 32 cols).
// acc[fm(2)][fn(6)], fn = gate*2 + f. Epilogue computes GRU gates lane-locally,
// scatters updated rows into dst, and reduces umix via shfl_xor(16).
template<bool DIRECT>
__global__ __launch_bounds__(256)
void sp_gh_gru(const u16* __restrict__ slotb, const u16* __restrict__ whhb,
               const float* __restrict__ gi, const float* __restrict__ bih,
               const float* __restrict__ bhh, const int* __restrict__ tki,
               const float* __restrict__ tkw, float* __restrict__ dst,
               u16* __restrict__ umixb) {
  __shared__ u16 lA[64 * 32];
  __shared__ u16 lB[192 * 32];
  __shared__ int   sTki[64];
  __shared__ float sTkw[64];
  // grid = 4096 = 256 mtiles x 16 dblocks (db fast for slotb L2 reuse); XCD swizzle
  int wg = blockIdx.x;
  wg = (wg & 7) * 512 + (wg >> 3);
  const int mt = wg >> 4, db = wg & 15;
  const int m0 = mt * 64, d0 = db * 64;
  const int t = threadIdx.x;
  const int lane = t & 63, w = t >> 6;
  const int wm = w >> 1, wn = w & 1;
  const int lane15 = lane & 15, hi = lane >> 4;

  if (t < 64) { sTki[t] = tki[m0 + t]; sTkw[t] = tkw[m0 + t]; }

  f32x4 acc[2][6] = {};

  const int srow = t >> 2;
  const int scol = (t & 3) * 8;
  const u16* gA  = slotb + (size_t)(m0 + srow) * D_ + scol;
  const u16* gB0 = whhb + (size_t)(d0 + srow) * D_ + scol;
  const u16* gB1 = whhb + (size_t)(D_ + d0 + srow) * D_ + scol;
  const u16* gB2 = whhb + (size_t)(2 * D_ + d0 + srow) * D_ + scol;
  u16* lAw  = &lA[(t & 192) * 8];
  u16* lBw0 = &lB[(t & 192) * 8];

  const int kb = hi * 8;
  const int rA = wm * 32 + lane15;
  const int rB = wn * 32 + lane15;

  for (int k0 = 0; k0 < D_; k0 += 32) {
    __builtin_amdgcn_global_load_lds(AS1C(gA  + k0), AS3(lAw), 16, 0, 0);
    __builtin_amdgcn_global_load_lds(AS1C(gB0 + k0), AS3(lBw0), 16, 0, 0);
    __builtin_amdgcn_global_load_lds(AS1C(gB1 + k0), AS3(lBw0 + 2048), 16, 0, 0);
    __builtin_amdgcn_global_load_lds(AS1C(gB2 + k0), AS3(lBw0 + 4096), 16, 0, 0);
    __syncthreads();
    bf16x8 af[2], bfr[6];
    #pragma unroll
    for (int fm = 0; fm < 2; ++fm)
      af[fm] = *(const bf16x8*)&lA[(rA + fm * 16) * 32 + kb];
    #pragma unroll
    for (int g = 0; g < 3; ++g) {
      #pragma unroll
      for (int f = 0; f < 2; ++f)
        bfr[g * 2 + f] = *(const bf16x8*)&lB[(g * 64 + rB + f * 16) * 32 + kb];
    }
    #pragma unroll
    for (int fm = 0; fm < 2; ++fm) {
      #pragma unroll
      for (int fn = 0; fn < 6; ++fn)
        acc[fm][fn] = __builtin_amdgcn_mfma_f32_16x16x32_bf16(af[fm], bfr[fn], acc[fm][fn], 0, 0, 0);
    }
    __syncthreads();
  }

  // ---- GRU epilogue ----
  #pragma unroll
  for (int fm = 0; fm < 2; ++fm) {
    const int rbase = wm * 32 + fm * 16 + hi * 4;     // tile-local; 4 rows same batch
    const int bglob = (m0 + rbase) >> 3;
    #pragma unroll
    for (int f = 0; f < 2; ++f) {
      const int dg = d0 + wn * 32 + f * 16 + lane15;  // d within [0,1024)
      const float Gr = gi[(size_t)bglob * G3_ + dg]           + bih[dg];
      const float Gz = gi[(size_t)bglob * G3_ + D_ + dg]      + bih[D_ + dg];
      const float Gn = gi[(size_t)bglob * G3_ + 2 * D_ + dg]  + bih[2 * D_ + dg];
      const float Br = bhh[dg], Bz = bhh[D_ + dg], Bn = bhh[2 * D_ + dg];
      float part = 0.f;
      #pragma unroll
      for (int i = 0; i < 4; ++i) {
        const int row = rbase + i;
        const int grow = m0 + row;
        const float slot = bf2f(slotb[(size_t)grow * D_ + dg]);
        const float rr = acc[fm][f][i] + Br;
        const float zz = acc[fm][f + 2][i] + Bz;
        const float nn = acc[fm][f + 4][i] + Bn;
        const float rg = 1.f / (1.f + expf(-(Gr + rr)));
        const float zg = 1.f / (1.f + expf(-(Gz + zz)));
        const float ng = tanhf(Gn + rg * nn);
        const float uv = (1.f - zg) * ng + zg * slot;
        part = fmaf(sTkw[row], uv, part);
        if (DIRECT)
          dst[((size_t)bglob * NS_ + sTki[row]) * D_ + dg] = uv;
        else
          dst[(size_t)grow * D_ + dg] = uv;
      }
      part += __shfl_xor(part, 16);
      if ((hi & 1) == 0)
        umixb[(size_t)bglob * D_ + dg] = f2bf(part);
    }
  }
}

// ---------------- variant B: copy S->S_new with merge of updated rows ----------------
__global__ __launch_bounds__(256)
void sp_copy_scatter(const float* __restrict__ S, const float* __restrict__ upd,
                     const int* __restrict__ tki, float* __restrict__ Snew) {
  const int b = blockIdx.x, t = threadIdx.x;
  const int d0 = t * 4;
  int idx[K_];
  #pragma unroll
  for (int k = 0; k < K_; ++k) idx[k] = tki[b * K_ + k];
  for (int s = 0; s < NS_; ++s) {
    int sk = -1;
    #pragma unroll
    for (int k = 0; k < K_; ++k) if (idx[k] == s) sk = k;
    float4 v;
    if (sk >= 0) v = *(const float4*)&upd[((size_t)b * K_ + sk) * D_ + d0];
    else         v = *(const float4*)&S[((size_t)b * NS_ + s) * D_ + d0];
    *(float4*)&Snew[((size_t)b * NS_ + s) * D_ + d0] = v;
  }
}

extern "C" void kernel_launch(void* const* d_in, const int* in_sizes, int n_in,
                              void* d_out, int out_size, void* d_ws, size_t ws_size,
                              hipStream_t stream) {
  const float* x    = (const float*)d_in[0];
  const float* S    = (const float*)d_in[1];
  const float* w1   = (const float*)d_in[2];
  const float* b1   = (const float*)d_in[3];
  const float* w2   = (const float*)d_in[4];
  const float* b2   = (const float*)d_in[5];
  const float* wih  = (const float*)d_in[6];
  const float* whh  = (const float*)d_in[7];
  const float* bih  = (const float*)d_in[8];
  const float* bhh  = (const float*)d_in[9];
  const float* wval = (const float*)d_in[10];
  const float* bval = (const float*)d_in[11];
  const float* wout = (const float*)d_in[12];
  const float* bout = (const float*)d_in[13];
  const float* tau  = (const float*)d_in[14];

  float* out  = (float*)d_out;
  float* Snew = out + (size_t)B_ * D_;

  const bool bigws = ws_size >= (size_t)400 * 1024 * 1024;
  char* bigbase = bigws ? (char*)d_ws : (char*)Snew;  // variant B: scratch in S_new region
  size_t bo = 0;
  auto balloc = [&](size_t bytes) -> void* {
    void* p = bigbase + bo; bo += (bytes + 255) & ~(size_t)255; return p;
  };

  float* mean  = (float*)balloc((size_t)B_ * D_ * 4);
  float* h     = (float*)balloc((size_t)B_ * DH_ * 4);
  u16* xb      = (u16*)balloc((size_t)B_ * D_ * 2);
  u16* wihb    = (u16*)balloc((size_t)G3_ * D_ * 2);
  u16* whhb    = (u16*)balloc((size_t)G3_ * D_ * 2);
  u16* wvalb   = (u16*)balloc((size_t)D_ * D_ * 2);
  u16* woutb   = (u16*)balloc((size_t)D_ * D_ * 2);
  float* gi    = (float*)balloc((size_t)B_ * G3_ * 4);
  u16* slotb   = (u16*)balloc((size_t)B_ * K_ * D_ * 2);
  u16* umixb   = (u16*)balloc((size_t)B_ * D_ * 2);
  u16* mixedb  = (u16*)balloc((size_t)B_ * D_ * 2);

  // small buffers always live in d_ws
  char* wsb = (char*)d_ws;
  size_t so = bigws ? bo : 0;
  auto salloc = [&](size_t bytes) -> void* {
    void* p = wsb + so; so += (bytes + 255) & ~(size_t)255; return p;
  };
  int*   tki = (int*)salloc((size_t)B_ * K_ * 4);
  float* tkw = (float*)salloc((size_t)B_ * K_ * 4);
  float* upd = bigws ? nullptr : (float*)salloc((size_t)B_ * K_ * D_ * 4);

  // 1. fused copy + mean (variant B: mean only; Snew region is scratch there)
  if (bigws) sp_copymean<1><<<B_, 256, 0, stream>>>(S, Snew, mean);
  else       sp_copymean<0><<<B_, 256, 0, stream>>>(S, Snew, mean);

  // 2. bf16 conversions (fused)
  sp_convert_all<<<1024, 256, 0, stream>>>(x, wih, whh, wval, wout,
                                           xb, wihb, whhb, wvalb, woutb);

  // 3. routing MLP (f32 FMA) + top-k (f64 dot)
  sp_gemm1<<<512, 256, 0, stream>>>(x, mean, w1, b1, h);
  sp_route_topk<<<B_, 64, 0, stream>>>(h, w2, b2, tau, tki, tkw);

  // 4. gather selected slots -> bf16
  sp_gather<<<B_ * K_, 256, 0, stream>>>(S, tki, slotb);

  // 5. gi = x @ wih^T (bf16 MFMA)
  sp_gemm_bf16<0><<<384, 256, 0, stream>>>(xb, wihb, gi, nullptr, B_, G3_, D_, G3_ / 128);

  // 6. fused gh GEMM + GRU + scatter + weighted mix
  if (bigws)
    sp_gh_gru<true><<<4096, 256, 0, stream>>>(slotb, whhb, gi, bih, bhh,
                                              tki, tkw, Snew, umixb);
  else
    sp_gh_gru<false><<<4096, 256, 0, stream>>>(slotb, whhb, gi, bih, bhh,
                                               tki, tkw, upd, umixb);

  // 7. readout: mixed = umix @ wval^T + bval ; out = mixed @ wout^T + bout
  sp_gemm_bf16<3><<<128, 256, 0, stream>>>(umixb, wvalb, mixedb, bval, B_, D_, D_, D_ / 128);
  sp_gemm_bf16<2><<<128, 256, 0, stream>>>(mixedb, woutb, out, bout, B_, D_, D_, D_ / 128);

  // 8. variant B: final copy+merge
  if (!bigws)
    sp_copy_scatter<<<B_, 256, 0, stream>>>(S, upd, tki, Snew);
}

// Round 6
// 835.264 us; speedup vs baseline: 1.4069x; 1.0372x over previous
//
#include <hip/hip_runtime.h>
#include <math.h>
#include <stdint.h>

#define B_   2048
#define NS_  128
#define D_   1024
#define K_   8
#define DH_  512
#define G3_  3072

typedef unsigned short u16;
typedef short bf16x8 __attribute__((ext_vector_type(8)));
typedef float f32x4 __attribute__((ext_vector_type(4)));

__device__ __forceinline__ float bf2f(u16 u) {
  union { unsigned i; float f; } v; v.i = ((unsigned)u) << 16; return v.f;
}
__device__ __forceinline__ u16 f2bf(float f) {
  unsigned x = __float_as_uint(f);
  return (u16)((x + 0x7fffu + ((x >> 16) & 1u)) >> 16);
}

#define AS1C(p) ((const __attribute__((address_space(1))) void*)(uintptr_t)(p))
#define AS3(p)  ((__attribute__((address_space(3))) void*)(unsigned)(uintptr_t)(p))

// ---------------- fused S->Snew copy + slot mean (f64 accum, NT streams) ----------------
template<int DO_COPY>
__global__ __launch_bounds__(256)
void sp_copymean(const float* __restrict__ S, float* __restrict__ Snew,
                 float* __restrict__ mean) {
  const int b = blockIdx.x;
  const int t = threadIdx.x, d0 = t * 4;
  const f32x4* src = (const f32x4*)(S + (size_t)b * NS_ * D_) + t;
  f32x4* dst = (f32x4*)(Snew + (size_t)b * NS_ * D_) + t;
  double a0 = 0, a1 = 0, a2 = 0, a3 = 0;
  #pragma unroll 4
  for (int s = 0; s < NS_; ++s) {
    f32x4 v = __builtin_nontemporal_load(src);
    if (DO_COPY) __builtin_nontemporal_store(v, dst);
    a0 += v[0]; a1 += v[1]; a2 += v[2]; a3 += v[3];
    src += 256; dst += 256;
  }
  float4 m;
  m.x = (float)(a0 * (1.0 / 128.0)); m.y = (float)(a1 * (1.0 / 128.0));
  m.z = (float)(a2 * (1.0 / 128.0)); m.w = (float)(a3 * (1.0 / 128.0));
  *(float4*)&mean[(size_t)b * D_ + d0] = m;
}

// ---------------- fused f32 -> bf16 conversions (x, wih, whh, wout) ----------------
__global__ __launch_bounds__(256)
void sp_convert_all(const float* __restrict__ x, const float* __restrict__ wih,
                    const float* __restrict__ whh, const float* __restrict__ wout,
                    u16* __restrict__ xb, u16* __restrict__ wihb,
                    u16* __restrict__ whhb, u16* __restrict__ woutb) {
  const int stride = gridDim.x * 256;
  for (int i = blockIdx.x * 256 + threadIdx.x; i < 2359296; i += stride) {
    const float* s; u16* d; int off;
    if (i < 524288)       { s = x;    d = xb;    off = i; }
    else if (i < 1310720) { s = wih;  d = wihb;  off = i - 524288; }
    else if (i < 2097152) { s = whh;  d = whhb;  off = i - 1310720; }
    else                  { s = wout; d = woutb; off = i - 2097152; }
    float4 v = ((const float4*)s)[off];
    ushort4 o;
    o.x = f2bf(v.x); o.y = f2bf(v.y); o.z = f2bf(v.z); o.w = f2bf(v.w);
    ((ushort4*)d)[off] = o;
  }
}

// ---------------- wval f32 -> bf16 transposed (64x64 LDS tiles) ----------------
__global__ __launch_bounds__(256)
void sp_transpose_wval(const float* __restrict__ wval, u16* __restrict__ wvalT) {
  __shared__ u16 tile[64][65];
  const int bx = blockIdx.x & 15, by = blockIdx.x >> 4;
  const int t = threadIdx.x;
  const int r = t >> 4, c4 = (t & 15) * 4;
  #pragma unroll
  for (int p = 0; p < 4; ++p) {
    const int row = by * 64 + p * 16 + r;
    float4 v = *(const float4*)&wval[(size_t)row * D_ + bx * 64 + c4];
    tile[p * 16 + r][c4 + 0] = f2bf(v.x);
    tile[p * 16 + r][c4 + 1] = f2bf(v.y);
    tile[p * 16 + r][c4 + 2] = f2bf(v.z);
    tile[p * 16 + r][c4 + 3] = f2bf(v.w);
  }
  __syncthreads();
  #pragma unroll
  for (int p = 0; p < 4; ++p) {
    const int jr = p * 16 + r;
    ushort4 o;
    o.x = tile[c4 + 0][jr];
    o.y = tile[c4 + 1][jr];
    o.z = tile[c4 + 2][jr];
    o.w = tile[c4 + 3][jr];
    *(ushort4*)&wvalT[(size_t)(bx * 64 + jr) * D_ + by * 64 + c4] = o;
  }
}

// ---------------- brow = wout @ bval + bout (one wave per output) ----------------
__global__ __launch_bounds__(64)
void sp_brow(const float* __restrict__ wout, const float* __restrict__ bval,
             const float* __restrict__ bout, float* __restrict__ brow) {
  const int i = blockIdx.x, l = threadIdx.x;
  float s = 0.f;
  const float* wr = &wout[(size_t)i * D_ + l * 16];
  const float* bv = &bval[l * 16];
  #pragma unroll
  for (int j = 0; j < 16; j += 4) {
    float4 w4 = *(const float4*)&wr[j];
    float4 b4 = *(const float4*)&bv[j];
    s += w4.x * b4.x + w4.y * b4.y + w4.z * b4.z + w4.w * b4.w;
  }
  #pragma unroll
  for (int off = 32; off > 0; off >>= 1) s += __shfl_xor(s, off);
  if (l == 0) brow[i] = s + bout[i];
}

// ---------------- routing GEMM1: h = gelu(ctx @ w1^T + b1), f32 FMA accum ----------------
__global__ __launch_bounds__(256)
void sp_gemm1(const float* __restrict__ x, const float* __restrict__ mean,
              const float* __restrict__ w1, const float* __restrict__ bias1,
              float* __restrict__ h) {
  __shared__ float As[16][68];
  __shared__ float Bs[16][36];
  int wg = blockIdx.x;
  wg = (wg & 7) * 64 + (wg >> 3);          // bijective XCD swizzle, 512 wgs
  const int n0 = (wg & 15) * 32;           // nbx = 16
  const int m0 = (wg >> 4) * 64;
  const int t = threadIdx.x;
  const int tx = t & 15, ty = t >> 4;
  float acc[4][2] = {};
  const int sr = t >> 2, sc = (t & 3) * 4;
  for (int k0 = 0; k0 < 2 * D_; k0 += 16) {
    const float* src = (k0 < D_) ? (x + k0) : (mean + (k0 - D_));
    float4 va = *(const float4*)&src[(size_t)(m0 + sr) * D_ + sc];
    As[sc + 0][sr] = va.x; As[sc + 1][sr] = va.y; As[sc + 2][sr] = va.z; As[sc + 3][sr] = va.w;
    if (t < 128) {
      const int bn = t >> 2, bc = (t & 3) * 4;
      float4 vb = *(const float4*)&w1[(size_t)(n0 + bn) * (2 * D_) + k0 + bc];
      Bs[bc + 0][bn] = vb.x; Bs[bc + 1][bn] = vb.y; Bs[bc + 2][bn] = vb.z; Bs[bc + 3][bn] = vb.w;
    }
    __syncthreads();
    #pragma unroll
    for (int kk = 0; kk < 16; ++kk) {
      float4 a = *(const float4*)&As[kk][ty * 4];
      float2 bb = *(const float2*)&Bs[kk][tx * 2];
      acc[0][0] = fmaf(a.x, bb.x, acc[0][0]); acc[0][1] = fmaf(a.x, bb.y, acc[0][1]);
      acc[1][0] = fmaf(a.y, bb.x, acc[1][0]); acc[1][1] = fmaf(a.y, bb.y, acc[1][1]);
      acc[2][0] = fmaf(a.z, bb.x, acc[2][0]); acc[2][1] = fmaf(a.z, bb.y, acc[2][1]);
      acc[3][0] = fmaf(a.w, bb.x, acc[3][0]); acc[3][1] = fmaf(a.w, bb.y, acc[3][1]);
    }
    __syncthreads();
  }
  #pragma unroll
  for (int i = 0; i < 4; ++i) {
    #pragma unroll
    for (int j = 0; j < 2; ++j) {
      const int r = m0 + ty * 4 + i, c = n0 + tx * 2 + j;
      float v = acc[i][j] + bias1[c];
      v = 0.5f * v * (1.0f + erff(v * 0.70710678118654752f));
      h[(size_t)r * DH_ + c] = v;
    }
  }
}

// ---------------- logits + top-8 + softmax (one wave per row, f64 dot) ----------------
__global__ __launch_bounds__(64)
void sp_route_topk(const float* __restrict__ h, const float* __restrict__ w2,
                   const float* __restrict__ b2, const float* __restrict__ tau,
                   int* __restrict__ tki, float* __restrict__ tkw) {
  __shared__ float hs[DH_];
  const int b = blockIdx.x, l = threadIdx.x;
  *(float4*)&hs[l * 4] = *(const float4*)&h[(size_t)b * DH_ + l * 4];
  *(float4*)&hs[256 + l * 4] = *(const float4*)&h[(size_t)b * DH_ + 256 + l * 4];
  __syncthreads();
  const double invd = 1.0 / ((double)fabsf(tau[0]) + 0.1);
  float v[2]; int id[2];
  #pragma unroll
  for (int c = 0; c < 2; ++c) {
    const int n = c * 64 + l;
    const float* wr = &w2[(size_t)n * DH_];
    double s = 0.0;
    for (int j = 0; j < DH_; j += 4) {
      float4 w4 = *(const float4*)&wr[j];
      s += (double)hs[j] * (double)w4.x;
      s += (double)hs[j + 1] * (double)w4.y;
      s += (double)hs[j + 2] * (double)w4.z;
      s += (double)hs[j + 3] * (double)w4.w;
    }
    v[c] = (float)((s + (double)b2[n]) * invd);
    id[c] = n;
  }
  float m0f = 0.f, sum = 0.f, mye = 0.f; int myi = 0;
  for (int r = 0; r < 8; ++r) {
    float mv; int mi;
    if (v[1] > v[0]) { mv = v[1]; mi = id[1]; } else { mv = v[0]; mi = id[0]; }
    #pragma unroll
    for (int off = 32; off > 0; off >>= 1) {
      float ov = __shfl_xor(mv, off);
      int oi = __shfl_xor(mi, off);
      if (ov > mv || (ov == mv && oi < mi)) { mv = ov; mi = oi; }
    }
    if (r == 0) m0f = mv;
    float er = expf(mv - m0f);
    sum += er;
    if (l == r) { mye = er; myi = mi; }
    if (mi == id[0]) v[0] = -3.0e38f;
    if (mi == id[1]) v[1] = -3.0e38f;
  }
  if (l < 8) { tki[b * K_ + l] = myi; tkw[b * K_ + l] = mye / sum; }
}

// ---------------- gather selected slot rows -> bf16 ----------------
__global__ __launch_bounds__(256)
void sp_gather(const float* __restrict__ S, const int* __restrict__ tki,
               u16* __restrict__ slotb) {
  const int blk = blockIdx.x;
  const int b = blk >> 3, k = blk & 7;
  const int s = tki[b * K_ + k];
  const int t = threadIdx.x;
  float4 v = *(const float4*)&S[((size_t)b * NS_ + s) * D_ + t * 4];
  ushort4 o;
  o.x = f2bf(v.x); o.y = f2bf(v.y); o.z = f2bf(v.z); o.w = f2bf(v.w);
  *(ushort4*)&slotb[((size_t)b * K_ + k) * D_ + t * 4] = o;
}

// ---------------- plain bf16 TN MFMA GEMM ----------------
// 128x128 tile, BK=32, 4 waves, 16x16x32 MFMA, global_load_lds, XCD swizzle.
// EPI: 0=f32 store, 1=bf16 store, 2=bias+f32, 3=bias+bf16
template<int EPI>
__global__ __launch_bounds__(256)
void sp_gemm_bf16(const u16* __restrict__ A, const u16* __restrict__ Bm,
                  void* __restrict__ Cv, const float* __restrict__ bias,
                  int M, int N, int Kd, int nbx) {
  __shared__ u16 lA[128 * 32];
  __shared__ u16 lB[128 * 32];
  int wg = blockIdx.x;
  {
    const int nwg = nbx * ((M + 127) >> 7);
    const int cpx = nwg >> 3;               // nwg % 8 == 0 for all our shapes
    wg = (wg & 7) * cpx + (wg >> 3);
  }
  const int m0 = (wg / nbx) * 128, n0 = (wg % nbx) * 128;
  const int t = threadIdx.x;
  const int lane = t & 63;
  const int w = t >> 6;
  const int wm = w >> 1, wn = w & 1;

  f32x4 acc[4][4] = {};

  const int srow = t >> 2;
  const int scol = (t & 3) * 8;
  const u16* gA0 = A + (size_t)(m0 + srow) * Kd + scol;
  const u16* gA1 = A + (size_t)(m0 + 64 + srow) * Kd + scol;
  const u16* gB0 = Bm + (size_t)(n0 + srow) * Kd + scol;
  const u16* gB1 = Bm + (size_t)(n0 + 64 + srow) * Kd + scol;
  u16* lAw = &lA[(t & 192) * 8];
  u16* lBw = &lB[(t & 192) * 8];

  const int kb = (lane >> 4) * 8;
  const int rA = wm * 64 + (lane & 15);
  const int rB = wn * 64 + (lane & 15);

  for (int k0 = 0; k0 < Kd; k0 += 32) {
    __builtin_amdgcn_global_load_lds(AS1C(gA0 + k0), AS3(lAw), 16, 0, 0);
    __builtin_amdgcn_global_load_lds(AS1C(gA1 + k0), AS3(lAw + 2048), 16, 0, 0);
    __builtin_amdgcn_global_load_lds(AS1C(gB0 + k0), AS3(lBw), 16, 0, 0);
    __builtin_amdgcn_global_load_lds(AS1C(gB1 + k0), AS3(lBw + 2048), 16, 0, 0);
    __syncthreads();
    bf16x8 af[4], bfr[4];
    #pragma unroll
    for (int fm = 0; fm < 4; ++fm)
      af[fm] = *(const bf16x8*)&lA[(rA + fm * 16) * 32 + kb];
    #pragma unroll
    for (int fn = 0; fn < 4; ++fn)
      bfr[fn] = *(const bf16x8*)&lB[(rB + fn * 16) * 32 + kb];
    #pragma unroll
    for (int fm = 0; fm < 4; ++fm) {
      #pragma unroll
      for (int fn = 0; fn < 4; ++fn)
        acc[fm][fn] = __builtin_amdgcn_mfma_f32_16x16x32_bf16(af[fm], bfr[fn], acc[fm][fn], 0, 0, 0);
    }
    __syncthreads();
  }

  #pragma unroll
  for (int fm = 0; fm < 4; ++fm) {
    #pragma unroll
    for (int fn = 0; fn < 4; ++fn) {
      #pragma unroll
      for (int i = 0; i < 4; ++i) {
        const int r = m0 + wm * 64 + fm * 16 + (lane >> 4) * 4 + i;
        const int c = n0 + wn * 64 + fn * 16 + (lane & 15);
        float v = acc[fm][fn][i];
        if constexpr (EPI >= 2) v += bias[c];
        if constexpr (EPI == 0 || EPI == 2)
          ((float*)Cv)[(size_t)r * N + c] = v;
        else
          ((u16*)Cv)[(size_t)r * N + c] = f2bf(v);
      }
    }
  }
}

// ---------------- fused gh GEMM + GRU elementwise + scatter + weighted mix ----------------
// Tile: 128 rows x (3 gates x 64 d-cols). 4 waves (2x2): wm covers 64 rows each,
// wn covers 32 of 64 d-cols per gate. acc[fm(4)][fn(6)], fn = gate*2 + f.
template<bool DIRECT>
__global__ __launch_bounds__(256, 2)
void sp_gh_gru(const u16* __restrict__ slotb, const u16* __restrict__ whhb,
               const u16* __restrict__ gib, const float* __restrict__ bih,
               const float* __restrict__ bhh, const int* __restrict__ tki,
               const float* __restrict__ tkw, float* __restrict__ dst,
               u16* __restrict__ umixb) {
  __shared__ u16 lA[128 * 32];
  __shared__ u16 lB[192 * 32];
  __shared__ int   sTki[128];
  __shared__ float sTkw[128];
  // grid = 2048 = 128 mtiles x 16 dblocks (db fast); XCD swizzle
  int wg = blockIdx.x;
  wg = (wg & 7) * 256 + (wg >> 3);
  const int mt = wg >> 4, db = wg & 15;
  const int m0 = mt * 128, d0 = db * 64;
  const int t = threadIdx.x;
  const int lane = t & 63, w = t >> 6;
  const int wm = w >> 1, wn = w & 1;
  const int lane15 = lane & 15, hi = lane >> 4;

  if (t < 128) { sTki[t] = tki[m0 + t]; sTkw[t] = tkw[m0 + t]; }

  f32x4 acc[4][6] = {};

  const int srow = t >> 2;
  const int scol = (t & 3) * 8;
  const u16* gA0 = slotb + (size_t)(m0 + srow) * D_ + scol;
  const u16* gA1 = slotb + (size_t)(m0 + 64 + srow) * D_ + scol;
  const u16* gB0 = whhb + (size_t)(d0 + srow) * D_ + scol;
  const u16* gB1 = whhb + (size_t)(D_ + d0 + srow) * D_ + scol;
  const u16* gB2 = whhb + (size_t)(2 * D_ + d0 + srow) * D_ + scol;
  u16* lAw = &lA[(t & 192) * 8];
  u16* lBw = &lB[(t & 192) * 8];

  const int kb = hi * 8;
  const int rA = wm * 64 + lane15;
  const int rB = wn * 32 + lane15;

  for (int k0 = 0; k0 < D_; k0 += 32) {
    __builtin_amdgcn_global_load_lds(AS1C(gA0 + k0), AS3(lAw), 16, 0, 0);
    __builtin_amdgcn_global_load_lds(AS1C(gA1 + k0), AS3(lAw + 2048), 16, 0, 0);
    __builtin_amdgcn_global_load_lds(AS1C(gB0 + k0), AS3(lBw), 16, 0, 0);
    __builtin_amdgcn_global_load_lds(AS1C(gB1 + k0), AS3(lBw + 2048), 16, 0, 0);
    __builtin_amdgcn_global_load_lds(AS1C(gB2 + k0), AS3(lBw + 4096), 16, 0, 0);
    __syncthreads();
    bf16x8 af[4], bfr[6];
    #pragma unroll
    for (int fm = 0; fm < 4; ++fm)
      af[fm] = *(const bf16x8*)&lA[(rA + fm * 16) * 32 + kb];
    #pragma unroll
    for (int g = 0; g < 3; ++g) {
      #pragma unroll
      for (int f = 0; f < 2; ++f)
        bfr[g * 2 + f] = *(const bf16x8*)&lB[(g * 64 + rB + f * 16) * 32 + kb];
    }
    #pragma unroll
    for (int fm = 0; fm < 4; ++fm) {
      #pragma unroll
      for (int fn = 0; fn < 6; ++fn)
        acc[fm][fn] = __builtin_amdgcn_mfma_f32_16x16x32_bf16(af[fm], bfr[fn], acc[fm][fn], 0, 0, 0);
    }
    __syncthreads();
  }

  // ---- GRU epilogue ----
  #pragma unroll
  for (int fm = 0; fm < 4; ++fm) {
    const int rbase = wm * 64 + fm * 16 + hi * 4;     // 4 rows, same batch
    const int bglob = (m0 + rbase) >> 3;
    #pragma unroll
    for (int f = 0; f < 2; ++f) {
      const int dg = d0 + wn * 32 + f * 16 + lane15;  // d within [0,1024)
      const float Gr = bf2f(gib[(size_t)bglob * G3_ + dg])          + bih[dg];
      const float Gz = bf2f(gib[(size_t)bglob * G3_ + D_ + dg])     + bih[D_ + dg];
      const float Gn = bf2f(gib[(size_t)bglob * G3_ + 2 * D_ + dg]) + bih[2 * D_ + dg];
      const float Br = bhh[dg], Bz = bhh[D_ + dg], Bn = bhh[2 * D_ + dg];
      float part = 0.f;
      #pragma unroll
      for (int i = 0; i < 4; ++i) {
        const int row = rbase + i;
        const int grow = m0 + row;
        const float slot = bf2f(slotb[(size_t)grow * D_ + dg]);
        const float rr = acc[fm][f][i] + Br;
        const float zz = acc[fm][f + 2][i] + Bz;
        const float nn = acc[fm][f + 4][i] + Bn;
        const float rg = 1.f / (1.f + expf(-(Gr + rr)));
        const float zg = 1.f / (1.f + expf(-(Gz + zz)));
        const float ng = tanhf(Gn + rg * nn);
        const float uv = (1.f - zg) * ng + zg * slot;
        part = fmaf(sTkw[row], uv, part);
        if (DIRECT)
          dst[((size_t)bglob * NS_ + sTki[row]) * D_ + dg] = uv;
        else
          dst[(size_t)grow * D_ + dg] = uv;
      }
      part += __shfl_xor(part, 16);
      if ((hi & 1) == 0)
        umixb[(size_t)bglob * D_ + dg] = f2bf(part);
    }
  }
}

// ---------------- variant B: copy S->S_new with merge of updated rows ----------------
__global__ __launch_bounds__(256)
void sp_copy_scatter(const float* __restrict__ S, const float* __restrict__ upd,
                     const int* __restrict__ tki, float* __restrict__ Snew) {
  const int b = blockIdx.x, t = threadIdx.x;
  const int d0 = t * 4;
  int idx[K_];
  #pragma unroll
  for (int k = 0; k < K_; ++k) idx[k] = tki[b * K_ + k];
  for (int s = 0; s < NS_; ++s) {
    int sk = -1;
    #pragma unroll
    for (int k = 0; k < K_; ++k) if (idx[k] == s) sk = k;
    float4 v;
    if (sk >= 0) v = *(const float4*)&upd[((size_t)b * K_ + sk) * D_ + d0];
    else         v = *(const float4*)&S[((size_t)b * NS_ + s) * D_ + d0];
    *(float4*)&Snew[((size_t)b * NS_ + s) * D_ + d0] = v;
  }
}

extern "C" void kernel_launch(void* const* d_in, const int* in_sizes, int n_in,
                              void* d_out, int out_size, void* d_ws, size_t ws_size,
                              hipStream_t stream) {
  const float* x    = (const float*)d_in[0];
  const float* S    = (const float*)d_in[1];
  const float* w1   = (const float*)d_in[2];
  const float* b1   = (const float*)d_in[3];
  const float* w2   = (const float*)d_in[4];
  const float* b2   = (const float*)d_in[5];
  const float* wih  = (const float*)d_in[6];
  const float* whh  = (const float*)d_in[7];
  const float* bih  = (const float*)d_in[8];
  const float* bhh  = (const float*)d_in[9];
  const float* wval = (const float*)d_in[10];
  const float* bval = (const float*)d_in[11];
  const float* wout = (const float*)d_in[12];
  const float* bout = (const float*)d_in[13];
  const float* tau  = (const float*)d_in[14];

  float* out  = (float*)d_out;
  float* Snew = out + (size_t)B_ * D_;

  const bool bigws = ws_size >= (size_t)400 * 1024 * 1024;
  char* bigbase = bigws ? (char*)d_ws : (char*)Snew;  // variant B: scratch in S_new region
  size_t bo = 0;
  auto balloc = [&](size_t bytes) -> void* {
    void* p = bigbase + bo; bo += (bytes + 255) & ~(size_t)255; return p;
  };

  float* mean  = (float*)balloc((size_t)B_ * D_ * 4);
  float* h     = (float*)balloc((size_t)B_ * DH_ * 4);
  u16* xb      = (u16*)balloc((size_t)B_ * D_ * 2);
  u16* wihb    = (u16*)balloc((size_t)G3_ * D_ * 2);
  u16* whhb    = (u16*)balloc((size_t)G3_ * D_ * 2);
  u16* woutb   = (u16*)balloc((size_t)D_ * D_ * 2);
  u16* wvalTb  = (u16*)balloc((size_t)D_ * D_ * 2);
  u16* Wrob    = (u16*)balloc((size_t)D_ * D_ * 2);
  u16* gib     = (u16*)balloc((size_t)B_ * G3_ * 2);
  u16* slotb   = (u16*)balloc((size_t)B_ * K_ * D_ * 2);
  u16* umixb   = (u16*)balloc((size_t)B_ * D_ * 2);
  float* brow  = (float*)balloc((size_t)D_ * 4);

  // small buffers always live in d_ws
  char* wsb = (char*)d_ws;
  size_t so = bigws ? bo : 0;
  auto salloc = [&](size_t bytes) -> void* {
    void* p = wsb + so; so += (bytes + 255) & ~(size_t)255; return p;
  };
  int*   tki = (int*)salloc((size_t)B_ * K_ * 4);
  float* tkw = (float*)salloc((size_t)B_ * K_ * 4);
  float* upd = bigws ? nullptr : (float*)salloc((size_t)B_ * K_ * D_ * 4);

  // 1. fused copy + mean (variant B: mean only; Snew region is scratch there)
  if (bigws) sp_copymean<1><<<B_, 256, 0, stream>>>(S, Snew, mean);
  else       sp_copymean<0><<<B_, 256, 0, stream>>>(S, Snew, mean);

  // 2. bf16 conversions + wval transpose
  sp_convert_all<<<1024, 256, 0, stream>>>(x, wih, whh, wout, xb, wihb, whhb, woutb);
  sp_transpose_wval<<<256, 256, 0, stream>>>(wval, wvalTb);

  // 3. collapsed readout weights: Wro = wout @ wval (bf16), brow = wout@bval + bout
  sp_gemm_bf16<1><<<64, 256, 0, stream>>>(woutb, wvalTb, Wrob, nullptr, D_, D_, D_, 8);
  sp_brow<<<D_, 64, 0, stream>>>(wout, bval, bout, brow);

  // 4. routing MLP (f32 FMA) + top-k (f64 dot)
  sp_gemm1<<<512, 256, 0, stream>>>(x, mean, w1, b1, h);
  sp_route_topk<<<B_, 64, 0, stream>>>(h, w2, b2, tau, tki, tkw);

  // 5. gather selected slots -> bf16
  sp_gather<<<B_ * K_, 256, 0, stream>>>(S, tki, slotb);

  // 6. gi = x @ wih^T (bf16 MFMA, bf16 out)
  sp_gemm_bf16<1><<<384, 256, 0, stream>>>(xb, wihb, gib, nullptr, B_, G3_, D_, G3_ / 128);

  // 7. fused gh GEMM + GRU + scatter + weighted mix
  if (bigws)
    sp_gh_gru<true><<<2048, 256, 0, stream>>>(slotb, whhb, gib, bih, bhh,
                                              tki, tkw, Snew, umixb);
  else
    sp_gh_gru<false><<<2048, 256, 0, stream>>>(slotb, whhb, gib, bih, bhh,
                                               tki, tkw, upd, umixb);

  // 8. readout: out = umix @ Wro^T + brow
  sp_gemm_bf16<2><<<128, 256, 0, stream>>>(umixb, Wrob, out, brow, B_, D_, D_, 8);

  // 9. variant B: final copy+merge
  if (!bigws)
    sp_copy_scatter<<<B_, 256, 0, stream>>>(S, upd, tki, Snew);
}

// Round 9
// 827.337 us; speedup vs baseline: 1.4204x; 1.0096x over previous
//
#include <hip/hip_runtime.h>
#include <math.h>
#include <stdint.h>

#define B_   2048
#define NS_  128
#define D_   1024
#define K_   8
#define DH_  512
#define G3_  3072

typedef unsigned short u16;
typedef short bf16x8 __attribute__((ext_vector_type(8)));
typedef float f32x4 __attribute__((ext_vector_type(4)));

__device__ __forceinline__ float bf2f(u16 u) {
  union { unsigned i; float f; } v; v.i = ((unsigned)u) << 16; return v.f;
}
__device__ __forceinline__ u16 f2bf(float f) {
  unsigned x = __float_as_uint(f);
  return (u16)((x + 0x7fffu + ((x >> 16) & 1u)) >> 16);
}

#define AS1C(p) ((const __attribute__((address_space(1))) void*)(uintptr_t)(p))
#define AS3(p)  ((__attribute__((address_space(3))) void*)(unsigned)(uintptr_t)(p))

// ---------------- fused S->Snew copy + slot mean (f64 accum, NT streams) ----------------
// Bit-identical to rounds 4-6 (passing).
template<int DO_COPY>
__global__ __launch_bounds__(256)
void sp_copymean(const float* __restrict__ S, float* __restrict__ Snew,
                 float* __restrict__ mean) {
  const int b = blockIdx.x;
  const int t = threadIdx.x, d0 = t * 4;
  const f32x4* src = (const f32x4*)(S + (size_t)b * NS_ * D_) + t;
  f32x4* dst = (f32x4*)(Snew + (size_t)b * NS_ * D_) + t;
  double a0 = 0, a1 = 0, a2 = 0, a3 = 0;
  #pragma unroll 4
  for (int s = 0; s < NS_; ++s) {
    f32x4 v = __builtin_nontemporal_load(src);
    if (DO_COPY) __builtin_nontemporal_store(v, dst);
    a0 += v[0]; a1 += v[1]; a2 += v[2]; a3 += v[3];
    src += 256; dst += 256;
  }
  float4 m;
  m.x = (float)(a0 * (1.0 / 128.0)); m.y = (float)(a1 * (1.0 / 128.0));
  m.z = (float)(a2 * (1.0 / 128.0)); m.w = (float)(a3 * (1.0 / 128.0));
  *(float4*)&mean[(size_t)b * D_ + d0] = m;
}

// ---------------- one prep kernel: converts + wval^T + brow ----------------
// blocks [0,1024): grid-stride f4 converts; [1024,1280): wval transpose; [1280,1536): brow
// f4 regions: [0,524288) xb | [524288,1310720) wihb | [1310720,2097152) whhb |
//             [2097152,2359296) woutb
__global__ __launch_bounds__(256)
void sp_prep(const float* __restrict__ x, const float* __restrict__ wih,
             const float* __restrict__ whh, const float* __restrict__ wout,
             const float* __restrict__ wval, const float* __restrict__ bval,
             const float* __restrict__ bout,
             u16* __restrict__ xb, u16* __restrict__ wihb,
             u16* __restrict__ whhb, u16* __restrict__ woutb,
             u16* __restrict__ wvalT, float* __restrict__ brow) {
  __shared__ u16 tile[64][65];
  const int blk = blockIdx.x;
  const int t = threadIdx.x;
  if (blk < 1024) {
    for (int i = blk * 256 + t; i < 2359296; i += 1024 * 256) {
      const float* s; u16* d; int off;
      if (i < 524288)       { s = x;    d = xb;    off = i; }
      else if (i < 1310720) { s = wih;  d = wihb;  off = i - 524288; }
      else if (i < 2097152) { s = whh;  d = whhb;  off = i - 1310720; }
      else                  { s = wout; d = woutb; off = i - 2097152; }
      float4 v = ((const float4*)s)[off];
      ushort4 o;
      o.x = f2bf(v.x); o.y = f2bf(v.y); o.z = f2bf(v.z); o.w = f2bf(v.w);
      ((ushort4*)d)[off] = o;
    }
  } else if (blk < 1280) {
    const int tb = blk - 1024;
    const int bx = tb & 15, by = tb >> 4;
    const int r = t >> 4, c4 = (t & 15) * 4;
    #pragma unroll
    for (int p = 0; p < 4; ++p) {
      const int row = by * 64 + p * 16 + r;
      float4 v = *(const float4*)&wval[(size_t)row * D_ + bx * 64 + c4];
      tile[p * 16 + r][c4 + 0] = f2bf(v.x);
      tile[p * 16 + r][c4 + 1] = f2bf(v.y);
      tile[p * 16 + r][c4 + 2] = f2bf(v.z);
      tile[p * 16 + r][c4 + 3] = f2bf(v.w);
    }
    __syncthreads();
    #pragma unroll
    for (int p = 0; p < 4; ++p) {
      const int jr = p * 16 + r;
      ushort4 o;
      o.x = tile[c4 + 0][jr];
      o.y = tile[c4 + 1][jr];
      o.z = tile[c4 + 2][jr];
      o.w = tile[c4 + 3][jr];
      *(ushort4*)&wvalT[(size_t)(bx * 64 + jr) * D_ + by * 64 + c4] = o;
    }
  } else {
    // brow[i] = wout[i,:]@bval + bout[i]; 256 blocks x 4 waves = 1024 outputs
    const int w = t >> 6, l = t & 63;
    const int i = (blk - 1280) * 4 + w;
    float s = 0.f;
    const float* wr = &wout[(size_t)i * D_ + l * 16];
    const float* bv = &bval[l * 16];
    #pragma unroll
    for (int j = 0; j < 16; j += 4) {
      float4 w4 = *(const float4*)&wr[j];
      float4 b4 = *(const float4*)&bv[j];
      s += w4.x * b4.x + w4.y * b4.y + w4.z * b4.z + w4.w * b4.w;
    }
    #pragma unroll
    for (int off = 32; off > 0; off >>= 1) s += __shfl_xor(s, off);
    if (l == 0) brow[i] = s + bout[i];
  }
}

// ---------------- routing GEMM1: h = gelu(ctx @ w1^T + b1), f32 FMA accum ----------------
// Bit-identical to rounds 4-6 (passing).
__global__ __launch_bounds__(256)
void sp_gemm1(const float* __restrict__ x, const float* __restrict__ mean,
              const float* __restrict__ w1, const float* __restrict__ bias1,
              float* __restrict__ h) {
  __shared__ float As[16][68];
  __shared__ float Bs[16][36];
  int wg = blockIdx.x;
  wg = (wg & 7) * 64 + (wg >> 3);          // bijective XCD swizzle, 512 wgs
  const int n0 = (wg & 15) * 32;           // nbx = 16
  const int m0 = (wg >> 4) * 64;
  const int t = threadIdx.x;
  const int tx = t & 15, ty = t >> 4;
  float acc[4][2] = {};
  const int sr = t >> 2, sc = (t & 3) * 4;
  for (int k0 = 0; k0 < 2 * D_; k0 += 16) {
    const float* src = (k0 < D_) ? (x + k0) : (mean + (k0 - D_));
    float4 va = *(const float4*)&src[(size_t)(m0 + sr) * D_ + sc];
    As[sc + 0][sr] = va.x; As[sc + 1][sr] = va.y; As[sc + 2][sr] = va.z; As[sc + 3][sr] = va.w;
    if (t < 128) {
      const int bn = t >> 2, bc = (t & 3) * 4;
      float4 vb = *(const float4*)&w1[(size_t)(n0 + bn) * (2 * D_) + k0 + bc];
      Bs[bc + 0][bn] = vb.x; Bs[bc + 1][bn] = vb.y; Bs[bc + 2][bn] = vb.z; Bs[bc + 3][bn] = vb.w;
    }
    __syncthreads();
    #pragma unroll
    for (int kk = 0; kk < 16; ++kk) {
      float4 a = *(const float4*)&As[kk][ty * 4];
      float2 bb = *(const float2*)&Bs[kk][tx * 2];
      acc[0][0] = fmaf(a.x, bb.x, acc[0][0]); acc[0][1] = fmaf(a.x, bb.y, acc[0][1]);
      acc[1][0] = fmaf(a.y, bb.x, acc[1][0]); acc[1][1] = fmaf(a.y, bb.y, acc[1][1]);
      acc[2][0] = fmaf(a.z, bb.x, acc[2][0]); acc[2][1] = fmaf(a.z, bb.y, acc[2][1]);
      acc[3][0] = fmaf(a.w, bb.x, acc[3][0]); acc[3][1] = fmaf(a.w, bb.y, acc[3][1]);
    }
    __syncthreads();
  }
  #pragma unroll
  for (int i = 0; i < 4; ++i) {
    #pragma unroll
    for (int j = 0; j < 2; ++j) {
      const int r = m0 + ty * 4 + i, c = n0 + tx * 2 + j;
      float v = acc[i][j] + bias1[c];
      v = 0.5f * v * (1.0f + erff(v * 0.70710678118654752f));
      h[(size_t)r * DH_ + c] = v;
    }
  }
}

// ---------------- logits + top-8 + softmax + gather (one wave per row, f64 dot) ----------------
__global__ __launch_bounds__(64)
void sp_route_topk(const float* __restrict__ h, const float* __restrict__ w2,
                   const float* __restrict__ b2, const float* __restrict__ tau,
                   const float* __restrict__ S,
                   int* __restrict__ tki, float* __restrict__ tkw,
                   u16* __restrict__ slotb) {
  __shared__ float hs[DH_];
  __shared__ int sTki[K_];
  const int b = blockIdx.x, l = threadIdx.x;
  *(float4*)&hs[l * 4] = *(const float4*)&h[(size_t)b * DH_ + l * 4];
  *(float4*)&hs[256 + l * 4] = *(const float4*)&h[(size_t)b * DH_ + 256 + l * 4];
  __syncthreads();
  const double invd = 1.0 / ((double)fabsf(tau[0]) + 0.1);
  float v[2]; int id[2];
  #pragma unroll
  for (int c = 0; c < 2; ++c) {
    const int n = c * 64 + l;
    const float* wr = &w2[(size_t)n * DH_];
    double s = 0.0;
    for (int j = 0; j < DH_; j += 4) {
      float4 w4 = *(const float4*)&wr[j];
      s += (double)hs[j] * (double)w4.x;
      s += (double)hs[j + 1] * (double)w4.y;
      s += (double)hs[j + 2] * (double)w4.z;
      s += (double)hs[j + 3] * (double)w4.w;
    }
    v[c] = (float)((s + (double)b2[n]) * invd);
    id[c] = n;
  }
  float m0f = 0.f, sum = 0.f, mye = 0.f; int myi = 0;
  for (int r = 0; r < 8; ++r) {
    float mv; int mi;
    if (v[1] > v[0]) { mv = v[1]; mi = id[1]; } else { mv = v[0]; mi = id[0]; }
    #pragma unroll
    for (int off = 32; off > 0; off >>= 1) {
      float ov = __shfl_xor(mv, off);
      int oi = __shfl_xor(mi, off);
      if (ov > mv || (ov == mv && oi < mi)) { mv = ov; mi = oi; }
    }
    if (r == 0) m0f = mv;
    float er = expf(mv - m0f);
    sum += er;
    if (l == r) { mye = er; myi = mi; }
    if (mi == id[0]) v[0] = -3.0e38f;
    if (mi == id[1]) v[1] = -3.0e38f;
  }
  if (l < 8) {
    tki[b * K_ + l] = myi; tkw[b * K_ + l] = mye / sum;
    sTki[l] = myi;
  }
  __syncthreads();
  // gather the 8 selected rows -> bf16 slotb
  #pragma unroll
  for (int k = 0; k < K_; ++k) {
    const int s = sTki[k];
    const float4* src = (const float4*)&S[((size_t)b * NS_ + s) * D_];
    ushort4* dst = (ushort4*)&slotb[((size_t)b * K_ + k) * D_];
    #pragma unroll
    for (int c = 0; c < 4; ++c) {
      float4 vv = src[c * 64 + l];
      ushort4 o;
      o.x = f2bf(vv.x); o.y = f2bf(vv.y); o.z = f2bf(vv.z); o.w = f2bf(vv.w);
      dst[c * 64 + l] = o;
    }
  }
}

// ---------------- plain bf16 TN MFMA GEMM ----------------
// 128x128 tile, BK=32, 4 waves, 16x16x32 MFMA, global_load_lds, XCD swizzle.
// EPI: 0=f32 store, 1=bf16 store, 2=bias+f32, 3=bias+bf16
template<int EPI>
__global__ __launch_bounds__(256)
void sp_gemm_bf16(const u16* __restrict__ A, const u16* __restrict__ Bm,
                  void* __restrict__ Cv, const float* __restrict__ bias,
                  int M, int N, int Kd, int nbx) {
  __shared__ u16 lA[128 * 32];
  __shared__ u16 lB[128 * 32];
  int wg = blockIdx.x;
  {
    const int nwg = nbx * ((M + 127) >> 7);
    const int cpx = nwg >> 3;               // nwg % 8 == 0 for all our shapes
    wg = (wg & 7) * cpx + (wg >> 3);
  }
  const int m0 = (wg / nbx) * 128, n0 = (wg % nbx) * 128;
  const int t = threadIdx.x;
  const int lane = t & 63;
  const int w = t >> 6;
  const int wm = w >> 1, wn = w & 1;

  f32x4 acc[4][4] = {};

  const int srow = t >> 2;
  const int scol = (t & 3) * 8;
  const u16* gA0 = A + (size_t)(m0 + srow) * Kd + scol;
  const u16* gA1 = A + (size_t)(m0 + 64 + srow) * Kd + scol;
  const u16* gB0 = Bm + (size_t)(n0 + srow) * Kd + scol;
  const u16* gB1 = Bm + (size_t)(n0 + 64 + srow) * Kd + scol;
  u16* lAw = &lA[(t & 192) * 8];
  u16* lBw = &lB[(t & 192) * 8];

  const int kb = (lane >> 4) * 8;
  const int rA = wm * 64 + (lane & 15);
  const int rB = wn * 64 + (lane & 15);

  for (int k0 = 0; k0 < Kd; k0 += 32) {
    __builtin_amdgcn_global_load_lds(AS1C(gA0 + k0), AS3(lAw), 16, 0, 0);
    __builtin_amdgcn_global_load_lds(AS1C(gA1 + k0), AS3(lAw + 2048), 16, 0, 0);
    __builtin_amdgcn_global_load_lds(AS1C(gB0 + k0), AS3(lBw), 16, 0, 0);
    __builtin_amdgcn_global_load_lds(AS1C(gB1 + k0), AS3(lBw + 2048), 16, 0, 0);
    __syncthreads();
    bf16x8 af[4], bfr[4];
    #pragma unroll
    for (int fm = 0; fm < 4; ++fm)
      af[fm] = *(const bf16x8*)&lA[(rA + fm * 16) * 32 + kb];
    #pragma unroll
    for (int fn = 0; fn < 4; ++fn)
      bfr[fn] = *(const bf16x8*)&lB[(rB + fn * 16) * 32 + kb];
    #pragma unroll
    for (int fm = 0; fm < 4; ++fm) {
      #pragma unroll
      for (int fn = 0; fn < 4; ++fn)
        acc[fm][fn] = __builtin_amdgcn_mfma_f32_16x16x32_bf16(af[fm], bfr[fn], acc[fm][fn], 0, 0, 0);
    }
    __syncthreads();
  }

  #pragma unroll
  for (int fm = 0; fm < 4; ++fm) {
    #pragma unroll
    for (int fn = 0; fn < 4; ++fn) {
      #pragma unroll
      for (int i = 0; i < 4; ++i) {
        const int r = m0 + wm * 64 + fm * 16 + (lane >> 4) * 4 + i;
        const int c = n0 + wn * 64 + fn * 16 + (lane & 15);
        float v = acc[fm][fn][i];
        if constexpr (EPI >= 2) v += bias[c];
        if constexpr (EPI == 0 || EPI == 2)
          ((float*)Cv)[(size_t)r * N + c] = v;
        else
          ((u16*)Cv)[(size_t)r * N + c] = f2bf(v);
      }
    }
  }
}

// ---------------- fused gh GEMM + GRU elementwise + scatter + weighted mix ----------------
// Tile: 128 rows x (3 gates x 64 d-cols). 4 waves (2x2). acc[fm(4)][fn(6)], fn = gate*2+f.
template<bool DIRECT>
__global__ __launch_bounds__(256, 2)
void sp_gh_gru(const u16* __restrict__ slotb, const u16* __restrict__ whhb,
               const u16* __restrict__ gib, const float* __restrict__ bih,
               const float* __restrict__ bhh, const int* __restrict__ tki,
               const float* __restrict__ tkw, float* __restrict__ dst,
               u16* __restrict__ umixb) {
  __shared__ u16 lA[128 * 32];
  __shared__ u16 lB[192 * 32];
  __shared__ int   sTki[128];
  __shared__ float sTkw[128];
  int wg = blockIdx.x;
  wg = (wg & 7) * 256 + (wg >> 3);
  const int mt = wg >> 4, db = wg & 15;
  const int m0 = mt * 128, d0 = db * 64;
  const int t = threadIdx.x;
  const int lane = t & 63, w = t >> 6;
  const int wm = w >> 1, wn = w & 1;
  const int lane15 = lane & 15, hi = lane >> 4;

  if (t < 128) { sTki[t] = tki[m0 + t]; sTkw[t] = tkw[m0 + t]; }

  f32x4 acc[4][6] = {};

  const int srow = t >> 2;
  const int scol = (t & 3) * 8;
  const u16* gA0 = slotb + (size_t)(m0 + srow) * D_ + scol;
  const u16* gA1 = slotb + (size_t)(m0 + 64 + srow) * D_ + scol;
  const u16* gB0 = whhb + (size_t)(d0 + srow) * D_ + scol;
  const u16* gB1 = whhb + (size_t)(D_ + d0 + srow) * D_ + scol;
  const u16* gB2 = whhb + (size_t)(2 * D_ + d0 + srow) * D_ + scol;
  u16* lAw = &lA[(t & 192) * 8];
  u16* lBw = &lB[(t & 192) * 8];

  const int kb = hi * 8;
  const int rA = wm * 64 + lane15;
  const int rB = wn * 32 + lane15;

  for (int k0 = 0; k0 < D_; k0 += 32) {
    __builtin_amdgcn_global_load_lds(AS1C(gA0 + k0), AS3(lAw), 16, 0, 0);
    __builtin_amdgcn_global_load_lds(AS1C(gA1 + k0), AS3(lAw + 2048), 16, 0, 0);
    __builtin_amdgcn_global_load_lds(AS1C(gB0 + k0), AS3(lBw), 16, 0, 0);
    __builtin_amdgcn_global_load_lds(AS1C(gB1 + k0), AS3(lBw + 2048), 16, 0, 0);
    __builtin_amdgcn_global_load_lds(AS1C(gB2 + k0), AS3(lBw + 4096), 16, 0, 0);
    __syncthreads();
    bf16x8 af[4], bfr[6];
    #pragma unroll
    for (int fm = 0; fm < 4; ++fm)
      af[fm] = *(const bf16x8*)&lA[(rA + fm * 16) * 32 + kb];
    #pragma unroll
    for (int g = 0; g < 3; ++g) {
      #pragma unroll
      for (int f = 0; f < 2; ++f)
        bfr[g * 2 + f] = *(const bf16x8*)&lB[(g * 64 + rB + f * 16) * 32 + kb];
    }
    #pragma unroll
    for (int fm = 0; fm < 4; ++fm) {
      #pragma unroll
      for (int fn = 0; fn < 6; ++fn)
        acc[fm][fn] = __builtin_amdgcn_mfma_f32_16x16x32_bf16(af[fm], bfr[fn], acc[fm][fn], 0, 0, 0);
    }
    __syncthreads();
  }

  // ---- GRU epilogue ----
  #pragma unroll
  for (int fm = 0; fm < 4; ++fm) {
    const int rbase = wm * 64 + fm * 16 + hi * 4;     // 4 rows, same batch
    const int bglob = (m0 + rbase) >> 3;
    #pragma unroll
    for (int f = 0; f < 2; ++f) {
      const int dg = d0 + wn * 32 + f * 16 + lane15;  // d within [0,1024)
      const float Gr = bf2f(gib[(size_t)bglob * G3_ + dg])          + bih[dg];
      const float Gz = bf2f(gib[(size_t)bglob * G3_ + D_ + dg])     + bih[D_ + dg];
      const float Gn = bf2f(gib[(size_t)bglob * G3_ + 2 * D_ + dg]) + bih[2 * D_ + dg];
      const float Br = bhh[dg], Bz = bhh[D_ + dg], Bn = bhh[2 * D_ + dg];
      float part = 0.f;
      #pragma unroll
      for (int i = 0; i < 4; ++i) {
        const int row = rbase + i;
        const int grow = m0 + row;
        const float slot = bf2f(slotb[(size_t)grow * D_ + dg]);
        const float rr = acc[fm][f][i] + Br;
        const float zz = acc[fm][f + 2][i] + Bz;
        const float nn = acc[fm][f + 4][i] + Bn;
        const float rg = 1.f / (1.f + expf(-(Gr + rr)));
        const float zg = 1.f / (1.f + expf(-(Gz + zz)));
        const float ng = tanhf(Gn + rg * nn);
        const float uv = (1.f - zg) * ng + zg * slot;
        part = fmaf(sTkw[row], uv, part);
        if (DIRECT)
          dst[((size_t)bglob * NS_ + sTki[row]) * D_ + dg] = uv;
        else
          dst[(size_t)grow * D_ + dg] = uv;
      }
      part += __shfl_xor(part, 16);
      if ((hi & 1) == 0)
        umixb[(size_t)bglob * D_ + dg] = f2bf(part);
    }
  }
}

// ---------------- variant B: copy S->S_new with merge of updated rows ----------------
__global__ __launch_bounds__(256)
void sp_copy_scatter(const float* __restrict__ S, const float* __restrict__ upd,
                     const int* __restrict__ tki, float* __restrict__ Snew) {
  const int b = blockIdx.x, t = threadIdx.x;
  const int d0 = t * 4;
  int idx[K_];
  #pragma unroll
  for (int k = 0; k < K_; ++k) idx[k] = tki[b * K_ + k];
  for (int s = 0; s < NS_; ++s) {
    int sk = -1;
    #pragma unroll
    for (int k = 0; k < K_; ++k) if (idx[k] == s) sk = k;
    float4 v;
    if (sk >= 0) v = *(const float4*)&upd[((size_t)b * K_ + sk) * D_ + d0];
    else         v = *(const float4*)&S[((size_t)b * NS_ + s) * D_ + d0];
    *(float4*)&Snew[((size_t)b * NS_ + s) * D_ + d0] = v;
  }
}

extern "C" void kernel_launch(void* const* d_in, const int* in_sizes, int n_in,
                              void* d_out, int out_size, void* d_ws, size_t ws_size,
                              hipStream_t stream) {
  const float* x    = (const float*)d_in[0];
  const float* S    = (const float*)d_in[1];
  const float* w1   = (const float*)d_in[2];
  const float* b1   = (const float*)d_in[3];
  const float* w2   = (const float*)d_in[4];
  const float* b2   = (const float*)d_in[5];
  const float* wih  = (const float*)d_in[6];
  const float* whh  = (const float*)d_in[7];
  const float* bih  = (const float*)d_in[8];
  const float* bhh  = (const float*)d_in[9];
  const float* wval = (const float*)d_in[10];
  const float* bval = (const float*)d_in[11];
  const float* wout = (const float*)d_in[12];
  const float* bout = (const float*)d_in[13];
  const float* tau  = (const float*)d_in[14];

  float* out  = (float*)d_out;
  float* Snew = out + (size_t)B_ * D_;

  const bool bigws = ws_size >= (size_t)400 * 1024 * 1024;
  char* bigbase = bigws ? (char*)d_ws : (char*)Snew;  // variant B: scratch in S_new region
  size_t bo = 0;
  auto balloc = [&](size_t bytes) -> void* {
    void* p = bigbase + bo; bo += (bytes + 255) & ~(size_t)255; return p;
  };

  float* mean  = (float*)balloc((size_t)B_ * D_ * 4);
  float* h     = (float*)balloc((size_t)B_ * DH_ * 4);
  u16* xb      = (u16*)balloc((size_t)B_ * D_ * 2);
  u16* wihb    = (u16*)balloc((size_t)G3_ * D_ * 2);
  u16* whhb    = (u16*)balloc((size_t)G3_ * D_ * 2);
  u16* woutb   = (u16*)balloc((size_t)D_ * D_ * 2);
  u16* wvalTb  = (u16*)balloc((size_t)D_ * D_ * 2);
  u16* Wrob    = (u16*)balloc((size_t)D_ * D_ * 2);
  u16* gib     = (u16*)balloc((size_t)B_ * G3_ * 2);
  u16* slotb   = (u16*)balloc((size_t)B_ * K_ * D_ * 2);
  u16* umixb   = (u16*)balloc((size_t)B_ * D_ * 2);
  float* brow  = (float*)balloc((size_t)D_ * 4);

  // small buffers always live in d_ws
  char* wsb = (char*)d_ws;
  size_t so = bigws ? bo : 0;
  auto salloc = [&](size_t bytes) -> void* {
    void* p = wsb + so; so += (bytes + 255) & ~(size_t)255; return p;
  };
  int*   tki = (int*)salloc((size_t)B_ * K_ * 4);
  float* tkw = (float*)salloc((size_t)B_ * K_ * 4);
  float* upd = bigws ? nullptr : (float*)salloc((size_t)B_ * K_ * D_ * 4);

  // 1. fused copy + mean (variant B: mean only; Snew region is scratch there)
  if (bigws) sp_copymean<1><<<B_, 256, 0, stream>>>(S, Snew, mean);
  else       sp_copymean<0><<<B_, 256, 0, stream>>>(S, Snew, mean);

  // 2. one prep kernel (converts + wval^T + brow)
  sp_prep<<<1536, 256, 0, stream>>>(x, wih, whh, wout, wval, bval, bout,
                                    xb, wihb, whhb, woutb, wvalTb, brow);

  // 3. collapsed readout weights: Wro = wout @ wval (bf16)
  sp_gemm_bf16<1><<<64, 256, 0, stream>>>(woutb, wvalTb, Wrob, nullptr, D_, D_, D_, 8);

  // 4. routing MLP (f32 FMA, bit-identical to rounds 4-6)
  sp_gemm1<<<512, 256, 0, stream>>>(x, mean, w1, b1, h);

  // 5. top-k + softmax + gather (fused, f64 logit dot)
  sp_route_topk<<<B_, 64, 0, stream>>>(h, w2, b2, tau, S, tki, tkw, slotb);

  // 6. gi = x @ wih^T (bf16 MFMA, bf16 out)
  sp_gemm_bf16<1><<<384, 256, 0, stream>>>(xb, wihb, gib, nullptr, B_, G3_, D_, G3_ / 128);

  // 7. fused gh GEMM + GRU + scatter + weighted mix
  if (bigws)
    sp_gh_gru<true><<<2048, 256, 0, stream>>>(slotb, whhb, gib, bih, bhh,
                                              tki, tkw, Snew, umixb);
  else
    sp_gh_gru<false><<<2048, 256, 0, stream>>>(slotb, whhb, gib, bih, bhh,
                                               tki, tkw, upd, umixb);

  // 8. readout: out = umix @ Wro^T + brow
  sp_gemm_bf16<2><<<128, 256, 0, stream>>>(umixb, Wrob, out, brow, B_, D_, D_, 8);

  // 9. variant B: final copy+merge
  if (!bigws)
    sp_copy_scatter<<<B_, 256, 0, stream>>>(S, upd, tki, Snew);
}

// Round 10
// 782.540 us; speedup vs baseline: 1.5017x; 1.0572x over previous
//
#include <hip/hip_runtime.h>
#include <math.h>
#include <stdint.h>

#define B_   2048
#define NS_  128
#define D_   1024
#define K_   8
#define DH_  512
#define G3_  3072

typedef unsigned short u16;
typedef short bf16x8 __attribute__((ext_vector_type(8)));
typedef float f32x4 __attribute__((ext_vector_type(4)));

__device__ __forceinline__ float bf2f(u16 u) {
  union { unsigned i; float f; } v; v.i = ((unsigned)u) << 16; return v.f;
}
__device__ __forceinline__ u16 f2bf(float f) {
  unsigned x = __float_as_uint(f);
  return (u16)((x + 0x7fffu + ((x >> 16) & 1u)) >> 16);
}

#define AS1C(p) ((const __attribute__((address_space(1))) void*)(uintptr_t)(p))
#define AS3(p)  ((__attribute__((address_space(3))) void*)(unsigned)(uintptr_t)(p))

// ================= kernel 1: copymean + prep (fused, all HBM-streaming) =================
// blocks [0,2048): S->Snew copy + mean (f64 accum, NT; bit-identical to round 9)
// blocks [2048,3072): f32->bf16 converts (x, wih, whh, wout)
// blocks [3072,3328): wval transpose -> bf16
// blocks [3328,3584): brow = wout @ bval + bout
template<int DO_COPY>
__global__ __launch_bounds__(256)
void sp_copyprep(const float* __restrict__ S, float* __restrict__ Snew,
                 float* __restrict__ mean,
                 const float* __restrict__ x, const float* __restrict__ wih,
                 const float* __restrict__ whh, const float* __restrict__ wout,
                 const float* __restrict__ wval, const float* __restrict__ bval,
                 const float* __restrict__ bout,
                 u16* __restrict__ xb, u16* __restrict__ wihb,
                 u16* __restrict__ whhb, u16* __restrict__ woutb,
                 u16* __restrict__ wvalT, float* __restrict__ brow) {
  __shared__ u16 tile[64][65];
  const int blk = blockIdx.x;
  const int t = threadIdx.x;
  if (blk < 2048) {
    // ---- copymean (verbatim round 9) ----
    const int b = blk;
    const int d0 = t * 4;
    const f32x4* src = (const f32x4*)(S + (size_t)b * NS_ * D_) + t;
    f32x4* dst = (f32x4*)(Snew + (size_t)b * NS_ * D_) + t;
    double a0 = 0, a1 = 0, a2 = 0, a3 = 0;
    #pragma unroll 4
    for (int s = 0; s < NS_; ++s) {
      f32x4 v = __builtin_nontemporal_load(src);
      if (DO_COPY) __builtin_nontemporal_store(v, dst);
      a0 += v[0]; a1 += v[1]; a2 += v[2]; a3 += v[3];
      src += 256; dst += 256;
    }
    float4 m;
    m.x = (float)(a0 * (1.0 / 128.0)); m.y = (float)(a1 * (1.0 / 128.0));
    m.z = (float)(a2 * (1.0 / 128.0)); m.w = (float)(a3 * (1.0 / 128.0));
    *(float4*)&mean[(size_t)b * D_ + d0] = m;
  } else if (blk < 3072) {
    // ---- converts; f4 regions: [0,524288) xb | [524288,1310720) wihb |
    //      [1310720,2097152) whhb | [2097152,2359296) woutb ----
    const int cid = blk - 2048;
    for (int i = cid * 256 + t; i < 2359296; i += 1024 * 256) {
      const float* s; u16* d; int off;
      if (i < 524288)       { s = x;    d = xb;    off = i; }
      else if (i < 1310720) { s = wih;  d = wihb;  off = i - 524288; }
      else if (i < 2097152) { s = whh;  d = whhb;  off = i - 1310720; }
      else                  { s = wout; d = woutb; off = i - 2097152; }
      float4 v = ((const float4*)s)[off];
      ushort4 o;
      o.x = f2bf(v.x); o.y = f2bf(v.y); o.z = f2bf(v.z); o.w = f2bf(v.w);
      ((ushort4*)d)[off] = o;
    }
  } else if (blk < 3328) {
    // ---- wval transpose (verbatim round 9) ----
    const int tb = blk - 3072;
    const int bx = tb & 15, by = tb >> 4;
    const int r = t >> 4, c4 = (t & 15) * 4;
    #pragma unroll
    for (int p = 0; p < 4; ++p) {
      const int row = by * 64 + p * 16 + r;
      float4 v = *(const float4*)&wval[(size_t)row * D_ + bx * 64 + c4];
      tile[p * 16 + r][c4 + 0] = f2bf(v.x);
      tile[p * 16 + r][c4 + 1] = f2bf(v.y);
      tile[p * 16 + r][c4 + 2] = f2bf(v.z);
      tile[p * 16 + r][c4 + 3] = f2bf(v.w);
    }
    __syncthreads();
    #pragma unroll
    for (int p = 0; p < 4; ++p) {
      const int jr = p * 16 + r;
      ushort4 o;
      o.x = tile[c4 + 0][jr];
      o.y = tile[c4 + 1][jr];
      o.z = tile[c4 + 2][jr];
      o.w = tile[c4 + 3][jr];
      *(ushort4*)&wvalT[(size_t)(bx * 64 + jr) * D_ + by * 64 + c4] = o;
    }
  } else {
    // ---- brow (verbatim round 9) ----
    const int w = t >> 6, l = t & 63;
    const int i = (blk - 3328) * 4 + w;
    float s = 0.f;
    const float* wr = &wout[(size_t)i * D_ + l * 16];
    const float* bv = &bval[l * 16];
    #pragma unroll
    for (int j = 0; j < 16; j += 4) {
      float4 w4 = *(const float4*)&wr[j];
      float4 b4 = *(const float4*)&bv[j];
      s += w4.x * b4.x + w4.y * b4.y + w4.z * b4.z + w4.w * b4.w;
    }
    #pragma unroll
    for (int off = 32; off > 0; off >>= 1) s += __shfl_xor(s, off);
    if (l == 0) brow[i] = s + bout[i];
  }
}

// ================= bf16 TN MFMA GEMM body (device fn) =================
// 128x128 tile, BK=32, 4 waves, 16x16x32 MFMA, global_load_lds, XCD swizzle.
// EPI: 1=bf16 store, 2=bias+f32 store
template<int EPI>
__device__ __forceinline__ void gemm_bf16_body(
    const u16* __restrict__ A, const u16* __restrict__ Bm,
    void* __restrict__ Cv, const float* __restrict__ bias,
    int M, int N, int Kd, int nbx, int wg, u16* lA, u16* lB) {
  {
    const int nwg = nbx * ((M + 127) >> 7);
    const int cpx = nwg >> 3;               // nwg % 8 == 0 for all our shapes
    wg = (wg & 7) * cpx + (wg >> 3);
  }
  const int m0 = (wg / nbx) * 128, n0 = (wg % nbx) * 128;
  const int t = threadIdx.x;
  const int lane = t & 63;
  const int w = t >> 6;
  const int wm = w >> 1, wn = w & 1;

  f32x4 acc[4][4] = {};

  const int srow = t >> 2;
  const int scol = (t & 3) * 8;
  const u16* gA0 = A + (size_t)(m0 + srow) * Kd + scol;
  const u16* gA1 = A + (size_t)(m0 + 64 + srow) * Kd + scol;
  const u16* gB0 = Bm + (size_t)(n0 + srow) * Kd + scol;
  const u16* gB1 = Bm + (size_t)(n0 + 64 + srow) * Kd + scol;
  u16* lAw = lA + (t & 192) * 8;
  u16* lBw = lB + (t & 192) * 8;

  const int kb = (lane >> 4) * 8;
  const int rA = wm * 64 + (lane & 15);
  const int rB = wn * 64 + (lane & 15);

  for (int k0 = 0; k0 < Kd; k0 += 32) {
    __builtin_amdgcn_global_load_lds(AS1C(gA0 + k0), AS3(lAw), 16, 0, 0);
    __builtin_amdgcn_global_load_lds(AS1C(gA1 + k0), AS3(lAw + 2048), 16, 0, 0);
    __builtin_amdgcn_global_load_lds(AS1C(gB0 + k0), AS3(lBw), 16, 0, 0);
    __builtin_amdgcn_global_load_lds(AS1C(gB1 + k0), AS3(lBw + 2048), 16, 0, 0);
    __syncthreads();
    bf16x8 af[4], bfr[4];
    #pragma unroll
    for (int fm = 0; fm < 4; ++fm)
      af[fm] = *(const bf16x8*)&lA[(rA + fm * 16) * 32 + kb];
    #pragma unroll
    for (int fn = 0; fn < 4; ++fn)
      bfr[fn] = *(const bf16x8*)&lB[(rB + fn * 16) * 32 + kb];
    #pragma unroll
    for (int fm = 0; fm < 4; ++fm) {
      #pragma unroll
      for (int fn = 0; fn < 4; ++fn)
        acc[fm][fn] = __builtin_amdgcn_mfma_f32_16x16x32_bf16(af[fm], bfr[fn], acc[fm][fn], 0, 0, 0);
    }
    __syncthreads();
  }

  #pragma unroll
  for (int fm = 0; fm < 4; ++fm) {
    #pragma unroll
    for (int fn = 0; fn < 4; ++fn) {
      #pragma unroll
      for (int i = 0; i < 4; ++i) {
        const int r = m0 + wm * 64 + fm * 16 + (lane >> 4) * 4 + i;
        const int c = n0 + wn * 64 + fn * 16 + (lane & 15);
        float v = acc[fm][fn][i];
        if constexpr (EPI == 2) {
          ((float*)Cv)[(size_t)r * N + c] = v + bias[c];
        } else {
          ((u16*)Cv)[(size_t)r * N + c] = f2bf(v);
        }
      }
    }
  }
}

// ================= kernel 2: mid (gi GEMM + gemm1 + Wro GEMM, independent) =================
// blocks [0,384): gi = x@wih^T (bf16 MFMA, M=2048,N=3072,K=1024)
// blocks [384,640): h = gelu(ctx@w1^T+b1) f32 reg-blocked (bit-identical k-order)
// blocks [640,704): Wro = wout@wval (bf16 MFMA via wval^T, M=N=K=1024)
__global__ __launch_bounds__(256)
void sp_mid(const u16* __restrict__ xb, const u16* __restrict__ wihb,
            u16* __restrict__ gib,
            const float* __restrict__ x, const float* __restrict__ mean,
            const float* __restrict__ w1, const float* __restrict__ b1,
            float* __restrict__ h,
            const u16* __restrict__ woutb, const u16* __restrict__ wvalTb,
            u16* __restrict__ Wrob) {
  __shared__ u16 lA[128 * 32];
  __shared__ u16 lB[128 * 32];
  const int blk = blockIdx.x;
  const int t = threadIdx.x;
  if (blk < 384) {
    gemm_bf16_body<1>(xb, wihb, gib, nullptr, B_, G3_, D_, G3_ / 128, blk, lA, lB);
  } else if (blk < 640) {
    // ---- gemm1: BM=64, BN=64, BK=16, 4x4 acc/thread, k-sequential fmaf ----
    float (*As)[68] = (float(*)[68])lA;   // 16*68*4 = 4352 B (in lA's 8192)
    float (*Bs)[68] = (float(*)[68])lB;
    int wg = blk - 384;
    wg = (wg & 7) * 32 + (wg >> 3);       // bijective XCD swizzle, 256 wgs
    const int m0 = (wg >> 3) * 64;        // 32 m-tiles
    const int n0 = (wg & 7) * 64;         // 8 n-tiles
    const int tx = t & 15, ty = t >> 4;
    float acc[4][4] = {};
    const int sr = t >> 2, sc = (t & 3) * 4;
    for (int k0 = 0; k0 < 2 * D_; k0 += 16) {
      const float* src = (k0 < D_) ? (x + k0) : (mean + (k0 - D_));
      float4 va = *(const float4*)&src[(size_t)(m0 + sr) * D_ + sc];
      As[sc + 0][sr] = va.x; As[sc + 1][sr] = va.y; As[sc + 2][sr] = va.z; As[sc + 3][sr] = va.w;
      float4 vb = *(const float4*)&w1[(size_t)(n0 + sr) * (2 * D_) + k0 + sc];
      Bs[sc + 0][sr] = vb.x; Bs[sc + 1][sr] = vb.y; Bs[sc + 2][sr] = vb.z; Bs[sc + 3][sr] = vb.w;
      __syncthreads();
      #pragma unroll
      for (int kk = 0; kk < 16; ++kk) {
        float4 a4 = *(const float4*)&As[kk][ty * 4];
        float4 b4 = *(const float4*)&Bs[kk][tx * 4];
        acc[0][0] = fmaf(a4.x, b4.x, acc[0][0]); acc[0][1] = fmaf(a4.x, b4.y, acc[0][1]);
        acc[0][2] = fmaf(a4.x, b4.z, acc[0][2]); acc[0][3] = fmaf(a4.x, b4.w, acc[0][3]);
        acc[1][0] = fmaf(a4.y, b4.x, acc[1][0]); acc[1][1] = fmaf(a4.y, b4.y, acc[1][1]);
        acc[1][2] = fmaf(a4.y, b4.z, acc[1][2]); acc[1][3] = fmaf(a4.y, b4.w, acc[1][3]);
        acc[2][0] = fmaf(a4.z, b4.x, acc[2][0]); acc[2][1] = fmaf(a4.z, b4.y, acc[2][1]);
        acc[2][2] = fmaf(a4.z, b4.z, acc[2][2]); acc[2][3] = fmaf(a4.z, b4.w, acc[2][3]);
        acc[3][0] = fmaf(a4.w, b4.x, acc[3][0]); acc[3][1] = fmaf(a4.w, b4.y, acc[3][1]);
        acc[3][2] = fmaf(a4.w, b4.z, acc[3][2]); acc[3][3] = fmaf(a4.w, b4.w, acc[3][3]);
      }
      __syncthreads();
    }
    #pragma unroll
    for (int i = 0; i < 4; ++i) {
      #pragma unroll
      for (int j = 0; j < 4; ++j) {
        const int r = m0 + ty * 4 + i, c = n0 + tx * 4 + j;
        float v = acc[i][j] + b1[c];
        v = 0.5f * v * (1.0f + erff(v * 0.70710678118654752f));
        h[(size_t)r * DH_ + c] = v;
      }
    }
  } else {
    gemm_bf16_body<1>(woutb, wvalTb, Wrob, nullptr, D_, D_, D_, 8, blk - 640, lA, lB);
  }
}

// ================= kernel 3: logits + top-8 + softmax + gather =================
__global__ __launch_bounds__(64)
void sp_route_topk(const float* __restrict__ h, const float* __restrict__ w2,
                   const float* __restrict__ b2, const float* __restrict__ tau,
                   const float* __restrict__ S,
                   int* __restrict__ tki, float* __restrict__ tkw,
                   u16* __restrict__ slotb) {
  __shared__ float hs[DH_];
  __shared__ int sTki[K_];
  const int b = blockIdx.x, l = threadIdx.x;
  *(float4*)&hs[l * 4] = *(const float4*)&h[(size_t)b * DH_ + l * 4];
  *(float4*)&hs[256 + l * 4] = *(const float4*)&h[(size_t)b * DH_ + 256 + l * 4];
  __syncthreads();
  const double invd = 1.0 / ((double)fabsf(tau[0]) + 0.1);
  float v[2]; int id[2];
  #pragma unroll
  for (int c = 0; c < 2; ++c) {
    const int n = c * 64 + l;
    const float* wr = &w2[(size_t)n * DH_];
    double s = 0.0;
    for (int j = 0; j < DH_; j += 4) {
      float4 w4 = *(const float4*)&wr[j];
      s += (double)hs[j] * (double)w4.x;
      s += (double)hs[j + 1] * (double)w4.y;
      s += (double)hs[j + 2] * (double)w4.z;
      s += (double)hs[j + 3] * (double)w4.w;
    }
    v[c] = (float)((s + (double)b2[n]) * invd);
    id[c] = n;
  }
  float m0f = 0.f, sum = 0.f, mye = 0.f; int myi = 0;
  for (int r = 0; r < 8; ++r) {
    float mv; int mi;
    if (v[1] > v[0]) { mv = v[1]; mi = id[1]; } else { mv = v[0]; mi = id[0]; }
    #pragma unroll
    for (int off = 32; off > 0; off >>= 1) {
      float ov = __shfl_xor(mv, off);
      int oi = __shfl_xor(mi, off);
      if (ov > mv || (ov == mv && oi < mi)) { mv = ov; mi = oi; }
    }
    if (r == 0) m0f = mv;
    float er = expf(mv - m0f);
    sum += er;
    if (l == r) { mye = er; myi = mi; }
    if (mi == id[0]) v[0] = -3.0e38f;
    if (mi == id[1]) v[1] = -3.0e38f;
  }
  if (l < 8) {
    tki[b * K_ + l] = myi; tkw[b * K_ + l] = mye / sum;
    sTki[l] = myi;
  }
  __syncthreads();
  #pragma unroll
  for (int k = 0; k < K_; ++k) {
    const int s = sTki[k];
    const float4* src = (const float4*)&S[((size_t)b * NS_ + s) * D_];
    ushort4* dst = (ushort4*)&slotb[((size_t)b * K_ + k) * D_];
    #pragma unroll
    for (int c = 0; c < 4; ++c) {
      float4 vv = src[c * 64 + l];
      ushort4 o;
      o.x = f2bf(vv.x); o.y = f2bf(vv.y); o.z = f2bf(vv.z); o.w = f2bf(vv.w);
      dst[c * 64 + l] = o;
    }
  }
}

// ================= standalone bf16 GEMM wrapper (readout) =================
template<int EPI>
__global__ __launch_bounds__(256)
void sp_gemm_bf16(const u16* __restrict__ A, const u16* __restrict__ Bm,
                  void* __restrict__ Cv, const float* __restrict__ bias,
                  int M, int N, int Kd, int nbx) {
  __shared__ u16 lA[128 * 32];
  __shared__ u16 lB[128 * 32];
  gemm_bf16_body<EPI>(A, Bm, Cv, bias, M, N, Kd, nbx, blockIdx.x, lA, lB);
}

// ================= kernel 4: fused gh GEMM + GRU + scatter + weighted mix =================
// Tile: 128 rows x (3 gates x 64 d-cols). 4 waves (2x2). acc[fm(4)][fn(6)], fn = gate*2+f.
template<bool DIRECT>
__global__ __launch_bounds__(256, 2)
void sp_gh_gru(const u16* __restrict__ slotb, const u16* __restrict__ whhb,
               const u16* __restrict__ gib, const float* __restrict__ bih,
               const float* __restrict__ bhh, const int* __restrict__ tki,
               const float* __restrict__ tkw, float* __restrict__ dst,
               u16* __restrict__ umixb) {
  __shared__ u16 lA[128 * 32];
  __shared__ u16 lB[192 * 32];
  __shared__ int   sTki[128];
  __shared__ float sTkw[128];
  int wg = blockIdx.x;
  wg = (wg & 7) * 256 + (wg >> 3);
  const int mt = wg >> 4, db = wg & 15;
  const int m0 = mt * 128, d0 = db * 64;
  const int t = threadIdx.x;
  const int lane = t & 63, w = t >> 6;
  const int wm = w >> 1, wn = w & 1;
  const int lane15 = lane & 15, hi = lane >> 4;

  if (t < 128) { sTki[t] = tki[m0 + t]; sTkw[t] = tkw[m0 + t]; }

  f32x4 acc[4][6] = {};

  const int srow = t >> 2;
  const int scol = (t & 3) * 8;
  const u16* gA0 = slotb + (size_t)(m0 + srow) * D_ + scol;
  const u16* gA1 = slotb + (size_t)(m0 + 64 + srow) * D_ + scol;
  const u16* gB0 = whhb + (size_t)(d0 + srow) * D_ + scol;
  const u16* gB1 = whhb + (size_t)(D_ + d0 + srow) * D_ + scol;
  const u16* gB2 = whhb + (size_t)(2 * D_ + d0 + srow) * D_ + scol;
  u16* lAw = &lA[(t & 192) * 8];
  u16* lBw = &lB[(t & 192) * 8];

  const int kb = hi * 8;
  const int rA = wm * 64 + lane15;
  const int rB = wn * 32 + lane15;

  for (int k0 = 0; k0 < D_; k0 += 32) {
    __builtin_amdgcn_global_load_lds(AS1C(gA0 + k0), AS3(lAw), 16, 0, 0);
    __builtin_amdgcn_global_load_lds(AS1C(gA1 + k0), AS3(lAw + 2048), 16, 0, 0);
    __builtin_amdgcn_global_load_lds(AS1C(gB0 + k0), AS3(lBw), 16, 0, 0);
    __builtin_amdgcn_global_load_lds(AS1C(gB1 + k0), AS3(lBw + 2048), 16, 0, 0);
    __builtin_amdgcn_global_load_lds(AS1C(gB2 + k0), AS3(lBw + 4096), 16, 0, 0);
    __syncthreads();
    bf16x8 af[4], bfr[6];
    #pragma unroll
    for (int fm = 0; fm < 4; ++fm)
      af[fm] = *(const bf16x8*)&lA[(rA + fm * 16) * 32 + kb];
    #pragma unroll
    for (int g = 0; g < 3; ++g) {
      #pragma unroll
      for (int f = 0; f < 2; ++f)
        bfr[g * 2 + f] = *(const bf16x8*)&lB[(g * 64 + rB + f * 16) * 32 + kb];
    }
    #pragma unroll
    for (int fm = 0; fm < 4; ++fm) {
      #pragma unroll
      for (int fn = 0; fn < 6; ++fn)
        acc[fm][fn] = __builtin_amdgcn_mfma_f32_16x16x32_bf16(af[fm], bfr[fn], acc[fm][fn], 0, 0, 0);
    }
    __syncthreads();
  }

  #pragma unroll
  for (int fm = 0; fm < 4; ++fm) {
    const int rbase = wm * 64 + fm * 16 + hi * 4;     // 4 rows, same batch
    const int bglob = (m0 + rbase) >> 3;
    #pragma unroll
    for (int f = 0; f < 2; ++f) {
      const int dg = d0 + wn * 32 + f * 16 + lane15;  // d within [0,1024)
      const float Gr = bf2f(gib[(size_t)bglob * G3_ + dg])          + bih[dg];
      const float Gz = bf2f(gib[(size_t)bglob * G3_ + D_ + dg])     + bih[D_ + dg];
      const float Gn = bf2f(gib[(size_t)bglob * G3_ + 2 * D_ + dg]) + bih[2 * D_ + dg];
      const float Br = bhh[dg], Bz = bhh[D_ + dg], Bn = bhh[2 * D_ + dg];
      float part = 0.f;
      #pragma unroll
      for (int i = 0; i < 4; ++i) {
        const int row = rbase + i;
        const int grow = m0 + row;
        const float slot = bf2f(slotb[(size_t)grow * D_ + dg]);
        const float rr = acc[fm][f][i] + Br;
        const float zz = acc[fm][f + 2][i] + Bz;
        const float nn = acc[fm][f + 4][i] + Bn;
        const float rg = 1.f / (1.f + expf(-(Gr + rr)));
        const float zg = 1.f / (1.f + expf(-(Gz + zz)));
        const float ng = tanhf(Gn + rg * nn);
        const float uv = (1.f - zg) * ng + zg * slot;
        part = fmaf(sTkw[row], uv, part);
        if (DIRECT)
          dst[((size_t)bglob * NS_ + sTki[row]) * D_ + dg] = uv;
        else
          dst[(size_t)grow * D_ + dg] = uv;
      }
      part += __shfl_xor(part, 16);
      if ((hi & 1) == 0)
        umixb[(size_t)bglob * D_ + dg] = f2bf(part);
    }
  }
}

// ================= variant B: copy S->S_new with merge of updated rows =================
__global__ __launch_bounds__(256)
void sp_copy_scatter(const float* __restrict__ S, const float* __restrict__ upd,
                     const int* __restrict__ tki, float* __restrict__ Snew) {
  const int b = blockIdx.x, t = threadIdx.x;
  const int d0 = t * 4;
  int idx[K_];
  #pragma unroll
  for (int k = 0; k < K_; ++k) idx[k] = tki[b * K_ + k];
  for (int s = 0; s < NS_; ++s) {
    int sk = -1;
    #pragma unroll
    for (int k = 0; k < K_; ++k) if (idx[k] == s) sk = k;
    float4 v;
    if (sk >= 0) v = *(const float4*)&upd[((size_t)b * K_ + sk) * D_ + d0];
    else         v = *(const float4*)&S[((size_t)b * NS_ + s) * D_ + d0];
    *(float4*)&Snew[((size_t)b * NS_ + s) * D_ + d0] = v;
  }
}

extern "C" void kernel_launch(void* const* d_in, const int* in_sizes, int n_in,
                              void* d_out, int out_size, void* d_ws, size_t ws_size,
                              hipStream_t stream) {
  const float* x    = (const float*)d_in[0];
  const float* S    = (const float*)d_in[1];
  const float* w1   = (const float*)d_in[2];
  const float* b1   = (const float*)d_in[3];
  const float* w2   = (const float*)d_in[4];
  const float* b2   = (const float*)d_in[5];
  const float* wih  = (const float*)d_in[6];
  const float* whh  = (const float*)d_in[7];
  const float* bih  = (const float*)d_in[8];
  const float* bhh  = (const float*)d_in[9];
  const float* wval = (const float*)d_in[10];
  const float* bval = (const float*)d_in[11];
  const float* wout = (const float*)d_in[12];
  const float* bout = (const float*)d_in[13];
  const float* tau  = (const float*)d_in[14];

  float* out  = (float*)d_out;
  float* Snew = out + (size_t)B_ * D_;

  const bool bigws = ws_size >= (size_t)400 * 1024 * 1024;
  char* bigbase = bigws ? (char*)d_ws : (char*)Snew;  // variant B: scratch in S_new region
  size_t bo = 0;
  auto balloc = [&](size_t bytes) -> void* {
    void* p = bigbase + bo; bo += (bytes + 255) & ~(size_t)255; return p;
  };

  float* mean  = (float*)balloc((size_t)B_ * D_ * 4);
  float* h     = (float*)balloc((size_t)B_ * DH_ * 4);
  u16* xb      = (u16*)balloc((size_t)B_ * D_ * 2);
  u16* wihb    = (u16*)balloc((size_t)G3_ * D_ * 2);
  u16* whhb    = (u16*)balloc((size_t)G3_ * D_ * 2);
  u16* woutb   = (u16*)balloc((size_t)D_ * D_ * 2);
  u16* wvalTb  = (u16*)balloc((size_t)D_ * D_ * 2);
  u16* Wrob    = (u16*)balloc((size_t)D_ * D_ * 2);
  u16* gib     = (u16*)balloc((size_t)B_ * G3_ * 2);
  u16* slotb   = (u16*)balloc((size_t)B_ * K_ * D_ * 2);
  u16* umixb   = (u16*)balloc((size_t)B_ * D_ * 2);
  float* brow  = (float*)balloc((size_t)D_ * 4);

  // small buffers always live in d_ws
  char* wsb = (char*)d_ws;
  size_t so = bigws ? bo : 0;
  auto salloc = [&](size_t bytes) -> void* {
    void* p = wsb + so; so += (bytes + 255) & ~(size_t)255; return p;
  };
  int*   tki = (int*)salloc((size_t)B_ * K_ * 4);
  float* tkw = (float*)salloc((size_t)B_ * K_ * 4);
  float* upd = bigws ? nullptr : (float*)salloc((size_t)B_ * K_ * D_ * 4);

  // 1. copymean + prep (fused; variant B: mean only, Snew region is scratch)
  if (bigws)
    sp_copyprep<1><<<3584, 256, 0, stream>>>(S, Snew, mean, x, wih, whh, wout,
                                             wval, bval, bout, xb, wihb, whhb,
                                             woutb, wvalTb, brow);
  else
    sp_copyprep<0><<<3584, 256, 0, stream>>>(S, Snew, mean, x, wih, whh, wout,
                                             wval, bval, bout, xb, wihb, whhb,
                                             woutb, wvalTb, brow);

  // 2. mid: gi GEMM + routing gemm1 + Wro GEMM (mutually independent)
  sp_mid<<<704, 256, 0, stream>>>(xb, wihb, gib, x, mean, w1, b1, h,
                                  woutb, wvalTb, Wrob);

  // 3. top-k + softmax + gather
  sp_route_topk<<<B_, 64, 0, stream>>>(h, w2, b2, tau, S, tki, tkw, slotb);

  // 4. fused gh GEMM + GRU + scatter + weighted mix
  if (bigws)
    sp_gh_gru<true><<<2048, 256, 0, stream>>>(slotb, whhb, gib, bih, bhh,
                                              tki, tkw, Snew, umixb);
  else
    sp_gh_gru<false><<<2048, 256, 0, stream>>>(slotb, whhb, gib, bih, bhh,
                                               tki, tkw, upd, umixb);

  // 5. readout: out = umix @ Wro^T + brow
  sp_gemm_bf16<2><<<128, 256, 0, stream>>>(umixb, Wrob, out, brow, B_, D_, D_, 8);

  // 6. variant B: final copy+merge
  if (!bigws)
    sp_copy_scatter<<<B_, 256, 0, stream>>>(S, upd, tki, Snew);
}

// Round 11
// 782.435 us; speedup vs baseline: 1.5019x; 1.0001x over previous
//
#include <hip/hip_runtime.h>
#include <math.h>
#include <stdint.h>

#define B_   2048
#define NS_  128
#define D_   1024
#define K_   8
#define DH_  512
#define G3_  3072

typedef unsigned short u16;
typedef short bf16x8 __attribute__((ext_vector_type(8)));
typedef float f32x4 __attribute__((ext_vector_type(4)));

__device__ __forceinline__ float bf2f(u16 u) {
  union { unsigned i; float f; } v; v.i = ((unsigned)u) << 16; return v.f;
}
__device__ __forceinline__ u16 f2bf(float f) {
  unsigned x = __float_as_uint(f);
  return (u16)((x + 0x7fffu + ((x >> 16) & 1u)) >> 16);
}

#define AS1C(p) ((const __attribute__((address_space(1))) void*)(uintptr_t)(p))
#define AS3(p)  ((__attribute__((address_space(3))) void*)(unsigned)(uintptr_t)(p))

// ================= kernel 1: copymean + prep (fused, all HBM-streaming) =================
template<int DO_COPY>
__global__ __launch_bounds__(256)
void sp_copyprep(const float* __restrict__ S, float* __restrict__ Snew,
                 float* __restrict__ mean,
                 const float* __restrict__ x, const float* __restrict__ wih,
                 const float* __restrict__ whh, const float* __restrict__ wout,
                 const float* __restrict__ wval, const float* __restrict__ bval,
                 const float* __restrict__ bout,
                 u16* __restrict__ xb, u16* __restrict__ wihb,
                 u16* __restrict__ whhb, u16* __restrict__ woutb,
                 u16* __restrict__ wvalT, float* __restrict__ brow) {
  __shared__ u16 tile[64][65];
  const int blk = blockIdx.x;
  const int t = threadIdx.x;
  if (blk < 2048) {
    // ---- copymean (verbatim round 9/10) ----
    const int b = blk;
    const int d0 = t * 4;
    const f32x4* src = (const f32x4*)(S + (size_t)b * NS_ * D_) + t;
    f32x4* dst = (f32x4*)(Snew + (size_t)b * NS_ * D_) + t;
    double a0 = 0, a1 = 0, a2 = 0, a3 = 0;
    #pragma unroll 4
    for (int s = 0; s < NS_; ++s) {
      f32x4 v = __builtin_nontemporal_load(src);
      if (DO_COPY) __builtin_nontemporal_store(v, dst);
      a0 += v[0]; a1 += v[1]; a2 += v[2]; a3 += v[3];
      src += 256; dst += 256;
    }
    float4 m;
    m.x = (float)(a0 * (1.0 / 128.0)); m.y = (float)(a1 * (1.0 / 128.0));
    m.z = (float)(a2 * (1.0 / 128.0)); m.w = (float)(a3 * (1.0 / 128.0));
    *(float4*)&mean[(size_t)b * D_ + d0] = m;
  } else if (blk < 3072) {
    const int cid = blk - 2048;
    for (int i = cid * 256 + t; i < 2359296; i += 1024 * 256) {
      const float* s; u16* d; int off;
      if (i < 524288)       { s = x;    d = xb;    off = i; }
      else if (i < 1310720) { s = wih;  d = wihb;  off = i - 524288; }
      else if (i < 2097152) { s = whh;  d = whhb;  off = i - 1310720; }
      else                  { s = wout; d = woutb; off = i - 2097152; }
      float4 v = ((const float4*)s)[off];
      ushort4 o;
      o.x = f2bf(v.x); o.y = f2bf(v.y); o.z = f2bf(v.z); o.w = f2bf(v.w);
      ((ushort4*)d)[off] = o;
    }
  } else if (blk < 3328) {
    const int tb = blk - 3072;
    const int bx = tb & 15, by = tb >> 4;
    const int r = t >> 4, c4 = (t & 15) * 4;
    #pragma unroll
    for (int p = 0; p < 4; ++p) {
      const int row = by * 64 + p * 16 + r;
      float4 v = *(const float4*)&wval[(size_t)row * D_ + bx * 64 + c4];
      tile[p * 16 + r][c4 + 0] = f2bf(v.x);
      tile[p * 16 + r][c4 + 1] = f2bf(v.y);
      tile[p * 16 + r][c4 + 2] = f2bf(v.z);
      tile[p * 16 + r][c4 + 3] = f2bf(v.w);
    }
    __syncthreads();
    #pragma unroll
    for (int p = 0; p < 4; ++p) {
      const int jr = p * 16 + r;
      ushort4 o;
      o.x = tile[c4 + 0][jr];
      o.y = tile[c4 + 1][jr];
      o.z = tile[c4 + 2][jr];
      o.w = tile[c4 + 3][jr];
      *(ushort4*)&wvalT[(size_t)(bx * 64 + jr) * D_ + by * 64 + c4] = o;
    }
  } else {
    const int w = t >> 6, l = t & 63;
    const int i = (blk - 3328) * 4 + w;
    float s = 0.f;
    const float* wr = &wout[(size_t)i * D_ + l * 16];
    const float* bv = &bval[l * 16];
    #pragma unroll
    for (int j = 0; j < 16; j += 4) {
      float4 w4 = *(const float4*)&wr[j];
      float4 b4 = *(const float4*)&bv[j];
      s += w4.x * b4.x + w4.y * b4.y + w4.z * b4.z + w4.w * b4.w;
    }
    #pragma unroll
    for (int off = 32; off > 0; off >>= 1) s += __shfl_xor(s, off);
    if (l == 0) brow[i] = s + bout[i];
  }
}

// ================= bf16 TN MFMA GEMM body (device fn) =================
template<int EPI>
__device__ __forceinline__ void gemm_bf16_body(
    const u16* __restrict__ A, const u16* __restrict__ Bm,
    void* __restrict__ Cv, const float* __restrict__ bias,
    int M, int N, int Kd, int nbx, int wg, u16* lA, u16* lB) {
  {
    const int nwg = nbx * ((M + 127) >> 7);
    const int cpx = nwg >> 3;               // nwg % 8 == 0 for all our shapes
    wg = (wg & 7) * cpx + (wg >> 3);
  }
  const int m0 = (wg / nbx) * 128, n0 = (wg % nbx) * 128;
  const int t = threadIdx.x;
  const int lane = t & 63;
  const int w = t >> 6;
  const int wm = w >> 1, wn = w & 1;

  f32x4 acc[4][4] = {};

  const int srow = t >> 2;
  const int scol = (t & 3) * 8;
  const u16* gA0 = A + (size_t)(m0 + srow) * Kd + scol;
  const u16* gA1 = A + (size_t)(m0 + 64 + srow) * Kd + scol;
  const u16* gB0 = Bm + (size_t)(n0 + srow) * Kd + scol;
  const u16* gB1 = Bm + (size_t)(n0 + 64 + srow) * Kd + scol;
  u16* lAw = lA + (t & 192) * 8;
  u16* lBw = lB + (t & 192) * 8;

  const int kb = (lane >> 4) * 8;
  const int rA = wm * 64 + (lane & 15);
  const int rB = wn * 64 + (lane & 15);

  for (int k0 = 0; k0 < Kd; k0 += 32) {
    __builtin_amdgcn_global_load_lds(AS1C(gA0 + k0), AS3(lAw), 16, 0, 0);
    __builtin_amdgcn_global_load_lds(AS1C(gA1 + k0), AS3(lAw + 2048), 16, 0, 0);
    __builtin_amdgcn_global_load_lds(AS1C(gB0 + k0), AS3(lBw), 16, 0, 0);
    __builtin_amdgcn_global_load_lds(AS1C(gB1 + k0), AS3(lBw + 2048), 16, 0, 0);
    __syncthreads();
    bf16x8 af[4], bfr[4];
    #pragma unroll
    for (int fm = 0; fm < 4; ++fm)
      af[fm] = *(const bf16x8*)&lA[(rA + fm * 16) * 32 + kb];
    #pragma unroll
    for (int fn = 0; fn < 4; ++fn)
      bfr[fn] = *(const bf16x8*)&lB[(rB + fn * 16) * 32 + kb];
    #pragma unroll
    for (int fm = 0; fm < 4; ++fm) {
      #pragma unroll
      for (int fn = 0; fn < 4; ++fn)
        acc[fm][fn] = __builtin_amdgcn_mfma_f32_16x16x32_bf16(af[fm], bfr[fn], acc[fm][fn], 0, 0, 0);
    }
    __syncthreads();
  }

  #pragma unroll
  for (int fm = 0; fm < 4; ++fm) {
    #pragma unroll
    for (int fn = 0; fn < 4; ++fn) {
      #pragma unroll
      for (int i = 0; i < 4; ++i) {
        const int r = m0 + wm * 64 + fm * 16 + (lane >> 4) * 4 + i;
        const int c = n0 + wn * 64 + fn * 16 + (lane & 15);
        float v = acc[fm][fn][i];
        if constexpr (EPI == 2) {
          ((float*)Cv)[(size_t)r * N + c] = v + bias[c];
        } else {
          ((u16*)Cv)[(size_t)r * N + c] = f2bf(v);
        }
      }
    }
  }
}

// ================= kernel 2: mid (gi GEMM + gemm1 + Wro GEMM, independent) =================
__global__ __launch_bounds__(256)
void sp_mid(const u16* __restrict__ xb, const u16* __restrict__ wihb,
            u16* __restrict__ gib,
            const float* __restrict__ x, const float* __restrict__ mean,
            const float* __restrict__ w1, const float* __restrict__ b1,
            float* __restrict__ h,
            const u16* __restrict__ woutb, const u16* __restrict__ wvalTb,
            u16* __restrict__ Wrob) {
  __shared__ u16 lA[128 * 32];
  __shared__ u16 lB[128 * 32];
  const int blk = blockIdx.x;
  const int t = threadIdx.x;
  if (blk < 384) {
    gemm_bf16_body<1>(xb, wihb, gib, nullptr, B_, G3_, D_, G3_ / 128, blk, lA, lB);
  } else if (blk < 640) {
    // ---- gemm1: BM=64, BN=64, BK=16, 4x4 acc/thread, k-sequential fmaf ----
    float (*As)[68] = (float(*)[68])lA;
    float (*Bs)[68] = (float(*)[68])lB;
    int wg = blk - 384;
    wg = (wg & 7) * 32 + (wg >> 3);       // bijective XCD swizzle, 256 wgs
    const int m0 = (wg >> 3) * 64;
    const int n0 = (wg & 7) * 64;
    const int tx = t & 15, ty = t >> 4;
    float acc[4][4] = {};
    const int sr = t >> 2, sc = (t & 3) * 4;
    for (int k0 = 0; k0 < 2 * D_; k0 += 16) {
      const float* src = (k0 < D_) ? (x + k0) : (mean + (k0 - D_));
      float4 va = *(const float4*)&src[(size_t)(m0 + sr) * D_ + sc];
      As[sc + 0][sr] = va.x; As[sc + 1][sr] = va.y; As[sc + 2][sr] = va.z; As[sc + 3][sr] = va.w;
      float4 vb = *(const float4*)&w1[(size_t)(n0 + sr) * (2 * D_) + k0 + sc];
      Bs[sc + 0][sr] = vb.x; Bs[sc + 1][sr] = vb.y; Bs[sc + 2][sr] = vb.z; Bs[sc + 3][sr] = vb.w;
      __syncthreads();
      #pragma unroll
      for (int kk = 0; kk < 16; ++kk) {
        float4 a4 = *(const float4*)&As[kk][ty * 4];
        float4 b4 = *(const float4*)&Bs[kk][tx * 4];
        acc[0][0] = fmaf(a4.x, b4.x, acc[0][0]); acc[0][1] = fmaf(a4.x, b4.y, acc[0][1]);
        acc[0][2] = fmaf(a4.x, b4.z, acc[0][2]); acc[0][3] = fmaf(a4.x, b4.w, acc[0][3]);
        acc[1][0] = fmaf(a4.y, b4.x, acc[1][0]); acc[1][1] = fmaf(a4.y, b4.y, acc[1][1]);
        acc[1][2] = fmaf(a4.y, b4.z, acc[1][2]); acc[1][3] = fmaf(a4.y, b4.w, acc[1][3]);
        acc[2][0] = fmaf(a4.z, b4.x, acc[2][0]); acc[2][1] = fmaf(a4.z, b4.y, acc[2][1]);
        acc[2][2] = fmaf(a4.z, b4.z, acc[2][2]); acc[2][3] = fmaf(a4.z, b4.w, acc[2][3]);
        acc[3][0] = fmaf(a4.w, b4.x, acc[3][0]); acc[3][1] = fmaf(a4.w, b4.y, acc[3][1]);
        acc[3][2] = fmaf(a4.w, b4.z, acc[3][2]); acc[3][3] = fmaf(a4.w, b4.w, acc[3][3]);
      }
      __syncthreads();
    }
    #pragma unroll
    for (int i = 0; i < 4; ++i) {
      #pragma unroll
      for (int j = 0; j < 4; ++j) {
        const int r = m0 + ty * 4 + i, c = n0 + tx * 4 + j;
        float v = acc[i][j] + b1[c];
        v = 0.5f * v * (1.0f + erff(v * 0.70710678118654752f));
        h[(size_t)r * DH_ + c] = v;
      }
    }
  } else {
    gemm_bf16_body<1>(woutb, wvalTb, Wrob, nullptr, D_, D_, D_, 8, blk - 640, lA, lB);
  }
}

// ================= kernel 3: logits + top-8 + softmax + gather =================
__global__ __launch_bounds__(64)
void sp_route_topk(const float* __restrict__ h, const float* __restrict__ w2,
                   const float* __restrict__ b2, const float* __restrict__ tau,
                   const float* __restrict__ S,
                   int* __restrict__ tki, float* __restrict__ tkw,
                   u16* __restrict__ slotb) {
  __shared__ float hs[DH_];
  __shared__ int sTki[K_];
  const int b = blockIdx.x, l = threadIdx.x;
  *(float4*)&hs[l * 4] = *(const float4*)&h[(size_t)b * DH_ + l * 4];
  *(float4*)&hs[256 + l * 4] = *(const float4*)&h[(size_t)b * DH_ + 256 + l * 4];
  __syncthreads();
  const double invd = 1.0 / ((double)fabsf(tau[0]) + 0.1);
  float v[2]; int id[2];
  #pragma unroll
  for (int c = 0; c < 2; ++c) {
    const int n = c * 64 + l;
    const float* wr = &w2[(size_t)n * DH_];
    double s = 0.0;
    for (int j = 0; j < DH_; j += 4) {
      float4 w4 = *(const float4*)&wr[j];
      s += (double)hs[j] * (double)w4.x;
      s += (double)hs[j + 1] * (double)w4.y;
      s += (double)hs[j + 2] * (double)w4.z;
      s += (double)hs[j + 3] * (double)w4.w;
    }
    v[c] = (float)((s + (double)b2[n]) * invd);
    id[c] = n;
  }
  float m0f = 0.f, sum = 0.f, mye = 0.f; int myi = 0;
  for (int r = 0; r < 8; ++r) {
    float mv; int mi;
    if (v[1] > v[0]) { mv = v[1]; mi = id[1]; } else { mv = v[0]; mi = id[0]; }
    #pragma unroll
    for (int off = 32; off > 0; off >>= 1) {
      float ov = __shfl_xor(mv, off);
      int oi = __shfl_xor(mi, off);
      if (ov > mv || (ov == mv && oi < mi)) { mv = ov; mi = oi; }
    }
    if (r == 0) m0f = mv;
    float er = expf(mv - m0f);
    sum += er;
    if (l == r) { mye = er; myi = mi; }
    if (mi == id[0]) v[0] = -3.0e38f;
    if (mi == id[1]) v[1] = -3.0e38f;
  }
  if (l < 8) {
    tki[b * K_ + l] = myi; tkw[b * K_ + l] = mye / sum;
    sTki[l] = myi;
  }
  __syncthreads();
  #pragma unroll
  for (int k = 0; k < K_; ++k) {
    const int s = sTki[k];
    const float4* src = (const float4*)&S[((size_t)b * NS_ + s) * D_];
    ushort4* dst = (ushort4*)&slotb[((size_t)b * K_ + k) * D_];
    #pragma unroll
    for (int c = 0; c < 4; ++c) {
      float4 vv = src[c * 64 + l];
      ushort4 o;
      o.x = f2bf(vv.x); o.y = f2bf(vv.y); o.z = f2bf(vv.z); o.w = f2bf(vv.w);
      dst[c * 64 + l] = o;
    }
  }
}

// ================= standalone bf16 GEMM wrapper (readout) =================
template<int EPI>
__global__ __launch_bounds__(256)
void sp_gemm_bf16(const u16* __restrict__ A, const u16* __restrict__ Bm,
                  void* __restrict__ Cv, const float* __restrict__ bias,
                  int M, int N, int Kd, int nbx) {
  __shared__ u16 lA[128 * 32];
  __shared__ u16 lB[128 * 32];
  gemm_bf16_body<EPI>(A, Bm, Cv, bias, M, N, Kd, nbx, blockIdx.x, lA, lB);
}

// ================= kernel 4: fused gh GEMM + GRU + scatter + weighted mix =================
// Tile: 128 rows x (3 gates x 64 d-cols). 4 waves (2x2). acc[fm(4)][fn(6)], fn = gate*2+f.
// XCD-affinity remap: block b -> XCD b%8 (dispatch RR); XCD x owns db in {2x,2x+1}
// for all 128 mtiles -> whh working set 768 KB/XCD (L2-resident); consecutive
// r-pairs share an A-tile (slotb) so A is L2-hot on the 2nd block.
template<bool DIRECT>
__global__ __launch_bounds__(256, 2)
void sp_gh_gru(const u16* __restrict__ slotb, const u16* __restrict__ whhb,
               const u16* __restrict__ gib, const float* __restrict__ bih,
               const float* __restrict__ bhh, const int* __restrict__ tki,
               const float* __restrict__ tkw, float* __restrict__ dst,
               u16* __restrict__ umixb) {
  __shared__ u16 lA[128 * 32];
  __shared__ u16 lB[192 * 32];
  __shared__ int   sTki[128];
  __shared__ float sTkw[128];
  const int bidx = blockIdx.x;
  const int xcd = bidx & 7, rr = bidx >> 3;   // rr in [0,256)
  const int db = xcd * 2 + (rr & 1);
  const int mt = rr >> 1;                      // [0,128)
  const int m0 = mt * 128, d0 = db * 64;
  const int t = threadIdx.x;
  const int lane = t & 63, w = t >> 6;
  const int wm = w >> 1, wn = w & 1;
  const int lane15 = lane & 15, hi = lane >> 4;

  if (t < 128) { sTki[t] = tki[m0 + t]; sTkw[t] = tkw[m0 + t]; }

  f32x4 acc[4][6] = {};

  const int srow = t >> 2;
  const int scol = (t & 3) * 8;
  const u16* gA0 = slotb + (size_t)(m0 + srow) * D_ + scol;
  const u16* gA1 = slotb + (size_t)(m0 + 64 + srow) * D_ + scol;
  const u16* gB0 = whhb + (size_t)(d0 + srow) * D_ + scol;
  const u16* gB1 = whhb + (size_t)(D_ + d0 + srow) * D_ + scol;
  const u16* gB2 = whhb + (size_t)(2 * D_ + d0 + srow) * D_ + scol;
  u16* lAw = &lA[(t & 192) * 8];
  u16* lBw = &lB[(t & 192) * 8];

  const int kb = hi * 8;
  const int rA = wm * 64 + lane15;
  const int rB = wn * 32 + lane15;

  for (int k0 = 0; k0 < D_; k0 += 32) {
    __builtin_amdgcn_global_load_lds(AS1C(gA0 + k0), AS3(lAw), 16, 0, 0);
    __builtin_amdgcn_global_load_lds(AS1C(gA1 + k0), AS3(lAw + 2048), 16, 0, 0);
    __builtin_amdgcn_global_load_lds(AS1C(gB0 + k0), AS3(lBw), 16, 0, 0);
    __builtin_amdgcn_global_load_lds(AS1C(gB1 + k0), AS3(lBw + 2048), 16, 0, 0);
    __builtin_amdgcn_global_load_lds(AS1C(gB2 + k0), AS3(lBw + 4096), 16, 0, 0);
    __syncthreads();
    bf16x8 af[4], bfr[6];
    #pragma unroll
    for (int fm = 0; fm < 4; ++fm)
      af[fm] = *(const bf16x8*)&lA[(rA + fm * 16) * 32 + kb];
    #pragma unroll
    for (int g = 0; g < 3; ++g) {
      #pragma unroll
      for (int f = 0; f < 2; ++f)
        bfr[g * 2 + f] = *(const bf16x8*)&lB[(g * 64 + rB + f * 16) * 32 + kb];
    }
    #pragma unroll
    for (int fm = 0; fm < 4; ++fm) {
      #pragma unroll
      for (int fn = 0; fn < 6; ++fn)
        acc[fm][fn] = __builtin_amdgcn_mfma_f32_16x16x32_bf16(af[fm], bfr[fn], acc[fm][fn], 0, 0, 0);
    }
    __syncthreads();
  }

  // ---- GRU epilogue ----
  #pragma unroll
  for (int fm = 0; fm < 4; ++fm) {
    const int rbase = wm * 64 + fm * 16 + hi * 4;     // 4 rows, same batch
    const int bglob = (m0 + rbase) >> 3;
    #pragma unroll
    for (int f = 0; f < 2; ++f) {
      const int dg = d0 + wn * 32 + f * 16 + lane15;  // d within [0,1024)
      const float Gr = bf2f(gib[(size_t)bglob * G3_ + dg])          + bih[dg];
      const float Gz = bf2f(gib[(size_t)bglob * G3_ + D_ + dg])     + bih[D_ + dg];
      const float Gn = bf2f(gib[(size_t)bglob * G3_ + 2 * D_ + dg]) + bih[2 * D_ + dg];
      const float Br = bhh[dg], Bz = bhh[D_ + dg], Bn = bhh[2 * D_ + dg];
      float part = 0.f;
      #pragma unroll
      for (int i = 0; i < 4; ++i) {
        const int row = rbase + i;
        const int grow = m0 + row;
        const float slot = bf2f(slotb[(size_t)grow * D_ + dg]);
        const float rr2 = acc[fm][f][i] + Br;
        const float zz = acc[fm][f + 2][i] + Bz;
        const float nn = acc[fm][f + 4][i] + Bn;
        const float rg = 1.f / (1.f + expf(-(Gr + rr2)));
        const float zg = 1.f / (1.f + expf(-(Gz + zz)));
        const float ng = tanhf(Gn + rg * nn);
        const float uv = (1.f - zg) * ng + zg * slot;
        part = fmaf(sTkw[row], uv, part);
        if (DIRECT)
          __builtin_nontemporal_store(uv, &dst[((size_t)bglob * NS_ + sTki[row]) * D_ + dg]);
        else
          dst[(size_t)grow * D_ + dg] = uv;
      }
      part += __shfl_xor(part, 16);
      if ((hi & 1) == 0)
        umixb[(size_t)bglob * D_ + dg] = f2bf(part);
    }
  }
}

// ================= variant B: copy S->S_new with merge of updated rows =================
__global__ __launch_bounds__(256)
void sp_copy_scatter(const float* __restrict__ S, const float* __restrict__ upd,
                     const int* __restrict__ tki, float* __restrict__ Snew) {
  const int b = blockIdx.x, t = threadIdx.x;
  const int d0 = t * 4;
  int idx[K_];
  #pragma unroll
  for (int k = 0; k < K_; ++k) idx[k] = tki[b * K_ + k];
  for (int s = 0; s < NS_; ++s) {
    int sk = -1;
    #pragma unroll
    for (int k = 0; k < K_; ++k) if (idx[k] == s) sk = k;
    float4 v;
    if (sk >= 0) v = *(const float4*)&upd[((size_t)b * K_ + sk) * D_ + d0];
    else         v = *(const float4*)&S[((size_t)b * NS_ + s) * D_ + d0];
    *(float4*)&Snew[((size_t)b * NS_ + s) * D_ + d0] = v;
  }
}

extern "C" void kernel_launch(void* const* d_in, const int* in_sizes, int n_in,
                              void* d_out, int out_size, void* d_ws, size_t ws_size,
                              hipStream_t stream) {
  const float* x    = (const float*)d_in[0];
  const float* S    = (const float*)d_in[1];
  const float* w1   = (const float*)d_in[2];
  const float* b1   = (const float*)d_in[3];
  const float* w2   = (const float*)d_in[4];
  const float* b2   = (const float*)d_in[5];
  const float* wih  = (const float*)d_in[6];
  const float* whh  = (const float*)d_in[7];
  const float* bih  = (const float*)d_in[8];
  const float* bhh  = (const float*)d_in[9];
  const float* wval = (const float*)d_in[10];
  const float* bval = (const float*)d_in[11];
  const float* wout = (const float*)d_in[12];
  const float* bout = (const float*)d_in[13];
  const float* tau  = (const float*)d_in[14];

  float* out  = (float*)d_out;
  float* Snew = out + (size_t)B_ * D_;

  const bool bigws = ws_size >= (size_t)400 * 1024 * 1024;
  char* bigbase = bigws ? (char*)d_ws : (char*)Snew;  // variant B: scratch in S_new region
  size_t bo = 0;
  auto balloc = [&](size_t bytes) -> void* {
    void* p = bigbase + bo; bo += (bytes + 255) & ~(size_t)255; return p;
  };

  float* mean  = (float*)balloc((size_t)B_ * D_ * 4);
  float* h     = (float*)balloc((size_t)B_ * DH_ * 4);
  u16* xb      = (u16*)balloc((size_t)B_ * D_ * 2);
  u16* wihb    = (u16*)balloc((size_t)G3_ * D_ * 2);
  u16* whhb    = (u16*)balloc((size_t)G3_ * D_ * 2);
  u16* woutb   = (u16*)balloc((size_t)D_ * D_ * 2);
  u16* wvalTb  = (u16*)balloc((size_t)D_ * D_ * 2);
  u16* Wrob    = (u16*)balloc((size_t)D_ * D_ * 2);
  u16* gib     = (u16*)balloc((size_t)B_ * G3_ * 2);
  u16* slotb   = (u16*)balloc((size_t)B_ * K_ * D_ * 2);
  u16* umixb   = (u16*)balloc((size_t)B_ * D_ * 2);
  float* brow  = (float*)balloc((size_t)D_ * 4);

  // small buffers always live in d_ws
  char* wsb = (char*)d_ws;
  size_t so = bigws ? bo : 0;
  auto salloc = [&](size_t bytes) -> void* {
    void* p = wsb + so; so += (bytes + 255) & ~(size_t)255; return p;
  };
  int*   tki = (int*)salloc((size_t)B_ * K_ * 4);
  float* tkw = (float*)salloc((size_t)B_ * K_ * 4);
  float* upd = bigws ? nullptr : (float*)salloc((size_t)B_ * K_ * D_ * 4);

  // 1. copymean + prep (fused; variant B: mean only, Snew region is scratch)
  if (bigws)
    sp_copyprep<1><<<3584, 256, 0, stream>>>(S, Snew, mean, x, wih, whh, wout,
                                             wval, bval, bout, xb, wihb, whhb,
                                             woutb, wvalTb, brow);
  else
    sp_copyprep<0><<<3584, 256, 0, stream>>>(S, Snew, mean, x, wih, whh, wout,
                                             wval, bval, bout, xb, wihb, whhb,
                                             woutb, wvalTb, brow);

  // 2. mid: gi GEMM + routing gemm1 + Wro GEMM (mutually independent)
  sp_mid<<<704, 256, 0, stream>>>(xb, wihb, gib, x, mean, w1, b1, h,
                                  woutb, wvalTb, Wrob);

  // 3. top-k + softmax + gather
  sp_route_topk<<<B_, 64, 0, stream>>>(h, w2, b2, tau, S, tki, tkw, slotb);

  // 4. fused gh GEMM + GRU + scatter + weighted mix (XCD-affinity remap)
  if (bigws)
    sp_gh_gru<true><<<2048, 256, 0, stream>>>(slotb, whhb, gib, bih, bhh,
                                              tki, tkw, Snew, umixb);
  else
    sp_gh_gru<false><<<2048, 256, 0, stream>>>(slotb, whhb, gib, bih, bhh,
                                               tki, tkw, upd, umixb);

  // 5. readout: out = umix @ Wro^T + brow
  sp_gemm_bf16<2><<<128, 256, 0, stream>>>(umixb, Wrob, out, brow, B_, D_, D_, 8);

  // 6. variant B: final copy+merge
  if (!bigws)
    sp_copy_scatter<<<B_, 256, 0, stream>>>(S, upd, tki, Snew);
}

// Round 12
// 773.475 us; speedup vs baseline: 1.5193x; 1.0116x over previous
//
#include <hip/hip_runtime.h>
#include <math.h>
#include <stdint.h>

#define B_   2048
#define NS_  128
#define D_   1024
#define K_   8
#define DH_  512
#define G3_  3072

typedef unsigned short u16;
typedef short bf16x8 __attribute__((ext_vector_type(8)));
typedef float f32x4 __attribute__((ext_vector_type(4)));

__device__ __forceinline__ float bf2f(u16 u) {
  union { unsigned i; float f; } v; v.i = ((unsigned)u) << 16; return v.f;
}
__device__ __forceinline__ u16 f2bf(float f) {
  unsigned x = __float_as_uint(f);
  return (u16)((x + 0x7fffu + ((x >> 16) & 1u)) >> 16);
}

#define AS1C(p) ((const __attribute__((address_space(1))) void*)(uintptr_t)(p))
#define AS3(p)  ((__attribute__((address_space(3))) void*)(unsigned)(uintptr_t)(p))

// ================= kernel 1: copymean + prep (fused, all HBM-streaming) =================
template<int DO_COPY>
__global__ __launch_bounds__(256)
void sp_copyprep(const float* __restrict__ S, float* __restrict__ Snew,
                 float* __restrict__ mean,
                 const float* __restrict__ x, const float* __restrict__ wih,
                 const float* __restrict__ whh, const float* __restrict__ wout,
                 const float* __restrict__ wval, const float* __restrict__ bval,
                 const float* __restrict__ bout,
                 u16* __restrict__ xb, u16* __restrict__ wihb,
                 u16* __restrict__ whhb, u16* __restrict__ woutb,
                 u16* __restrict__ wvalT, float* __restrict__ brow) {
  __shared__ u16 tile[64][65];
  const int blk = blockIdx.x;
  const int t = threadIdx.x;
  if (blk < 2048) {
    const int b = blk;
    const int d0 = t * 4;
    const f32x4* src = (const f32x4*)(S + (size_t)b * NS_ * D_) + t;
    f32x4* dst = (f32x4*)(Snew + (size_t)b * NS_ * D_) + t;
    double a0 = 0, a1 = 0, a2 = 0, a3 = 0;
    #pragma unroll 4
    for (int s = 0; s < NS_; ++s) {
      f32x4 v = __builtin_nontemporal_load(src);
      if (DO_COPY) __builtin_nontemporal_store(v, dst);
      a0 += v[0]; a1 += v[1]; a2 += v[2]; a3 += v[3];
      src += 256; dst += 256;
    }
    float4 m;
    m.x = (float)(a0 * (1.0 / 128.0)); m.y = (float)(a1 * (1.0 / 128.0));
    m.z = (float)(a2 * (1.0 / 128.0)); m.w = (float)(a3 * (1.0 / 128.0));
    *(float4*)&mean[(size_t)b * D_ + d0] = m;
  } else if (blk < 3072) {
    const int cid = blk - 2048;
    for (int i = cid * 256 + t; i < 2359296; i += 1024 * 256) {
      const float* s; u16* d; int off;
      if (i < 524288)       { s = x;    d = xb;    off = i; }
      else if (i < 1310720) { s = wih;  d = wihb;  off = i - 524288; }
      else if (i < 2097152) { s = whh;  d = whhb;  off = i - 1310720; }
      else                  { s = wout; d = woutb; off = i - 2097152; }
      float4 v = ((const float4*)s)[off];
      ushort4 o;
      o.x = f2bf(v.x); o.y = f2bf(v.y); o.z = f2bf(v.z); o.w = f2bf(v.w);
      ((ushort4*)d)[off] = o;
    }
  } else if (blk < 3328) {
    const int tb = blk - 3072;
    const int bx = tb & 15, by = tb >> 4;
    const int r = t >> 4, c4 = (t & 15) * 4;
    #pragma unroll
    for (int p = 0; p < 4; ++p) {
      const int row = by * 64 + p * 16 + r;
      float4 v = *(const float4*)&wval[(size_t)row * D_ + bx * 64 + c4];
      tile[p * 16 + r][c4 + 0] = f2bf(v.x);
      tile[p * 16 + r][c4 + 1] = f2bf(v.y);
      tile[p * 16 + r][c4 + 2] = f2bf(v.z);
      tile[p * 16 + r][c4 + 3] = f2bf(v.w);
    }
    __syncthreads();
    #pragma unroll
    for (int p = 0; p < 4; ++p) {
      const int jr = p * 16 + r;
      ushort4 o;
      o.x = tile[c4 + 0][jr];
      o.y = tile[c4 + 1][jr];
      o.z = tile[c4 + 2][jr];
      o.w = tile[c4 + 3][jr];
      *(ushort4*)&wvalT[(size_t)(bx * 64 + jr) * D_ + by * 64 + c4] = o;
    }
  } else {
    const int w = t >> 6, l = t & 63;
    const int i = (blk - 3328) * 4 + w;
    float s = 0.f;
    const float* wr = &wout[(size_t)i * D_ + l * 16];
    const float* bv = &bval[l * 16];
    #pragma unroll
    for (int j = 0; j < 16; j += 4) {
      float4 w4 = *(const float4*)&wr[j];
      float4 b4 = *(const float4*)&bv[j];
      s += w4.x * b4.x + w4.y * b4.y + w4.z * b4.z + w4.w * b4.w;
    }
    #pragma unroll
    for (int off = 32; off > 0; off >>= 1) s += __shfl_xor(s, off);
    if (l == 0) brow[i] = s + bout[i];
  }
}

// ================= bf16 TN MFMA GEMM body, 2-phase prefetch (dbuf LDS) =================
// 128x128 tile, BK=32, 4 waves, 16x16x32 MFMA, global_load_lds, XCD swizzle.
// EPI: 1=bf16 store, 2=bias+f32 store
template<int EPI>
__device__ __forceinline__ void gemm_bf16_body(
    const u16* __restrict__ A, const u16* __restrict__ Bm,
    void* __restrict__ Cv, const float* __restrict__ bias,
    int M, int N, int Kd, int nbx, int wg,
    u16* lA0, u16* lA1, u16* lB0, u16* lB1) {
  {
    const int nwg = nbx * ((M + 127) >> 7);
    const int cpx = nwg >> 3;               // nwg % 8 == 0 for all our shapes
    wg = (wg & 7) * cpx + (wg >> 3);
  }
  const int m0 = (wg / nbx) * 128, n0 = (wg % nbx) * 128;
  const int t = threadIdx.x;
  const int lane = t & 63;
  const int w = t >> 6;
  const int wm = w >> 1, wn = w & 1;

  f32x4 acc[4][4] = {};

  const int srow = t >> 2;
  const int scol = (t & 3) * 8;
  const u16* gA0 = A + (size_t)(m0 + srow) * Kd + scol;
  const u16* gA1 = A + (size_t)(m0 + 64 + srow) * Kd + scol;
  const u16* gB0 = Bm + (size_t)(n0 + srow) * Kd + scol;
  const u16* gB1 = Bm + (size_t)(n0 + 64 + srow) * Kd + scol;
  const int w16 = (t & 192) * 8;

  const int kb = (lane >> 4) * 8;
  const int rA = wm * 64 + (lane & 15);
  const int rB = wn * 64 + (lane & 15);

  u16 *cA = lA0, *cB = lB0, *nA = lA1, *nB = lB1;
  // prologue: stage k0=0 into current buffers
  __builtin_amdgcn_global_load_lds(AS1C(gA0), AS3(cA + w16), 16, 0, 0);
  __builtin_amdgcn_global_load_lds(AS1C(gA1), AS3(cA + w16 + 2048), 16, 0, 0);
  __builtin_amdgcn_global_load_lds(AS1C(gB0), AS3(cB + w16), 16, 0, 0);
  __builtin_amdgcn_global_load_lds(AS1C(gB1), AS3(cB + w16 + 2048), 16, 0, 0);
  __syncthreads();

  for (int k0 = 0; k0 < Kd; k0 += 32) {
    const int kn = k0 + 32;
    if (kn < Kd) {
      __builtin_amdgcn_global_load_lds(AS1C(gA0 + kn), AS3(nA + w16), 16, 0, 0);
      __builtin_amdgcn_global_load_lds(AS1C(gA1 + kn), AS3(nA + w16 + 2048), 16, 0, 0);
      __builtin_amdgcn_global_load_lds(AS1C(gB0 + kn), AS3(nB + w16), 16, 0, 0);
      __builtin_amdgcn_global_load_lds(AS1C(gB1 + kn), AS3(nB + w16 + 2048), 16, 0, 0);
    }
    bf16x8 af[4], bfr[4];
    #pragma unroll
    for (int fm = 0; fm < 4; ++fm)
      af[fm] = *(const bf16x8*)&cA[(rA + fm * 16) * 32 + kb];
    #pragma unroll
    for (int fn = 0; fn < 4; ++fn)
      bfr[fn] = *(const bf16x8*)&cB[(rB + fn * 16) * 32 + kb];
    #pragma unroll
    for (int fm = 0; fm < 4; ++fm) {
      #pragma unroll
      for (int fn = 0; fn < 4; ++fn)
        acc[fm][fn] = __builtin_amdgcn_mfma_f32_16x16x32_bf16(af[fm], bfr[fn], acc[fm][fn], 0, 0, 0);
    }
    __syncthreads();
    u16* tp;
    tp = cA; cA = nA; nA = tp;
    tp = cB; cB = nB; nB = tp;
  }

  #pragma unroll
  for (int fm = 0; fm < 4; ++fm) {
    #pragma unroll
    for (int fn = 0; fn < 4; ++fn) {
      #pragma unroll
      for (int i = 0; i < 4; ++i) {
        const int r = m0 + wm * 64 + fm * 16 + (lane >> 4) * 4 + i;
        const int c = n0 + wn * 64 + fn * 16 + (lane & 15);
        float v = acc[fm][fn][i];
        if constexpr (EPI == 2) {
          ((float*)Cv)[(size_t)r * N + c] = v + bias[c];
        } else {
          ((u16*)Cv)[(size_t)r * N + c] = f2bf(v);
        }
      }
    }
  }
}

// ================= kernel 2: mid (gi GEMM + gemm1 + Wro GEMM, independent) =================
__global__ __launch_bounds__(256)
void sp_mid(const u16* __restrict__ xb, const u16* __restrict__ wihb,
            u16* __restrict__ gib,
            const float* __restrict__ x, const float* __restrict__ mean,
            const float* __restrict__ w1, const float* __restrict__ b1,
            float* __restrict__ h,
            const u16* __restrict__ woutb, const u16* __restrict__ wvalTb,
            u16* __restrict__ Wrob) {
  __shared__ u16 lA[2][4096];
  __shared__ u16 lB[2][4096];
  const int blk = blockIdx.x;
  const int t = threadIdx.x;
  if (blk < 384) {
    gemm_bf16_body<1>(xb, wihb, gib, nullptr, B_, G3_, D_, G3_ / 128, blk,
                      lA[0], lA[1], lB[0], lB[1]);
  } else if (blk < 640) {
    // ---- gemm1: BM=64, BN=64, BK=16, 4x4 acc/thread, k-sequential fmaf ----
    float (*As)[68] = (float(*)[68])&lA[0][0];
    float (*Bs)[68] = (float(*)[68])&lB[0][0];
    int wg = blk - 384;
    wg = (wg & 7) * 32 + (wg >> 3);       // bijective XCD swizzle, 256 wgs
    const int m0 = (wg >> 3) * 64;
    const int n0 = (wg & 7) * 64;
    const int tx = t & 15, ty = t >> 4;
    float acc[4][4] = {};
    const int sr = t >> 2, sc = (t & 3) * 4;
    for (int k0 = 0; k0 < 2 * D_; k0 += 16) {
      const float* src = (k0 < D_) ? (x + k0) : (mean + (k0 - D_));
      float4 va = *(const float4*)&src[(size_t)(m0 + sr) * D_ + sc];
      As[sc + 0][sr] = va.x; As[sc + 1][sr] = va.y; As[sc + 2][sr] = va.z; As[sc + 3][sr] = va.w;
      float4 vb = *(const float4*)&w1[(size_t)(n0 + sr) * (2 * D_) + k0 + sc];
      Bs[sc + 0][sr] = vb.x; Bs[sc + 1][sr] = vb.y; Bs[sc + 2][sr] = vb.z; Bs[sc + 3][sr] = vb.w;
      __syncthreads();
      #pragma unroll
      for (int kk = 0; kk < 16; ++kk) {
        float4 a4 = *(const float4*)&As[kk][ty * 4];
        float4 b4 = *(const float4*)&Bs[kk][tx * 4];
        acc[0][0] = fmaf(a4.x, b4.x, acc[0][0]); acc[0][1] = fmaf(a4.x, b4.y, acc[0][1]);
        acc[0][2] = fmaf(a4.x, b4.z, acc[0][2]); acc[0][3] = fmaf(a4.x, b4.w, acc[0][3]);
        acc[1][0] = fmaf(a4.y, b4.x, acc[1][0]); acc[1][1] = fmaf(a4.y, b4.y, acc[1][1]);
        acc[1][2] = fmaf(a4.y, b4.z, acc[1][2]); acc[1][3] = fmaf(a4.y, b4.w, acc[1][3]);
        acc[2][0] = fmaf(a4.z, b4.x, acc[2][0]); acc[2][1] = fmaf(a4.z, b4.y, acc[2][1]);
        acc[2][2] = fmaf(a4.z, b4.z, acc[2][2]); acc[2][3] = fmaf(a4.z, b4.w, acc[2][3]);
        acc[3][0] = fmaf(a4.w, b4.x, acc[3][0]); acc[3][1] = fmaf(a4.w, b4.y, acc[3][1]);
        acc[3][2] = fmaf(a4.w, b4.z, acc[3][2]); acc[3][3] = fmaf(a4.w, b4.w, acc[3][3]);
      }
      __syncthreads();
    }
    #pragma unroll
    for (int i = 0; i < 4; ++i) {
      #pragma unroll
      for (int j = 0; j < 4; ++j) {
        const int r = m0 + ty * 4 + i, c = n0 + tx * 4 + j;
        float v = acc[i][j] + b1[c];
        v = 0.5f * v * (1.0f + erff(v * 0.70710678118654752f));
        h[(size_t)r * DH_ + c] = v;
      }
    }
  } else {
    gemm_bf16_body<1>(woutb, wvalTb, Wrob, nullptr, D_, D_, D_, 8, blk - 640,
                      lA[0], lA[1], lB[0], lB[1]);
  }
}

// ================= kernel 3: logits + top-8 + softmax + gather =================
__global__ __launch_bounds__(64)
void sp_route_topk(const float* __restrict__ h, const float* __restrict__ w2,
                   const float* __restrict__ b2, const float* __restrict__ tau,
                   const float* __restrict__ S,
                   int* __restrict__ tki, float* __restrict__ tkw,
                   u16* __restrict__ slotb) {
  __shared__ float hs[DH_];
  __shared__ int sTki[K_];
  const int b = blockIdx.x, l = threadIdx.x;
  *(float4*)&hs[l * 4] = *(const float4*)&h[(size_t)b * DH_ + l * 4];
  *(float4*)&hs[256 + l * 4] = *(const float4*)&h[(size_t)b * DH_ + 256 + l * 4];
  __syncthreads();
  const double invd = 1.0 / ((double)fabsf(tau[0]) + 0.1);
  float v[2]; int id[2];
  #pragma unroll
  for (int c = 0; c < 2; ++c) {
    const int n = c * 64 + l;
    const float* wr = &w2[(size_t)n * DH_];
    double s = 0.0;
    for (int j = 0; j < DH_; j += 4) {
      float4 w4 = *(const float4*)&wr[j];
      s += (double)hs[j] * (double)w4.x;
      s += (double)hs[j + 1] * (double)w4.y;
      s += (double)hs[j + 2] * (double)w4.z;
      s += (double)hs[j + 3] * (double)w4.w;
    }
    v[c] = (float)((s + (double)b2[n]) * invd);
    id[c] = n;
  }
  float m0f = 0.f, sum = 0.f, mye = 0.f; int myi = 0;
  for (int r = 0; r < 8; ++r) {
    float mv; int mi;
    if (v[1] > v[0]) { mv = v[1]; mi = id[1]; } else { mv = v[0]; mi = id[0]; }
    #pragma unroll
    for (int off = 32; off > 0; off >>= 1) {
      float ov = __shfl_xor(mv, off);
      int oi = __shfl_xor(mi, off);
      if (ov > mv || (ov == mv && oi < mi)) { mv = ov; mi = oi; }
    }
    if (r == 0) m0f = mv;
    float er = expf(mv - m0f);
    sum += er;
    if (l == r) { mye = er; myi = mi; }
    if (mi == id[0]) v[0] = -3.0e38f;
    if (mi == id[1]) v[1] = -3.0e38f;
  }
  if (l < 8) {
    tki[b * K_ + l] = myi; tkw[b * K_ + l] = mye / sum;
    sTki[l] = myi;
  }
  __syncthreads();
  #pragma unroll
  for (int k = 0; k < K_; ++k) {
    const int s = sTki[k];
    const float4* src = (const float4*)&S[((size_t)b * NS_ + s) * D_];
    ushort4* dst = (ushort4*)&slotb[((size_t)b * K_ + k) * D_];
    #pragma unroll
    for (int c = 0; c < 4; ++c) {
      float4 vv = src[c * 64 + l];
      ushort4 o;
      o.x = f2bf(vv.x); o.y = f2bf(vv.y); o.z = f2bf(vv.z); o.w = f2bf(vv.w);
      dst[c * 64 + l] = o;
    }
  }
}

// ================= standalone bf16 GEMM wrapper (readout) =================
template<int EPI>
__global__ __launch_bounds__(256)
void sp_gemm_bf16(const u16* __restrict__ A, const u16* __restrict__ Bm,
                  void* __restrict__ Cv, const float* __restrict__ bias,
                  int M, int N, int Kd, int nbx) {
  __shared__ u16 lA[2][4096];
  __shared__ u16 lB[2][4096];
  gemm_bf16_body<EPI>(A, Bm, Cv, bias, M, N, Kd, nbx, blockIdx.x,
                      lA[0], lA[1], lB[0], lB[1]);
}

// ================= kernel 4: fused gh GEMM + GRU + scatter + weighted mix =================
// Tile: 128 rows x (3 gates x 64 d-cols). 4 waves (2x2). acc[fm(4)][fn(6)], fn = gate*2+f.
// 2-phase prefetch (dbuf LDS), per-gate MFMA clustering, 3 blocks/CU.
// XCD-affinity remap: block b -> XCD b%8; XCD x owns db in {2x,2x+1}.
template<bool DIRECT>
__global__ __launch_bounds__(256, 3)
void sp_gh_gru(const u16* __restrict__ slotb, const u16* __restrict__ whhb,
               const u16* __restrict__ gib, const float* __restrict__ bih,
               const float* __restrict__ bhh, const int* __restrict__ tki,
               const float* __restrict__ tkw, float* __restrict__ dst,
               u16* __restrict__ umixb) {
  __shared__ u16 lA[2][4096];    // 128 x 32
  __shared__ u16 lB[2][6144];    // 192 x 32
  __shared__ int   sTki[128];
  __shared__ float sTkw[128];
  const int bidx = blockIdx.x;
  const int xcd = bidx & 7, rr = bidx >> 3;   // rr in [0,256)
  const int db = xcd * 2 + (rr & 1);
  const int mt = rr >> 1;                      // [0,128)
  const int m0 = mt * 128, d0 = db * 64;
  const int t = threadIdx.x;
  const int lane = t & 63, w = t >> 6;
  const int wm = w >> 1, wn = w & 1;
  const int lane15 = lane & 15, hi = lane >> 4;

  if (t < 128) { sTki[t] = tki[m0 + t]; sTkw[t] = tkw[m0 + t]; }

  f32x4 acc[4][6] = {};

  const int srow = t >> 2;
  const int scol = (t & 3) * 8;
  const u16* gA0 = slotb + (size_t)(m0 + srow) * D_ + scol;
  const u16* gA1 = slotb + (size_t)(m0 + 64 + srow) * D_ + scol;
  const u16* gB0 = whhb + (size_t)(d0 + srow) * D_ + scol;
  const u16* gB1 = whhb + (size_t)(D_ + d0 + srow) * D_ + scol;
  const u16* gB2 = whhb + (size_t)(2 * D_ + d0 + srow) * D_ + scol;
  const int w16 = (t & 192) * 8;

  const int kb = hi * 8;
  const int rA = wm * 64 + lane15;
  const int rB = wn * 32 + lane15;

  u16 *cA = lA[0], *cB = lB[0], *nA = lA[1], *nB = lB[1];
  // prologue: stage k0=0
  __builtin_amdgcn_global_load_lds(AS1C(gA0), AS3(cA + w16), 16, 0, 0);
  __builtin_amdgcn_global_load_lds(AS1C(gA1), AS3(cA + w16 + 2048), 16, 0, 0);
  __builtin_amdgcn_global_load_lds(AS1C(gB0), AS3(cB + w16), 16, 0, 0);
  __builtin_amdgcn_global_load_lds(AS1C(gB1), AS3(cB + w16 + 2048), 16, 0, 0);
  __builtin_amdgcn_global_load_lds(AS1C(gB2), AS3(cB + w16 + 4096), 16, 0, 0);
  __syncthreads();

  for (int k0 = 0; k0 < D_; k0 += 32) {
    const int kn = k0 + 32;
    if (kn < D_) {
      __builtin_amdgcn_global_load_lds(AS1C(gA0 + kn), AS3(nA + w16), 16, 0, 0);
      __builtin_amdgcn_global_load_lds(AS1C(gA1 + kn), AS3(nA + w16 + 2048), 16, 0, 0);
      __builtin_amdgcn_global_load_lds(AS1C(gB0 + kn), AS3(nB + w16), 16, 0, 0);
      __builtin_amdgcn_global_load_lds(AS1C(gB1 + kn), AS3(nB + w16 + 2048), 16, 0, 0);
      __builtin_amdgcn_global_load_lds(AS1C(gB2 + kn), AS3(nB + w16 + 4096), 16, 0, 0);
    }
    bf16x8 af[4];
    #pragma unroll
    for (int fm = 0; fm < 4; ++fm)
      af[fm] = *(const bf16x8*)&cA[(rA + fm * 16) * 32 + kb];
    #pragma unroll
    for (int g = 0; g < 3; ++g) {
      bf16x8 b0 = *(const bf16x8*)&cB[(g * 64 + rB) * 32 + kb];
      bf16x8 b1 = *(const bf16x8*)&cB[(g * 64 + rB + 16) * 32 + kb];
      #pragma unroll
      for (int fm = 0; fm < 4; ++fm) {
        acc[fm][g * 2]     = __builtin_amdgcn_mfma_f32_16x16x32_bf16(af[fm], b0, acc[fm][g * 2], 0, 0, 0);
        acc[fm][g * 2 + 1] = __builtin_amdgcn_mfma_f32_16x16x32_bf16(af[fm], b1, acc[fm][g * 2 + 1], 0, 0, 0);
      }
    }
    __syncthreads();
    u16* tp;
    tp = cA; cA = nA; nA = tp;
    tp = cB; cB = nB; nB = tp;
  }

  // ---- GRU epilogue ----
  #pragma unroll
  for (int fm = 0; fm < 4; ++fm) {
    const int rbase = wm * 64 + fm * 16 + hi * 4;     // 4 rows, same batch
    const int bglob = (m0 + rbase) >> 3;
    #pragma unroll
    for (int f = 0; f < 2; ++f) {
      const int dg = d0 + wn * 32 + f * 16 + lane15;  // d within [0,1024)
      const float Gr = bf2f(gib[(size_t)bglob * G3_ + dg])          + bih[dg];
      const float Gz = bf2f(gib[(size_t)bglob * G3_ + D_ + dg])     + bih[D_ + dg];
      const float Gn = bf2f(gib[(size_t)bglob * G3_ + 2 * D_ + dg]) + bih[2 * D_ + dg];
      const float Br = bhh[dg], Bz = bhh[D_ + dg], Bn = bhh[2 * D_ + dg];
      float part = 0.f;
      #pragma unroll
      for (int i = 0; i < 4; ++i) {
        const int row = rbase + i;
        const int grow = m0 + row;
        const float slot = bf2f(slotb[(size_t)grow * D_ + dg]);
        const float rr2 = acc[fm][f][i] + Br;
        const float zz = acc[fm][f + 2][i] + Bz;
        const float nn = acc[fm][f + 4][i] + Bn;
        const float rg = 1.f / (1.f + expf(-(Gr + rr2)));
        const float zg = 1.f / (1.f + expf(-(Gz + zz)));
        const float ng = tanhf(Gn + rg * nn);
        const float uv = (1.f - zg) * ng + zg * slot;
        part = fmaf(sTkw[row], uv, part);
        if (DIRECT)
          __builtin_nontemporal_store(uv, &dst[((size_t)bglob * NS_ + sTki[row]) * D_ + dg]);
        else
          dst[(size_t)grow * D_ + dg] = uv;
      }
      part += __shfl_xor(part, 16);
      if ((hi & 1) == 0)
        umixb[(size_t)bglob * D_ + dg] = f2bf(part);
    }
  }
}

// ================= variant B: copy S->S_new with merge of updated rows =================
__global__ __launch_bounds__(256)
void sp_copy_scatter(const float* __restrict__ S, const float* __restrict__ upd,
                     const int* __restrict__ tki, float* __restrict__ Snew) {
  const int b = blockIdx.x, t = threadIdx.x;
  const int d0 = t * 4;
  int idx[K_];
  #pragma unroll
  for (int k = 0; k < K_; ++k) idx[k] = tki[b * K_ + k];
  for (int s = 0; s < NS_; ++s) {
    int sk = -1;
    #pragma unroll
    for (int k = 0; k < K_; ++k) if (idx[k] == s) sk = k;
    float4 v;
    if (sk >= 0) v = *(const float4*)&upd[((size_t)b * K_ + sk) * D_ + d0];
    else         v = *(const float4*)&S[((size_t)b * NS_ + s) * D_ + d0];
    *(float4*)&Snew[((size_t)b * NS_ + s) * D_ + d0] = v;
  }
}

extern "C" void kernel_launch(void* const* d_in, const int* in_sizes, int n_in,
                              void* d_out, int out_size, void* d_ws, size_t ws_size,
                              hipStream_t stream) {
  const float* x    = (const float*)d_in[0];
  const float* S    = (const float*)d_in[1];
  const float* w1   = (const float*)d_in[2];
  const float* b1   = (const float*)d_in[3];
  const float* w2   = (const float*)d_in[4];
  const float* b2   = (const float*)d_in[5];
  const float* wih  = (const float*)d_in[6];
  const float* whh  = (const float*)d_in[7];
  const float* bih  = (const float*)d_in[8];
  const float* bhh  = (const float*)d_in[9];
  const float* wval = (const float*)d_in[10];
  const float* bval = (const float*)d_in[11];
  const float* wout = (const float*)d_in[12];
  const float* bout = (const float*)d_in[13];
  const float* tau  = (const float*)d_in[14];

  float* out  = (float*)d_out;
  float* Snew = out + (size_t)B_ * D_;

  const bool bigws = ws_size >= (size_t)400 * 1024 * 1024;
  char* bigbase = bigws ? (char*)d_ws : (char*)Snew;  // variant B: scratch in S_new region
  size_t bo = 0;
  auto balloc = [&](size_t bytes) -> void* {
    void* p = bigbase + bo; bo += (bytes + 255) & ~(size_t)255; return p;
  };

  float* mean  = (float*)balloc((size_t)B_ * D_ * 4);
  float* h     = (float*)balloc((size_t)B_ * DH_ * 4);
  u16* xb      = (u16*)balloc((size_t)B_ * D_ * 2);
  u16* wihb    = (u16*)balloc((size_t)G3_ * D_ * 2);
  u16* whhb    = (u16*)balloc((size_t)G3_ * D_ * 2);
  u16* woutb   = (u16*)balloc((size_t)D_ * D_ * 2);
  u16* wvalTb  = (u16*)balloc((size_t)D_ * D_ * 2);
  u16* Wrob    = (u16*)balloc((size_t)D_ * D_ * 2);
  u16* gib     = (u16*)balloc((size_t)B_ * G3_ * 2);
  u16* slotb   = (u16*)balloc((size_t)B_ * K_ * D_ * 2);
  u16* umixb   = (u16*)balloc((size_t)B_ * D_ * 2);
  float* brow  = (float*)balloc((size_t)D_ * 4);

  // small buffers always live in d_ws
  char* wsb = (char*)d_ws;
  size_t so = bigws ? bo : 0;
  auto salloc = [&](size_t bytes) -> void* {
    void* p = wsb + so; so += (bytes + 255) & ~(size_t)255; return p;
  };
  int*   tki = (int*)salloc((size_t)B_ * K_ * 4);
  float* tkw = (float*)salloc((size_t)B_ * K_ * 4);
  float* upd = bigws ? nullptr : (float*)salloc((size_t)B_ * K_ * D_ * 4);

  // 1. copymean + prep (fused; variant B: mean only, Snew region is scratch)
  if (bigws)
    sp_copyprep<1><<<3584, 256, 0, stream>>>(S, Snew, mean, x, wih, whh, wout,
                                             wval, bval, bout, xb, wihb, whhb,
                                             woutb, wvalTb, brow);
  else
    sp_copyprep<0><<<3584, 256, 0, stream>>>(S, Snew, mean, x, wih, whh, wout,
                                             wval, bval, bout, xb, wihb, whhb,
                                             woutb, wvalTb, brow);

  // 2. mid: gi GEMM + routing gemm1 + Wro GEMM (mutually independent)
  sp_mid<<<704, 256, 0, stream>>>(xb, wihb, gib, x, mean, w1, b1, h,
                                  woutb, wvalTb, Wrob);

  // 3. top-k + softmax + gather
  sp_route_topk<<<B_, 64, 0, stream>>>(h, w2, b2, tau, S, tki, tkw, slotb);

  // 4. fused gh GEMM + GRU + scatter + weighted mix (2-phase, 3 blocks/CU)
  if (bigws)
    sp_gh_gru<true><<<2048, 256, 0, stream>>>(slotb, whhb, gib, bih, bhh,
                                              tki, tkw, Snew, umixb);
  else
    sp_gh_gru<false><<<2048, 256, 0, stream>>>(slotb, whhb, gib, bih, bhh,
                                               tki, tkw, upd, umixb);

  // 5. readout: out = umix @ Wro^T + brow
  sp_gemm_bf16<2><<<128, 256, 0, stream>>>(umixb, Wrob, out, brow, B_, D_, D_, 8);

  // 6. variant B: final copy+merge
  if (!bigws)
    sp_copy_scatter<<<B_, 256, 0, stream>>>(S, upd, tki, Snew);
}